// Round 8
// baseline (10853.194 us; speedup 1.0000x reference)
//
#include <hip/hip_runtime.h>
#include <math.h>

#define B_   16
#define S_   1024
#define R_   512
#define H_   512
#define HD_  256
#define G_   1024
#define DIN_ 1536

// ---------------------------------------------------------------------------
// Tiled fp32 GEMM:  C[m][n] = sum_k A(m,k) * B(n,k)
// A layout MK (row-major [M][K], row stride a_rs), optional row remap for step1.
// B layout NK (row-major [N][K], row stride b_rs).
// EPI: 0 = none, 1 = tanh(x + bias[n]), 2 = x + bias[n] + bias2[n]
// ---------------------------------------------------------------------------
template<int EPI, int REMAP_A>
__global__ __launch_bounds__(256) void gemm_mk_nk(
    const float* __restrict__ A, long a_rs, long a_bs,
    const float* __restrict__ Bm, long b_rs, long b_bs,
    float* __restrict__ C, long c_rs, long c_bs,
    const float* __restrict__ bias, const float* __restrict__ bias2,
    int M, int N, int K)
{
    __shared__ float As[16][68];
    __shared__ float Bs[16][68];
    const int bb = blockIdx.z;
    const float* Ab = A + (long)bb * a_bs;
    const float* Bb = Bm + (long)bb * b_bs;
    float* Cb = C + (long)bb * c_bs;
    const int m0 = blockIdx.y * 64, n0 = blockIdx.x * 64;
    const int tid = threadIdx.x;
    const int tx = tid & 15, ty = tid >> 4;
    const int lr = tid >> 2;          // tile row 0..63
    const int lk = (tid & 3) << 2;    // k offset 0..12

    long arow;
    {
        int m = m0 + lr;
        if (REMAP_A) arow = (long)((m % S_) * B_ + (m / S_)) * a_rs;
        else         arow = (long)m * a_rs;
    }
    const long brow = (long)(n0 + lr) * b_rs;

    float acc[4][4] = {};
    for (int k0 = 0; k0 < K; k0 += 16) {
        float4 av = *(const float4*)(Ab + arow + k0 + lk);
        float4 bv = *(const float4*)(Bb + brow + k0 + lk);
        As[lk + 0][lr] = av.x; As[lk + 1][lr] = av.y;
        As[lk + 2][lr] = av.z; As[lk + 3][lr] = av.w;
        Bs[lk + 0][lr] = bv.x; Bs[lk + 1][lr] = bv.y;
        Bs[lk + 2][lr] = bv.z; Bs[lk + 3][lr] = bv.w;
        __syncthreads();
#pragma unroll
        for (int kk = 0; kk < 16; ++kk) {
            float4 a = *(const float4*)&As[kk][ty << 2];
            float4 b = *(const float4*)&Bs[kk][tx << 2];
            acc[0][0] += a.x * b.x; acc[0][1] += a.x * b.y; acc[0][2] += a.x * b.z; acc[0][3] += a.x * b.w;
            acc[1][0] += a.y * b.x; acc[1][1] += a.y * b.y; acc[1][2] += a.y * b.z; acc[1][3] += a.y * b.w;
            acc[2][0] += a.z * b.x; acc[2][1] += a.z * b.y; acc[2][2] += a.z * b.z; acc[2][3] += a.z * b.w;
            acc[3][0] += a.w * b.x; acc[3][1] += a.w * b.y; acc[3][2] += a.w * b.z; acc[3][3] += a.w * b.w;
        }
        __syncthreads();
    }
#pragma unroll
    for (int i = 0; i < 4; ++i) {
        const int m = m0 + (ty << 2) + i;
#pragma unroll
        for (int j = 0; j < 4; ++j) {
            const int n = n0 + (tx << 2) + j;
            float v = acc[i][j];
            if (EPI == 1) v = tanhf(v + bias[n]);
            else if (EPI == 2) v += bias[n] + bias2[n];
            Cb[(long)m * c_rs + n] = v;
        }
    }
}

// ---------------------------------------------------------------------------
// Tiled fp32 GEMM:  C[m][n] = sum_k A(k,m) * B(n,k)
// A layout KM ([K][M], k stride a_ks), B layout NK.  No epilogue.
// ---------------------------------------------------------------------------
__global__ __launch_bounds__(256) void gemm_km_nk(
    const float* __restrict__ A, long a_ks, long a_bs,
    const float* __restrict__ Bm, long b_rs, long b_bs,
    float* __restrict__ C, long c_rs, long c_bs,
    int M, int N, int K)
{
    __shared__ float As[16][68];
    __shared__ float Bs[16][68];
    const int bb = blockIdx.z;
    const float* Ab = A + (long)bb * a_bs;
    const float* Bb = Bm + (long)bb * b_bs;
    float* Cb = C + (long)bb * c_bs;
    const int m0 = blockIdx.y * 64, n0 = blockIdx.x * 64;
    const int tid = threadIdx.x;
    const int tx = tid & 15, ty = tid >> 4;
    const int lr = tid >> 2;            // B tile row (n) 0..63
    const int lk = (tid & 3) << 2;      // B k offset
    const int alk = tid >> 4;           // A k row 0..15
    const int alm = (tid & 15) << 2;    // A m offset
    const long brow = (long)(n0 + lr) * b_rs;

    float acc[4][4] = {};
    for (int k0 = 0; k0 < K; k0 += 16) {
        float4 av = *(const float4*)(Ab + (long)(k0 + alk) * a_ks + m0 + alm);
        *(float4*)&As[alk][alm] = av;
        float4 bv = *(const float4*)(Bb + brow + k0 + lk);
        Bs[lk + 0][lr] = bv.x; Bs[lk + 1][lr] = bv.y;
        Bs[lk + 2][lr] = bv.z; Bs[lk + 3][lr] = bv.w;
        __syncthreads();
#pragma unroll
        for (int kk = 0; kk < 16; ++kk) {
            float4 a = *(const float4*)&As[kk][ty << 2];
            float4 b = *(const float4*)&Bs[kk][tx << 2];
            acc[0][0] += a.x * b.x; acc[0][1] += a.x * b.y; acc[0][2] += a.x * b.z; acc[0][3] += a.x * b.w;
            acc[1][0] += a.y * b.x; acc[1][1] += a.y * b.y; acc[1][2] += a.y * b.z; acc[1][3] += a.y * b.w;
            acc[2][0] += a.z * b.x; acc[2][1] += a.z * b.y; acc[2][2] += a.z * b.z; acc[2][3] += a.z * b.w;
            acc[3][0] += a.w * b.x; acc[3][1] += a.w * b.y; acc[3][2] += a.w * b.z; acc[3][3] += a.w * b.w;
        }
        __syncthreads();
    }
#pragma unroll
    for (int i = 0; i < 4; ++i) {
        const int m = m0 + (ty << 2) + i;
#pragma unroll
        for (int j = 0; j < 4; ++j) {
            const int n = n0 + (tx << 2) + j;
            Cb[(long)m * c_rs + n] = acc[i][j];
        }
    }
}

// ---------------------------------------------------------------------------
// Softmax over r (last axis, contiguous, 512 elems): one wave per row, in-place
// ---------------------------------------------------------------------------
__global__ __launch_bounds__(256) void softmax_rows(float* __restrict__ l)
{
    const int lane = threadIdx.x & 63;
    const int wv = threadIdx.x >> 6;
    const long row = (long)blockIdx.x * 4 + wv;
    float* p = l + row * R_;
    float4 v0 = ((const float4*)p)[lane * 2];
    float4 v1 = ((const float4*)p)[lane * 2 + 1];
    float m = fmaxf(fmaxf(fmaxf(v0.x, v0.y), fmaxf(v0.z, v0.w)),
                    fmaxf(fmaxf(v1.x, v1.y), fmaxf(v1.z, v1.w)));
#pragma unroll
    for (int o = 32; o; o >>= 1) m = fmaxf(m, __shfl_xor(m, o));
    v0.x = __expf(v0.x - m); v0.y = __expf(v0.y - m);
    v0.z = __expf(v0.z - m); v0.w = __expf(v0.w - m);
    v1.x = __expf(v1.x - m); v1.y = __expf(v1.y - m);
    v1.z = __expf(v1.z - m); v1.w = __expf(v1.w - m);
    float s = v0.x + v0.y + v0.z + v0.w + v1.x + v1.y + v1.z + v1.w;
#pragma unroll
    for (int o = 32; o; o >>= 1) s += __shfl_xor(s, o);
    const float inv = 1.f / s;
    v0.x *= inv; v0.y *= inv; v0.z *= inv; v0.w *= inv;
    v1.x *= inv; v1.y *= inv; v1.z *= inv; v1.w *= inv;
    ((float4*)p)[lane * 2] = v0;
    ((float4*)p)[lane * 2 + 1] = v1;
}

// ---------------------------------------------------------------------------
// Softmax over s (axis 1, stride R): 512 threads = 128 cols x 4 s-groups,
// LDS reduce across the 4 partials, 3 coalesced passes.
// ---------------------------------------------------------------------------
__global__ __launch_bounds__(512) void softmax_cols(const float* __restrict__ l,
                                                    float* __restrict__ as_)
{
    const int b = blockIdx.y;
    const int rl = threadIdx.x & 127;
    const int r = blockIdx.x * 128 + rl;
    const int sg = threadIdx.x >> 7;           // 0..3
    const int s0 = sg * (S_ / 4), s1 = s0 + S_ / 4;
    const float* base = l + (long)b * S_ * R_ + r;
    __shared__ float red[4][128];

    float pm = -1e30f;
    for (int s = s0; s < s1; ++s) pm = fmaxf(pm, base[(long)s * R_]);
    red[sg][rl] = pm;
    __syncthreads();
    const float m = fmaxf(fmaxf(red[0][rl], red[1][rl]), fmaxf(red[2][rl], red[3][rl]));
    __syncthreads();

    float ps = 0.f;
    for (int s = s0; s < s1; ++s) ps += __expf(base[(long)s * R_] - m);
    red[sg][rl] = ps;
    __syncthreads();
    const float inv = 1.f / (red[0][rl] + red[1][rl] + red[2][rl] + red[3][rl]);

    float* ob = as_ + (long)b * S_ * R_ + r;
    for (int s = s0; s < s1; ++s) ob[(long)s * R_] = __expf(base[(long)s * R_] - m) * inv;
}

// ---------------------------------------------------------------------------
// cat[b][h][s] = h_s[b][s][h]  (s_t half of cat_sc), 32x32 LDS tile transpose
// ---------------------------------------------------------------------------
__global__ __launch_bounds__(256) void transpose_hs(const float* __restrict__ hs,
                                                    float* __restrict__ cat)
{
    __shared__ float tile[32][33];
    const int b = blockIdx.z;
    const int s0 = blockIdx.x * 32, h0 = blockIdx.y * 32;
    const int tx = threadIdx.x, ty = threadIdx.y;
#pragma unroll
    for (int i = 0; i < 32; i += 8)
        tile[ty + i][tx] = hs[((long)b * S_ + s0 + ty + i) * H_ + h0 + tx];
    __syncthreads();
#pragma unroll
    for (int i = 0; i < 32; i += 8)
        cat[((long)b * 2 * H_ + h0 + ty + i) * S_ + s0 + tx] = tile[tx][ty + i];
}

// ---------------------------------------------------------------------------
// bin[t][b][0:1024] = c_r[b][t][:]; bin[t][b][1024:1536] = ref[t][b][:]
// ---------------------------------------------------------------------------
__global__ __launch_bounds__(256) void build_bin(const float* __restrict__ cr,
                                                 const float* __restrict__ ref,
                                                 float* __restrict__ bin)
{
    const long idx4 = (long)blockIdx.x * blockDim.x + threadIdx.x;
    if (idx4 >= (long)R_ * B_ * DIN_ / 4) return;
    const long f = idx4 * 4;
    const int d = (int)(f % DIN_);
    const long tb = f / DIN_;
    const int b = (int)(tb % B_);
    const int t = (int)(tb / B_);
    float4 v;
    if (d < 2 * H_) v = *(const float4*)(cr + ((long)b * R_ + t) * (2 * H_) + d);
    else            v = *(const float4*)(ref + ((long)t * B_ + b) * H_ + (d - 2 * H_));
    *(float4*)(bin + f) = v;
}

// ---------------------------------------------------------------------------
// One-time W_hh transpose: WT4[dir][q][g][0:4] = Whh_dir[g][4q..4q+3]
// (k-quad-major layout so the scan's per-instr wave load is 64 consecutive
// float4 = perfectly coalesced 1 KB). 2 MB total, runs once per launch.
// ---------------------------------------------------------------------------
__global__ __launch_bounds__(256) void transpose_w(const float* __restrict__ Whh_f,
                                                   const float* __restrict__ Whh_b,
                                                   float* __restrict__ WT4)
{
    const int g = blockIdx.x * 256 + threadIdx.x;   // 0..1023
    const int q = blockIdx.y;                       // 0..63
    const int dir = blockIdx.z;
    const float* W = dir ? Whh_b : Whh_f;
    float4 v = *(const float4*)(W + (long)g * HD_ + 4 * q);
    *((float4*)WT4 + (long)dir * 65536 + q * 1024 + g) = v;
}

// ---------------------------------------------------------------------------
// Bi-LSTM scan, BATCH-PARTITIONED: the 2x16 (dir, batch) recurrences are
// completely independent -> one block each, 32 blocks, ZERO cross-block
// communication (no flags, no fences, no global h buffer - R7's 7.7us/step
// was pure cross-XCD sync latency, all of it gone).
// Block (dir,b), 1024 threads (16 waves): per step the 1024x256 gate matvec.
//   thread (ks=tid>>7, go=tid&127) owns rows {128*ri+go : ri<8}, k-chunk
//   [32ks, 32ks+32): 64 coalesced float4 W loads (WT4 layout), 8 uniform
//   ds_read_b128 h broadcasts, 256 FMA. 8-way k-partials reduced via 32KB
//   LDS; cell update on threads 0..255 (c in registers, h in LDS only).
// Per-step floor: 256 FMA x 2cy x 4 waves/SIMD ~ 0.86us; W stream 1MB/step
// from L2 (~0.93us/XCD at 4 blocks/XCD) overlapped.
// ---------------------------------------------------------------------------
__device__ inline float sig_(float x) { return 1.f / (1.f + __expf(-x)); }
__device__ inline float tanh_(float x) {
    float ax = fabsf(x);
    float t = 1.f - 2.f / (1.f + __expf(2.f * ax));
    return copysignf(t, x);
}

__global__ __launch_bounds__(1024) void lstm_scan_b(
    const float* __restrict__ xg_f, const float* __restrict__ xg_b,
    const float* __restrict__ WT4, float* __restrict__ out)
{
    const int blk = blockIdx.x;
    const int dir = blk >> 4;
    const int b = blk & 15;
    const float* xg = dir ? xg_b : xg_f;
    const float4* W = (const float4*)WT4 + (long)dir * 65536;

    __shared__ float h_lds[256];
    __shared__ float p_lds[8][1024];

    const int tid = threadIdx.x;
    const int ks = tid >> 7;        // 0..7, wave-uniform
    const int go = tid & 127;       // 0..127, consecutive within wave

    if (tid < 256) h_lds[tid] = 0.f;
    float c_reg = 0.f;
    __syncthreads();

    for (int t = 0; t < R_; ++t) {
        const int tt = dir ? (R_ - 1 - t) : t;
        // xg for this thread's reduce column (gate row = tid), coalesced 4KB
        const float xgv = xg[((long)tt * B_ + b) * G_ + tid];

        // dot: 8 rows x 32 k per thread
        float acc[8] = {};
#pragma unroll
        for (int kk = 0; kk < 8; ++kk) {
            const int q = ks * 8 + kk;                       // k-quad 0..63
            const float4 h4 = *(const float4*)&h_lds[q * 4]; // uniform bcast
            const float4* wp = W + q * 1024 + go;
#pragma unroll
            for (int ri = 0; ri < 8; ++ri) {
                const float4 w = wp[ri * 128];
                acc[ri] += w.x * h4.x + w.y * h4.y + w.z * h4.z + w.w * h4.w;
            }
        }
#pragma unroll
        for (int ri = 0; ri < 8; ++ri)
            p_lds[ks][ri * 128 + go] = acc[ri];
        __syncthreads();

        // reduce 8 k-partials for gate row g = tid (column-local overwrite)
        float gate = xgv;
#pragma unroll
        for (int k2 = 0; k2 < 8; ++k2) gate += p_lds[k2][tid];
        p_lds[0][tid] = gate;
        __syncthreads();

        // cell update: thread n<256 owns column n (c in register)
        if (tid < 256) {
            const float iv = p_lds[0][tid];
            const float fv = p_lds[0][256 + tid];
            const float gv = p_lds[0][512 + tid];
            const float ov = p_lds[0][768 + tid];
            c_reg = sig_(fv) * c_reg + sig_(iv) * tanh_(gv);
            const float h = sig_(ov) * tanh_(c_reg);
            h_lds[tid] = h;
            out[((long)tt * B_ + b) * (2 * HD_) + dir * HD_ + tid] = h;
        }
        __syncthreads();
    }
}

// ---------------------------------------------------------------------------
extern "C" void kernel_launch(void* const* d_in, const int* in_sizes, int n_in,
                              void* d_out, int out_size, void* d_ws, size_t ws_size,
                              hipStream_t stream)
{
    const float* src  = (const float*)d_in[1];   // [S][B][H]
    const float* ref  = (const float*)d_in[2];   // [R][B][H]
    const float* Wref = (const float*)d_in[3];   // [H][H]
    const float* bref = (const float*)d_in[4];   // [H]
    const float* Wihf = (const float*)d_in[5];   // [G][DIN]
    const float* Whhf = (const float*)d_in[6];   // [G][HD]
    const float* bihf = (const float*)d_in[7];
    const float* bhhf = (const float*)d_in[8];
    const float* Wihb = (const float*)d_in[9];
    const float* Whhb = (const float*)d_in[10];
    const float* bihb = (const float*)d_in[11];
    const float* bhhb = (const float*)d_in[12];
    float* out = (float*)d_out;                  // [R][B][2*HD]

    float* ws = (float*)d_ws;
    // workspace layout (floats), with aliasing:
    float* hs  = ws + 0L;                         // 8388608   [B][S][H]
    float* l   = ws + 8388608L;                   // 8388608   [B][S][R] (a_r in place)
    float* as_ = ws + 16777216L;                  // 8388608   [B][S][R]
    float* cat = ws + 25165824L;                  // 16777216  [B][2H][S]
    float* cr  = hs;                              // 8388608   [B][R][2H]  (hs dead after step 4)
    float* bin = cat;                             // 12582912  [T][B][DIN] (cat dead after step 6)
    float* xgf = l;                               // 8388608   [T][B][G]   (l dead after step 6)
    float* xgb = as_;                             // 8388608   [T][B][G]   (as_ dead after step 5)
    float* WT4 = ws + 41943040L;                  // 524288    2 dir x 64 q x 1024 g x 4

    // 0) one-time W_hh transpose into k-quad-major layout
    transpose_w<<<dim3(4, 64, 2), 256, 0, stream>>>(Whhf, Whhb, WT4);

    // 1) h_s = tanh(src . Wref^T + bref)   [B*S, 512] k=512
    gemm_mk_nk<1, 1><<<dim3(8, 256, 1), 256, 0, stream>>>(
        src, H_, 0, Wref, H_, 0, hs, H_, 0, bref, nullptr, B_ * S_, H_, H_);

    // 2) l[b] = h_s[b] . h_r[b]^T   M=1024 N=512 K=512, batched over b
    gemm_mk_nk<0, 0><<<dim3(8, 16, B_), 256, 0, stream>>>(
        hs, H_, (long)S_ * H_, ref, (long)B_ * H_, H_, l, R_, (long)S_ * R_,
        nullptr, nullptr, S_, R_, H_);

    // 3) a_s = softmax over s (columns), then a_r = softmax over r in place
    softmax_cols<<<dim3(R_ / 128, B_), 512, 0, stream>>>(l, as_);
    softmax_rows<<<(B_ * S_) / 4, 256, 0, stream>>>(l);

    // 4) cat rows 0..511 = h_s transposed
    transpose_hs<<<dim3(S_ / 32, H_ / 32, B_), dim3(32, 8), 0, stream>>>(hs, cat);

    // 5) cat rows 512..1023: c_s[b,h,s] = sum_r ref[r,b,h]*a_s[b,s,r]
    gemm_km_nk<<<dim3(16, 8, B_), 256, 0, stream>>>(
        ref, (long)B_ * H_, H_, as_, R_, (long)S_ * R_,
        cat + (long)H_ * S_, S_, (long)2 * H_ * S_, H_, S_, R_);

    // 6) c_r[b,r,k] = sum_s cat[b,k,s]*a_r[b,s,r]   M=512 N=1024 K=1024
    gemm_km_nk<<<dim3(16, 8, B_), 256, 0, stream>>>(
        l, R_, (long)S_ * R_, cat, S_, (long)2 * H_ * S_,
        cr, 2 * H_, (long)R_ * 2 * H_, R_, 2 * H_, S_);

    // 7) bilstm_in
    build_bin<<<(R_ * B_ * DIN_ / 4 + 255) / 256, 256, 0, stream>>>(cr, ref, bin);

    // 8) xg = bin . W_ih^T + b_ih + b_hh  (both directions)
    gemm_mk_nk<2, 0><<<dim3(16, 128, 1), 256, 0, stream>>>(
        bin, DIN_, 0, Wihf, DIN_, 0, xgf, G_, 0, bihf, bhhf, R_ * B_, G_, DIN_);
    gemm_mk_nk<2, 0><<<dim3(16, 128, 1), 256, 0, stream>>>(
        bin, DIN_, 0, Wihb, DIN_, 0, xgb, G_, 0, bihb, bhhb, R_ * B_, G_, DIN_);

    // 9) bi-LSTM scan: 32 independent (dir,batch) blocks, block-local only
    lstm_scan_b<<<dim3(32), dim3(1024), 0, stream>>>(xgf, xgb, WT4, out);
}

// Round 9
// 7104.575 us; speedup vs baseline: 1.5276x; 1.5276x over previous
//
#include <hip/hip_runtime.h>
#include <hip/hip_bf16.h>
#include <math.h>

#define B_   16
#define S_   1024
#define R_   512
#define H_   512
#define HD_  256
#define G_   1024
#define DIN_ 1536

// ---------------------------------------------------------------------------
// Tiled fp32 GEMM:  C[m][n] = sum_k A(m,k) * B(n,k)
// ---------------------------------------------------------------------------
template<int EPI, int REMAP_A>
__global__ __launch_bounds__(256) void gemm_mk_nk(
    const float* __restrict__ A, long a_rs, long a_bs,
    const float* __restrict__ Bm, long b_rs, long b_bs,
    float* __restrict__ C, long c_rs, long c_bs,
    const float* __restrict__ bias, const float* __restrict__ bias2,
    int M, int N, int K)
{
    __shared__ float As[16][68];
    __shared__ float Bs[16][68];
    const int bb = blockIdx.z;
    const float* Ab = A + (long)bb * a_bs;
    const float* Bb = Bm + (long)bb * b_bs;
    float* Cb = C + (long)bb * c_bs;
    const int m0 = blockIdx.y * 64, n0 = blockIdx.x * 64;
    const int tid = threadIdx.x;
    const int tx = tid & 15, ty = tid >> 4;
    const int lr = tid >> 2;          // tile row 0..63
    const int lk = (tid & 3) << 2;    // k offset 0..12

    long arow;
    {
        int m = m0 + lr;
        if (REMAP_A) arow = (long)((m % S_) * B_ + (m / S_)) * a_rs;
        else         arow = (long)m * a_rs;
    }
    const long brow = (long)(n0 + lr) * b_rs;

    float acc[4][4] = {};
    for (int k0 = 0; k0 < K; k0 += 16) {
        float4 av = *(const float4*)(Ab + arow + k0 + lk);
        float4 bv = *(const float4*)(Bb + brow + k0 + lk);
        As[lk + 0][lr] = av.x; As[lk + 1][lr] = av.y;
        As[lk + 2][lr] = av.z; As[lk + 3][lr] = av.w;
        Bs[lk + 0][lr] = bv.x; Bs[lk + 1][lr] = bv.y;
        Bs[lk + 2][lr] = bv.z; Bs[lk + 3][lr] = bv.w;
        __syncthreads();
#pragma unroll
        for (int kk = 0; kk < 16; ++kk) {
            float4 a = *(const float4*)&As[kk][ty << 2];
            float4 b = *(const float4*)&Bs[kk][tx << 2];
            acc[0][0] += a.x * b.x; acc[0][1] += a.x * b.y; acc[0][2] += a.x * b.z; acc[0][3] += a.x * b.w;
            acc[1][0] += a.y * b.x; acc[1][1] += a.y * b.y; acc[1][2] += a.y * b.z; acc[1][3] += a.y * b.w;
            acc[2][0] += a.z * b.x; acc[2][1] += a.z * b.y; acc[2][2] += a.z * b.z; acc[2][3] += a.z * b.w;
            acc[3][0] += a.w * b.x; acc[3][1] += a.w * b.y; acc[3][2] += a.w * b.z; acc[3][3] += a.w * b.w;
        }
        __syncthreads();
    }
#pragma unroll
    for (int i = 0; i < 4; ++i) {
        const int m = m0 + (ty << 2) + i;
#pragma unroll
        for (int j = 0; j < 4; ++j) {
            const int n = n0 + (tx << 2) + j;
            float v = acc[i][j];
            if (EPI == 1) v = tanhf(v + bias[n]);
            else if (EPI == 2) v += bias[n] + bias2[n];
            Cb[(long)m * c_rs + n] = v;
        }
    }
}

// ---------------------------------------------------------------------------
// Tiled fp32 GEMM:  C[m][n] = sum_k A(k,m) * B(n,k)
// ---------------------------------------------------------------------------
__global__ __launch_bounds__(256) void gemm_km_nk(
    const float* __restrict__ A, long a_ks, long a_bs,
    const float* __restrict__ Bm, long b_rs, long b_bs,
    float* __restrict__ C, long c_rs, long c_bs,
    int M, int N, int K)
{
    __shared__ float As[16][68];
    __shared__ float Bs[16][68];
    const int bb = blockIdx.z;
    const float* Ab = A + (long)bb * a_bs;
    const float* Bb = Bm + (long)bb * b_bs;
    float* Cb = C + (long)bb * c_bs;
    const int m0 = blockIdx.y * 64, n0 = blockIdx.x * 64;
    const int tid = threadIdx.x;
    const int tx = tid & 15, ty = tid >> 4;
    const int lr = tid >> 2;            // B tile row (n) 0..63
    const int lk = (tid & 3) << 2;      // B k offset
    const int alk = tid >> 4;           // A k row 0..15
    const int alm = (tid & 15) << 2;    // A m offset
    const long brow = (long)(n0 + lr) * b_rs;

    float acc[4][4] = {};
    for (int k0 = 0; k0 < K; k0 += 16) {
        float4 av = *(const float4*)(Ab + (long)(k0 + alk) * a_ks + m0 + alm);
        *(float4*)&As[alk][alm] = av;
        float4 bv = *(const float4*)(Bb + brow + k0 + lk);
        Bs[lk + 0][lr] = bv.x; Bs[lk + 1][lr] = bv.y;
        Bs[lk + 2][lr] = bv.z; Bs[lk + 3][lr] = bv.w;
        __syncthreads();
#pragma unroll
        for (int kk = 0; kk < 16; ++kk) {
            float4 a = *(const float4*)&As[kk][ty << 2];
            float4 b = *(const float4*)&Bs[kk][tx << 2];
            acc[0][0] += a.x * b.x; acc[0][1] += a.x * b.y; acc[0][2] += a.x * b.z; acc[0][3] += a.x * b.w;
            acc[1][0] += a.y * b.x; acc[1][1] += a.y * b.y; acc[1][2] += a.y * b.z; acc[1][3] += a.y * b.w;
            acc[2][0] += a.z * b.x; acc[2][1] += a.z * b.y; acc[2][2] += a.z * b.z; acc[2][3] += a.z * b.w;
            acc[3][0] += a.w * b.x; acc[3][1] += a.w * b.y; acc[3][2] += a.w * b.z; acc[3][3] += a.w * b.w;
        }
        __syncthreads();
    }
#pragma unroll
    for (int i = 0; i < 4; ++i) {
        const int m = m0 + (ty << 2) + i;
#pragma unroll
        for (int j = 0; j < 4; ++j) {
            const int n = n0 + (tx << 2) + j;
            Cb[(long)m * c_rs + n] = acc[i][j];
        }
    }
}

// ---------------------------------------------------------------------------
// Softmax over r (last axis, contiguous, 512 elems): one wave per row, in-place
// ---------------------------------------------------------------------------
__global__ __launch_bounds__(256) void softmax_rows(float* __restrict__ l)
{
    const int lane = threadIdx.x & 63;
    const int wv = threadIdx.x >> 6;
    const long row = (long)blockIdx.x * 4 + wv;
    float* p = l + row * R_;
    float4 v0 = ((const float4*)p)[lane * 2];
    float4 v1 = ((const float4*)p)[lane * 2 + 1];
    float m = fmaxf(fmaxf(fmaxf(v0.x, v0.y), fmaxf(v0.z, v0.w)),
                    fmaxf(fmaxf(v1.x, v1.y), fmaxf(v1.z, v1.w)));
#pragma unroll
    for (int o = 32; o; o >>= 1) m = fmaxf(m, __shfl_xor(m, o));
    v0.x = __expf(v0.x - m); v0.y = __expf(v0.y - m);
    v0.z = __expf(v0.z - m); v0.w = __expf(v0.w - m);
    v1.x = __expf(v1.x - m); v1.y = __expf(v1.y - m);
    v1.z = __expf(v1.z - m); v1.w = __expf(v1.w - m);
    float s = v0.x + v0.y + v0.z + v0.w + v1.x + v1.y + v1.z + v1.w;
#pragma unroll
    for (int o = 32; o; o >>= 1) s += __shfl_xor(s, o);
    const float inv = 1.f / s;
    v0.x *= inv; v0.y *= inv; v0.z *= inv; v0.w *= inv;
    v1.x *= inv; v1.y *= inv; v1.z *= inv; v1.w *= inv;
    ((float4*)p)[lane * 2] = v0;
    ((float4*)p)[lane * 2 + 1] = v1;
}

// ---------------------------------------------------------------------------
// Softmax over s (axis 1, stride R): 512 threads = 128 cols x 4 s-groups
// ---------------------------------------------------------------------------
__global__ __launch_bounds__(512) void softmax_cols(const float* __restrict__ l,
                                                    float* __restrict__ as_)
{
    const int b = blockIdx.y;
    const int rl = threadIdx.x & 127;
    const int r = blockIdx.x * 128 + rl;
    const int sg = threadIdx.x >> 7;           // 0..3
    const int s0 = sg * (S_ / 4), s1 = s0 + S_ / 4;
    const float* base = l + (long)b * S_ * R_ + r;
    __shared__ float red[4][128];

    float pm = -1e30f;
    for (int s = s0; s < s1; ++s) pm = fmaxf(pm, base[(long)s * R_]);
    red[sg][rl] = pm;
    __syncthreads();
    const float m = fmaxf(fmaxf(red[0][rl], red[1][rl]), fmaxf(red[2][rl], red[3][rl]));
    __syncthreads();

    float ps = 0.f;
    for (int s = s0; s < s1; ++s) ps += __expf(base[(long)s * R_] - m);
    red[sg][rl] = ps;
    __syncthreads();
    const float inv = 1.f / (red[0][rl] + red[1][rl] + red[2][rl] + red[3][rl]);

    float* ob = as_ + (long)b * S_ * R_ + r;
    for (int s = s0; s < s1; ++s) ob[(long)s * R_] = __expf(base[(long)s * R_] - m) * inv;
}

// ---------------------------------------------------------------------------
// cat[b][h][s] = h_s[b][s][h]  (s_t half of cat_sc), 32x32 LDS tile transpose
// ---------------------------------------------------------------------------
__global__ __launch_bounds__(256) void transpose_hs(const float* __restrict__ hs,
                                                    float* __restrict__ cat)
{
    __shared__ float tile[32][33];
    const int b = blockIdx.z;
    const int s0 = blockIdx.x * 32, h0 = blockIdx.y * 32;
    const int tx = threadIdx.x, ty = threadIdx.y;
#pragma unroll
    for (int i = 0; i < 32; i += 8)
        tile[ty + i][tx] = hs[((long)b * S_ + s0 + ty + i) * H_ + h0 + tx];
    __syncthreads();
#pragma unroll
    for (int i = 0; i < 32; i += 8)
        cat[((long)b * 2 * H_ + h0 + ty + i) * S_ + s0 + tx] = tile[tx][ty + i];
}

// ---------------------------------------------------------------------------
// bin[t][b][0:1024] = c_r[b][t][:]; bin[t][b][1024:1536] = ref[t][b][:]
// ---------------------------------------------------------------------------
__global__ __launch_bounds__(256) void build_bin(const float* __restrict__ cr,
                                                 const float* __restrict__ ref,
                                                 float* __restrict__ bin)
{
    const long idx4 = (long)blockIdx.x * blockDim.x + threadIdx.x;
    if (idx4 >= (long)R_ * B_ * DIN_ / 4) return;
    const long f = idx4 * 4;
    const int d = (int)(f % DIN_);
    const long tb = f / DIN_;
    const int b = (int)(tb % B_);
    const int t = (int)(tb / B_);
    float4 v;
    if (d < 2 * H_) v = *(const float4*)(cr + ((long)b * R_ + t) * (2 * H_) + d);
    else            v = *(const float4*)(ref + ((long)t * B_ + b) * H_ + (d - 2 * H_));
    *(float4*)(bin + f) = v;
}

// ---------------------------------------------------------------------------
// One-time W_hh transpose + bf16(RTN) pack:
// WB[dir][q2][g] = uint4 of 8 bf16 = Whh_dir[g][8*q2 .. 8*q2+8)
// (k-octet-major: the scan's per-instr wave load is 64 consecutive uint4 =
// coalesced 1 KB). 1 MB total, runs once per launch.
// ---------------------------------------------------------------------------
__device__ inline unsigned pk_bf16(float lo, float hi)
{
    __hip_bfloat16 l = __float2bfloat16(lo);
    __hip_bfloat16 h = __float2bfloat16(hi);
    unsigned short ul, uh;
    __builtin_memcpy(&ul, &l, 2);
    __builtin_memcpy(&uh, &h, 2);
    return (unsigned)ul | ((unsigned)uh << 16);
}

__global__ __launch_bounds__(256) void transpose_w_bf16(
    const float* __restrict__ Whh_f, const float* __restrict__ Whh_b,
    unsigned* __restrict__ WB)
{
    const int g = blockIdx.x * 256 + threadIdx.x;   // 0..1023
    const int q2 = blockIdx.y;                      // 0..31
    const int dir = blockIdx.z;
    const float* W = dir ? Whh_b : Whh_f;
    const float4 a = *(const float4*)(W + (long)g * HD_ + q2 * 8);
    const float4 b = *(const float4*)(W + (long)g * HD_ + q2 * 8 + 4);
    uint4 u;
    u.x = pk_bf16(a.x, a.y);
    u.y = pk_bf16(a.z, a.w);
    u.z = pk_bf16(b.x, b.y);
    u.w = pk_bf16(b.z, b.w);
    *((uint4*)WB + ((long)dir * 32 + q2) * 1024 + g) = u;
}

// ---------------------------------------------------------------------------
// Bi-LSTM scan, BATCH-PARTITIONED (zero cross-block sync), v2:
// R8's miss: W stream is bounded by PER-CU L2 read BW (~150 GB/s), not
// per-XCD; 1 MB fp32/step/CU = 6.7us floor (measured 18 w/ poor batching).
// Fixes: (1) W in bf16 -> 512 KB/step/CU, floor 3.3us. (2) 2 batches per
// block -> each W load feeds 2 FMA streams (compute ~2.6us fills latency
// gaps). (3) 512 threads -> 256-VGPR budget, deep load pipelining.
// Block (dir, bg) handles batches {2bg, 2bg+1}: 16 blocks.
// Thread (ks=tid>>7, go=tid&127): rows {128*ri+go}, k-octets ks*8..ks*8+7.
// h in LDS fp32 (uniform broadcast reads); 4-way k-partials via LDS.
// ---------------------------------------------------------------------------
__device__ inline float sig_(float x) { return 1.f / (1.f + __expf(-x)); }
__device__ inline float tanh_(float x) {
    float ax = fabsf(x);
    float t = 1.f - 2.f / (1.f + __expf(2.f * ax));
    return copysignf(t, x);
}

__global__ __launch_bounds__(512) void lstm_scan_b(
    const float* __restrict__ xg_f, const float* __restrict__ xg_b,
    const unsigned* __restrict__ WBu, float* __restrict__ out)
{
    const int blk = blockIdx.x;
    const int dir = blk >> 3;
    const int b0 = (blk & 7) * 2;
    const float* xg = dir ? xg_b : xg_f;
    const uint4* W = (const uint4*)WBu + (long)dir * 32768;   // 32 q2 x 1024 g

    __shared__ float h_lds[2][256];
    __shared__ float p_lds[4][2][1024];   // [ks][batch][gate] 32 KB

    const int tid = threadIdx.x;
    const int ks = tid >> 7;        // 0..3 (wave-uniform)
    const int go = tid & 127;       // consecutive within wave
    const int cbb = tid >> 8;       // cell batch 0..1
    const int cn = tid & 255;       // cell column

    h_lds[tid >> 8][tid & 255] = 0.f;
    float c_reg = 0.f;
    __syncthreads();

    for (int t = 0; t < R_; ++t) {
        const int tt = dir ? (R_ - 1 - t) : t;
        // prefetch xg (independent of h), coalesced
        const long x0 = ((long)tt * B_ + b0) * G_;
        const long x1 = x0 + G_;
        const float xg00 = xg[x0 + tid];
        const float xg01 = xg[x0 + 512 + tid];
        const float xg10 = xg[x1 + tid];
        const float xg11 = xg[x1 + 512 + tid];

        // dot: 8 rows x 64 k per thread, both batches share every W load
        float acc0[8] = {}, acc1[8] = {};
#pragma unroll
        for (int q = 0; q < 8; ++q) {
            const int q2 = ks * 8 + q;
            const float4 ha0 = *(const float4*)&h_lds[0][q2 * 8];
            const float4 hb0 = *(const float4*)&h_lds[0][q2 * 8 + 4];
            const float4 ha1 = *(const float4*)&h_lds[1][q2 * 8];
            const float4 hb1 = *(const float4*)&h_lds[1][q2 * 8 + 4];
            const uint4* wp = W + q2 * 1024 + go;
#pragma unroll
            for (int ri = 0; ri < 8; ++ri) {
                const uint4 w = wp[ri * 128];
                const float w0 = __uint_as_float(w.x << 16);
                const float w1 = __uint_as_float(w.x & 0xffff0000u);
                const float w2 = __uint_as_float(w.y << 16);
                const float w3 = __uint_as_float(w.y & 0xffff0000u);
                const float w4 = __uint_as_float(w.z << 16);
                const float w5 = __uint_as_float(w.z & 0xffff0000u);
                const float w6 = __uint_as_float(w.w << 16);
                const float w7 = __uint_as_float(w.w & 0xffff0000u);
                acc0[ri] += w0 * ha0.x + w1 * ha0.y + w2 * ha0.z + w3 * ha0.w
                          + w4 * hb0.x + w5 * hb0.y + w6 * hb0.z + w7 * hb0.w;
                acc1[ri] += w0 * ha1.x + w1 * ha1.y + w2 * ha1.z + w3 * ha1.w
                          + w4 * hb1.x + w5 * hb1.y + w6 * hb1.z + w7 * hb1.w;
            }
        }
#pragma unroll
        for (int ri = 0; ri < 8; ++ri) {
            p_lds[ks][0][ri * 128 + go] = acc0[ri];
            p_lds[ks][1][ri * 128 + go] = acc1[ri];
        }
        __syncthreads();

        // reduce 4 k-partials; thread owns columns {tid, 512+tid} x 2 batches
        float g00 = xg00, g01 = xg01, g10 = xg10, g11 = xg11;
#pragma unroll
        for (int k2 = 0; k2 < 4; ++k2) {
            g00 += p_lds[k2][0][tid];
            g01 += p_lds[k2][0][512 + tid];
            g10 += p_lds[k2][1][tid];
            g11 += p_lds[k2][1][512 + tid];
        }
        p_lds[0][0][tid] = g00; p_lds[0][0][512 + tid] = g01;
        p_lds[0][1][tid] = g10; p_lds[0][1][512 + tid] = g11;
        __syncthreads();

        // cell update: thread = (cbb, cn), c in register
        {
            const float iv = p_lds[0][cbb][cn];
            const float fv = p_lds[0][cbb][256 + cn];
            const float gv = p_lds[0][cbb][512 + cn];
            const float ov = p_lds[0][cbb][768 + cn];
            c_reg = sig_(fv) * c_reg + sig_(iv) * tanh_(gv);
            const float h = sig_(ov) * tanh_(c_reg);
            h_lds[cbb][cn] = h;
            out[((long)tt * B_ + b0 + cbb) * (2 * HD_) + dir * HD_ + cn] = h;
        }
        __syncthreads();
    }
}

// ---------------------------------------------------------------------------
extern "C" void kernel_launch(void* const* d_in, const int* in_sizes, int n_in,
                              void* d_out, int out_size, void* d_ws, size_t ws_size,
                              hipStream_t stream)
{
    const float* src  = (const float*)d_in[1];   // [S][B][H]
    const float* ref  = (const float*)d_in[2];   // [R][B][H]
    const float* Wref = (const float*)d_in[3];   // [H][H]
    const float* bref = (const float*)d_in[4];   // [H]
    const float* Wihf = (const float*)d_in[5];   // [G][DIN]
    const float* Whhf = (const float*)d_in[6];   // [G][HD]
    const float* bihf = (const float*)d_in[7];
    const float* bhhf = (const float*)d_in[8];
    const float* Wihb = (const float*)d_in[9];
    const float* Whhb = (const float*)d_in[10];
    const float* bihb = (const float*)d_in[11];
    const float* bhhb = (const float*)d_in[12];
    float* out = (float*)d_out;                  // [R][B][2*HD]

    float* ws = (float*)d_ws;
    // workspace layout (floats), with aliasing:
    float* hs  = ws + 0L;                         // 8388608   [B][S][H]
    float* l   = ws + 8388608L;                   // 8388608   [B][S][R] (a_r in place)
    float* as_ = ws + 16777216L;                  // 8388608   [B][S][R]
    float* cat = ws + 25165824L;                  // 16777216  [B][2H][S]
    float* cr  = hs;                              // 8388608   [B][R][2H]  (hs dead after step 4)
    float* bin = cat;                             // 12582912  [T][B][DIN] (cat dead after step 6)
    float* xgf = l;                               // 8388608   [T][B][G]   (l dead after step 6)
    float* xgb = as_;                             // 8388608   [T][B][G]   (as_ dead after step 5)
    unsigned* WB = (unsigned*)(ws + 41943040L);   // 262144 u32: 2 dir x 32 q2 x 1024 g x uint4

    // 0) one-time W_hh transpose + bf16 pack
    transpose_w_bf16<<<dim3(4, 32, 2), 256, 0, stream>>>(Whhf, Whhb, WB);

    // 1) h_s = tanh(src . Wref^T + bref)   [B*S, 512] k=512
    gemm_mk_nk<1, 1><<<dim3(8, 256, 1), 256, 0, stream>>>(
        src, H_, 0, Wref, H_, 0, hs, H_, 0, bref, nullptr, B_ * S_, H_, H_);

    // 2) l[b] = h_s[b] . h_r[b]^T   M=1024 N=512 K=512, batched over b
    gemm_mk_nk<0, 0><<<dim3(8, 16, B_), 256, 0, stream>>>(
        hs, H_, (long)S_ * H_, ref, (long)B_ * H_, H_, l, R_, (long)S_ * R_,
        nullptr, nullptr, S_, R_, H_);

    // 3) a_s = softmax over s (columns), then a_r = softmax over r in place
    softmax_cols<<<dim3(R_ / 128, B_), 512, 0, stream>>>(l, as_);
    softmax_rows<<<(B_ * S_) / 4, 256, 0, stream>>>(l);

    // 4) cat rows 0..511 = h_s transposed
    transpose_hs<<<dim3(S_ / 32, H_ / 32, B_), dim3(32, 8), 0, stream>>>(hs, cat);

    // 5) cat rows 512..1023: c_s[b,h,s] = sum_r ref[r,b,h]*a_s[b,s,r]
    gemm_km_nk<<<dim3(16, 8, B_), 256, 0, stream>>>(
        ref, (long)B_ * H_, H_, as_, R_, (long)S_ * R_,
        cat + (long)H_ * S_, S_, (long)2 * H_ * S_, H_, S_, R_);

    // 6) c_r[b,r,k] = sum_s cat[b,k,s]*a_r[b,s,r]   M=512 N=1024 K=1024
    gemm_km_nk<<<dim3(16, 8, B_), 256, 0, stream>>>(
        l, R_, (long)S_ * R_, cat, S_, (long)2 * H_ * S_,
        cr, 2 * H_, (long)R_ * 2 * H_, R_, 2 * H_, S_);

    // 7) bilstm_in
    build_bin<<<(R_ * B_ * DIN_ / 4 + 255) / 256, 256, 0, stream>>>(cr, ref, bin);

    // 8) xg = bin . W_ih^T + b_ih + b_hh  (both directions)
    gemm_mk_nk<2, 0><<<dim3(16, 128, 1), 256, 0, stream>>>(
        bin, DIN_, 0, Wihf, DIN_, 0, xgf, G_, 0, bihf, bhhf, R_ * B_, G_, DIN_);
    gemm_mk_nk<2, 0><<<dim3(16, 128, 1), 256, 0, stream>>>(
        bin, DIN_, 0, Wihb, DIN_, 0, xgb, G_, 0, bihb, bhhb, R_ * B_, G_, DIN_);

    // 9) bi-LSTM scan: 16 independent (dir, batch-pair) blocks, zero sync
    lstm_scan_b<<<dim3(16), dim3(512), 0, stream>>>(xgf, xgb, WB, out);
}

// Round 10
// 6818.234 us; speedup vs baseline: 1.5918x; 1.0420x over previous
//
#include <hip/hip_runtime.h>
#include <hip/hip_bf16.h>
#include <math.h>

#define B_   16
#define S_   1024
#define R_   512
#define H_   512
#define HD_  256
#define G_   1024
#define DIN_ 1536

// ---------------------------------------------------------------------------
// Tiled fp32 GEMM:  C[m][n] = sum_k A(m,k) * B(n,k)
// ---------------------------------------------------------------------------
template<int EPI, int REMAP_A>
__global__ __launch_bounds__(256) void gemm_mk_nk(
    const float* __restrict__ A, long a_rs, long a_bs,
    const float* __restrict__ Bm, long b_rs, long b_bs,
    float* __restrict__ C, long c_rs, long c_bs,
    const float* __restrict__ bias, const float* __restrict__ bias2,
    int M, int N, int K)
{
    __shared__ float As[16][68];
    __shared__ float Bs[16][68];
    const int bb = blockIdx.z;
    const float* Ab = A + (long)bb * a_bs;
    const float* Bb = Bm + (long)bb * b_bs;
    float* Cb = C + (long)bb * c_bs;
    const int m0 = blockIdx.y * 64, n0 = blockIdx.x * 64;
    const int tid = threadIdx.x;
    const int tx = tid & 15, ty = tid >> 4;
    const int lr = tid >> 2;          // tile row 0..63
    const int lk = (tid & 3) << 2;    // k offset 0..12

    long arow;
    {
        int m = m0 + lr;
        if (REMAP_A) arow = (long)((m % S_) * B_ + (m / S_)) * a_rs;
        else         arow = (long)m * a_rs;
    }
    const long brow = (long)(n0 + lr) * b_rs;

    float acc[4][4] = {};
    for (int k0 = 0; k0 < K; k0 += 16) {
        float4 av = *(const float4*)(Ab + arow + k0 + lk);
        float4 bv = *(const float4*)(Bb + brow + k0 + lk);
        As[lk + 0][lr] = av.x; As[lk + 1][lr] = av.y;
        As[lk + 2][lr] = av.z; As[lk + 3][lr] = av.w;
        Bs[lk + 0][lr] = bv.x; Bs[lk + 1][lr] = bv.y;
        Bs[lk + 2][lr] = bv.z; Bs[lk + 3][lr] = bv.w;
        __syncthreads();
#pragma unroll
        for (int kk = 0; kk < 16; ++kk) {
            float4 a = *(const float4*)&As[kk][ty << 2];
            float4 b = *(const float4*)&Bs[kk][tx << 2];
            acc[0][0] += a.x * b.x; acc[0][1] += a.x * b.y; acc[0][2] += a.x * b.z; acc[0][3] += a.x * b.w;
            acc[1][0] += a.y * b.x; acc[1][1] += a.y * b.y; acc[1][2] += a.y * b.z; acc[1][3] += a.y * b.w;
            acc[2][0] += a.z * b.x; acc[2][1] += a.z * b.y; acc[2][2] += a.z * b.z; acc[2][3] += a.z * b.w;
            acc[3][0] += a.w * b.x; acc[3][1] += a.w * b.y; acc[3][2] += a.w * b.z; acc[3][3] += a.w * b.w;
        }
        __syncthreads();
    }
#pragma unroll
    for (int i = 0; i < 4; ++i) {
        const int m = m0 + (ty << 2) + i;
#pragma unroll
        for (int j = 0; j < 4; ++j) {
            const int n = n0 + (tx << 2) + j;
            float v = acc[i][j];
            if (EPI == 1) v = tanhf(v + bias[n]);
            else if (EPI == 2) v += bias[n] + bias2[n];
            Cb[(long)m * c_rs + n] = v;
        }
    }
}

// ---------------------------------------------------------------------------
// Tiled fp32 GEMM:  C[m][n] = sum_k A(k,m) * B(n,k)
// ---------------------------------------------------------------------------
__global__ __launch_bounds__(256) void gemm_km_nk(
    const float* __restrict__ A, long a_ks, long a_bs,
    const float* __restrict__ Bm, long b_rs, long b_bs,
    float* __restrict__ C, long c_rs, long c_bs,
    int M, int N, int K)
{
    __shared__ float As[16][68];
    __shared__ float Bs[16][68];
    const int bb = blockIdx.z;
    const float* Ab = A + (long)bb * a_bs;
    const float* Bb = Bm + (long)bb * b_bs;
    float* Cb = C + (long)bb * c_bs;
    const int m0 = blockIdx.y * 64, n0 = blockIdx.x * 64;
    const int tid = threadIdx.x;
    const int tx = tid & 15, ty = tid >> 4;
    const int lr = tid >> 2;            // B tile row (n) 0..63
    const int lk = (tid & 3) << 2;      // B k offset
    const int alk = tid >> 4;           // A k row 0..15
    const int alm = (tid & 15) << 2;    // A m offset
    const long brow = (long)(n0 + lr) * b_rs;

    float acc[4][4] = {};
    for (int k0 = 0; k0 < K; k0 += 16) {
        float4 av = *(const float4*)(Ab + (long)(k0 + alk) * a_ks + m0 + alm);
        *(float4*)&As[alk][alm] = av;
        float4 bv = *(const float4*)(Bb + brow + k0 + lk);
        Bs[lk + 0][lr] = bv.x; Bs[lk + 1][lr] = bv.y;
        Bs[lk + 2][lr] = bv.z; Bs[lk + 3][lr] = bv.w;
        __syncthreads();
#pragma unroll
        for (int kk = 0; kk < 16; ++kk) {
            float4 a = *(const float4*)&As[kk][ty << 2];
            float4 b = *(const float4*)&Bs[kk][tx << 2];
            acc[0][0] += a.x * b.x; acc[0][1] += a.x * b.y; acc[0][2] += a.x * b.z; acc[0][3] += a.x * b.w;
            acc[1][0] += a.y * b.x; acc[1][1] += a.y * b.y; acc[1][2] += a.y * b.z; acc[1][3] += a.y * b.w;
            acc[2][0] += a.z * b.x; acc[2][1] += a.z * b.y; acc[2][2] += a.z * b.z; acc[2][3] += a.z * b.w;
            acc[3][0] += a.w * b.x; acc[3][1] += a.w * b.y; acc[3][2] += a.w * b.z; acc[3][3] += a.w * b.w;
        }
        __syncthreads();
    }
#pragma unroll
    for (int i = 0; i < 4; ++i) {
        const int m = m0 + (ty << 2) + i;
#pragma unroll
        for (int j = 0; j < 4; ++j) {
            const int n = n0 + (tx << 2) + j;
            Cb[(long)m * c_rs + n] = acc[i][j];
        }
    }
}

// ---------------------------------------------------------------------------
// Softmax over r (last axis, contiguous, 512 elems): one wave per row, in-place
// ---------------------------------------------------------------------------
__global__ __launch_bounds__(256) void softmax_rows(float* __restrict__ l)
{
    const int lane = threadIdx.x & 63;
    const int wv = threadIdx.x >> 6;
    const long row = (long)blockIdx.x * 4 + wv;
    float* p = l + row * R_;
    float4 v0 = ((const float4*)p)[lane * 2];
    float4 v1 = ((const float4*)p)[lane * 2 + 1];
    float m = fmaxf(fmaxf(fmaxf(v0.x, v0.y), fmaxf(v0.z, v0.w)),
                    fmaxf(fmaxf(v1.x, v1.y), fmaxf(v1.z, v1.w)));
#pragma unroll
    for (int o = 32; o; o >>= 1) m = fmaxf(m, __shfl_xor(m, o));
    v0.x = __expf(v0.x - m); v0.y = __expf(v0.y - m);
    v0.z = __expf(v0.z - m); v0.w = __expf(v0.w - m);
    v1.x = __expf(v1.x - m); v1.y = __expf(v1.y - m);
    v1.z = __expf(v1.z - m); v1.w = __expf(v1.w - m);
    float s = v0.x + v0.y + v0.z + v0.w + v1.x + v1.y + v1.z + v1.w;
#pragma unroll
    for (int o = 32; o; o >>= 1) s += __shfl_xor(s, o);
    const float inv = 1.f / s;
    v0.x *= inv; v0.y *= inv; v0.z *= inv; v0.w *= inv;
    v1.x *= inv; v1.y *= inv; v1.z *= inv; v1.w *= inv;
    ((float4*)p)[lane * 2] = v0;
    ((float4*)p)[lane * 2 + 1] = v1;
}

// ---------------------------------------------------------------------------
// Softmax over s (axis 1, stride R): 512 threads = 128 cols x 4 s-groups
// ---------------------------------------------------------------------------
__global__ __launch_bounds__(512) void softmax_cols(const float* __restrict__ l,
                                                    float* __restrict__ as_)
{
    const int b = blockIdx.y;
    const int rl = threadIdx.x & 127;
    const int r = blockIdx.x * 128 + rl;
    const int sg = threadIdx.x >> 7;           // 0..3
    const int s0 = sg * (S_ / 4), s1 = s0 + S_ / 4;
    const float* base = l + (long)b * S_ * R_ + r;
    __shared__ float red[4][128];

    float pm = -1e30f;
    for (int s = s0; s < s1; ++s) pm = fmaxf(pm, base[(long)s * R_]);
    red[sg][rl] = pm;
    __syncthreads();
    const float m = fmaxf(fmaxf(red[0][rl], red[1][rl]), fmaxf(red[2][rl], red[3][rl]));
    __syncthreads();

    float ps = 0.f;
    for (int s = s0; s < s1; ++s) ps += __expf(base[(long)s * R_] - m);
    red[sg][rl] = ps;
    __syncthreads();
    const float inv = 1.f / (red[0][rl] + red[1][rl] + red[2][rl] + red[3][rl]);

    float* ob = as_ + (long)b * S_ * R_ + r;
    for (int s = s0; s < s1; ++s) ob[(long)s * R_] = __expf(base[(long)s * R_] - m) * inv;
}

// ---------------------------------------------------------------------------
// cat[b][h][s] = h_s[b][s][h]  (s_t half of cat_sc), 32x32 LDS tile transpose
// ---------------------------------------------------------------------------
__global__ __launch_bounds__(256) void transpose_hs(const float* __restrict__ hs,
                                                    float* __restrict__ cat)
{
    __shared__ float tile[32][33];
    const int b = blockIdx.z;
    const int s0 = blockIdx.x * 32, h0 = blockIdx.y * 32;
    const int tx = threadIdx.x, ty = threadIdx.y;
#pragma unroll
    for (int i = 0; i < 32; i += 8)
        tile[ty + i][tx] = hs[((long)b * S_ + s0 + ty + i) * H_ + h0 + tx];
    __syncthreads();
#pragma unroll
    for (int i = 0; i < 32; i += 8)
        cat[((long)b * 2 * H_ + h0 + ty + i) * S_ + s0 + tx] = tile[tx][ty + i];
}

// ---------------------------------------------------------------------------
// bin[t][b][0:1024] = c_r[b][t][:]; bin[t][b][1024:1536] = ref[t][b][:]
// ---------------------------------------------------------------------------
__global__ __launch_bounds__(256) void build_bin(const float* __restrict__ cr,
                                                 const float* __restrict__ ref,
                                                 float* __restrict__ bin)
{
    const long idx4 = (long)blockIdx.x * blockDim.x + threadIdx.x;
    if (idx4 >= (long)R_ * B_ * DIN_ / 4) return;
    const long f = idx4 * 4;
    const int d = (int)(f % DIN_);
    const long tb = f / DIN_;
    const int b = (int)(tb % B_);
    const int t = (int)(tb / B_);
    float4 v;
    if (d < 2 * H_) v = *(const float4*)(cr + ((long)b * R_ + t) * (2 * H_) + d);
    else            v = *(const float4*)(ref + ((long)t * B_ + b) * H_ + (d - 2 * H_));
    *(float4*)(bin + f) = v;
}

// ---------------------------------------------------------------------------
// One-time W_hh transpose + bf16(RTN) pack:
// WB[dir][q2][g] = uint4 of 8 bf16 = Whh_dir[g][8*q2 .. 8*q2+8)
// ---------------------------------------------------------------------------
__device__ inline unsigned pk_bf16(float lo, float hi)
{
    __hip_bfloat16 l = __float2bfloat16(lo);
    __hip_bfloat16 h = __float2bfloat16(hi);
    unsigned short ul, uh;
    __builtin_memcpy(&ul, &l, 2);
    __builtin_memcpy(&uh, &h, 2);
    return (unsigned)ul | ((unsigned)uh << 16);
}

__global__ __launch_bounds__(256) void transpose_w_bf16(
    const float* __restrict__ Whh_f, const float* __restrict__ Whh_b,
    unsigned* __restrict__ WB)
{
    const int g = blockIdx.x * 256 + threadIdx.x;   // 0..1023
    const int q2 = blockIdx.y;                      // 0..31
    const int dir = blockIdx.z;
    const float* W = dir ? Whh_b : Whh_f;
    const float4 a = *(const float4*)(W + (long)g * HD_ + q2 * 8);
    const float4 b = *(const float4*)(W + (long)g * HD_ + q2 * 8 + 4);
    uint4 u;
    u.x = pk_bf16(a.x, a.y);
    u.y = pk_bf16(a.z, a.w);
    u.z = pk_bf16(b.x, b.y);
    u.w = pk_bf16(b.z, b.w);
    *((uint4*)WB + ((long)dir * 32 + q2) * 1024 + g) = u;
}

// ---------------------------------------------------------------------------
// Bi-LSTM scan, BATCH-PARTITIONED (zero cross-block sync), v3:
// R9's 10.9us/step was phase SERIALIZATION (dot|reduce|cell, 3 barriers, L2
// latency exposed inside dot at 2 waves/SIMD). v3:
//   (1) reduce fused into cell: 3 barriers -> 2, p_lds round-trip removed
//   (2) explicit 2-deep W register double-buffer (wa/wb, static indices):
//       every FMA chunk runs with the next 8 loads in flight
//   (3) cross-step prefetch: W addrs are step-invariant, so step t+1's first
//       8 loads issue during step t's cell phase
//   (4) __launch_bounds__(512,2): 256-VGPR budget for the 64-reg W buffers
// Block (dir, bg) = batches {2bg, 2bg+1}; thread (ks=tid>>7, go=tid&127)
// owns rows {128*ri+go : ri<8}, k-octets ks*8..ks*8+7; cell thread
// (cbb=tid>>8, cn=tid&255) sums 4 k-partials per gate directly.
// ---------------------------------------------------------------------------
__device__ inline float sig_(float x) { return 1.f / (1.f + __expf(-x)); }
__device__ inline float tanh_(float x) {
    float ax = fabsf(x);
    float t = 1.f - 2.f / (1.f + __expf(2.f * ax));
    return copysignf(t, x);
}

#define LOADW(buf, qrel)                                                      \
    {                                                                         \
        const uint4* wp_ = wbase + (qrel) * 1024;                             \
        _Pragma("unroll")                                                     \
        for (int r_ = 0; r_ < 8; ++r_) buf[r_] = wp_[r_ * 128];               \
    }

#define COMPUTE(buf, qrel)                                                    \
    {                                                                         \
        const int qq_ = ks * 8 + (qrel);                                      \
        const float4 ha0 = *(const float4*)&h_lds[0][qq_ * 8];                \
        const float4 hb0 = *(const float4*)&h_lds[0][qq_ * 8 + 4];            \
        const float4 ha1 = *(const float4*)&h_lds[1][qq_ * 8];                \
        const float4 hb1 = *(const float4*)&h_lds[1][qq_ * 8 + 4];            \
        _Pragma("unroll")                                                     \
        for (int ri_ = 0; ri_ < 8; ++ri_) {                                   \
            const uint4 w = buf[ri_];                                         \
            const float w0 = __uint_as_float(w.x << 16);                      \
            const float w1 = __uint_as_float(w.x & 0xffff0000u);              \
            const float w2 = __uint_as_float(w.y << 16);                      \
            const float w3 = __uint_as_float(w.y & 0xffff0000u);              \
            const float w4 = __uint_as_float(w.z << 16);                      \
            const float w5 = __uint_as_float(w.z & 0xffff0000u);              \
            const float w6 = __uint_as_float(w.w << 16);                      \
            const float w7 = __uint_as_float(w.w & 0xffff0000u);              \
            acc0[ri_] += w0 * ha0.x + w1 * ha0.y + w2 * ha0.z + w3 * ha0.w    \
                       + w4 * hb0.x + w5 * hb0.y + w6 * hb0.z + w7 * hb0.w;   \
            acc1[ri_] += w0 * ha1.x + w1 * ha1.y + w2 * ha1.z + w3 * ha1.w    \
                       + w4 * hb1.x + w5 * hb1.y + w6 * hb1.z + w7 * hb1.w;   \
        }                                                                     \
    }

__global__ __launch_bounds__(512, 2) void lstm_scan_b(
    const float* __restrict__ xg_f, const float* __restrict__ xg_b,
    const unsigned* __restrict__ WBu, float* __restrict__ out)
{
    const int blk = blockIdx.x;
    const int dir = blk >> 3;
    const int b0 = (blk & 7) * 2;
    const float* xg = dir ? xg_b : xg_f;
    const uint4* W = (const uint4*)WBu + (long)dir * 32768;   // 32 q2 x 1024 g

    __shared__ float h_lds[2][256];
    __shared__ float p_lds[4][2][1024];   // [ks][batch][gate] 32 KB

    const int tid = threadIdx.x;
    const int ks = tid >> 7;        // 0..3 (wave-uniform)
    const int go = tid & 127;       // consecutive within wave
    const int cbb = tid >> 8;       // cell batch 0..1
    const int cn = tid & 255;       // cell column

    h_lds[tid >> 8][tid & 255] = 0.f;
    float c_reg = 0.f;
    __syncthreads();

    const uint4* wbase = W + (ks * 8) * 1024 + go;
    uint4 wa[8], wb[8];
    LOADW(wa, 0);   // prologue: q2-rel 0 in flight before first step

    for (int t = 0; t < R_; ++t) {
        const int tt = dir ? (R_ - 1 - t) : t;
        // xg for the cell phase: 4 gates of column cn, batch b0+cbb
        const long xb = ((long)tt * B_ + b0 + cbb) * G_ + cn;
        const float xgi = xg[xb];
        const float xgf2 = xg[xb + 256];
        const float xgg = xg[xb + 512];
        const float xgo = xg[xb + 768];

        float acc0[8] = {}, acc1[8] = {};
#pragma unroll
        for (int q = 0; q < 8; q += 2) {
            if (q + 1 < 8) LOADW(wb, q + 1);
            COMPUTE(wa, q);
            if (q + 2 < 8) LOADW(wa, q + 2);
            if (q + 1 < 8) COMPUTE(wb, q + 1);
        }
#pragma unroll
        for (int ri = 0; ri < 8; ++ri) {
            p_lds[ks][0][ri * 128 + go] = acc0[ri];
            p_lds[ks][1][ri * 128 + go] = acc1[ri];
        }
        __syncthreads();

        LOADW(wa, 0);   // prefetch next step's first W batch under cell phase

        // fused reduce + cell update: thread = (cbb, cn)
        {
            float iv = xgi, fv = xgf2, gv = xgg, ov = xgo;
#pragma unroll
            for (int k2 = 0; k2 < 4; ++k2) {
                iv += p_lds[k2][cbb][cn];
                fv += p_lds[k2][cbb][256 + cn];
                gv += p_lds[k2][cbb][512 + cn];
                ov += p_lds[k2][cbb][768 + cn];
            }
            c_reg = sig_(fv) * c_reg + sig_(iv) * tanh_(gv);
            const float h = sig_(ov) * tanh_(c_reg);
            h_lds[cbb][cn] = h;
            out[((long)tt * B_ + b0 + cbb) * (2 * HD_) + dir * HD_ + cn] = h;
        }
        __syncthreads();
    }
}

// ---------------------------------------------------------------------------
extern "C" void kernel_launch(void* const* d_in, const int* in_sizes, int n_in,
                              void* d_out, int out_size, void* d_ws, size_t ws_size,
                              hipStream_t stream)
{
    const float* src  = (const float*)d_in[1];   // [S][B][H]
    const float* ref  = (const float*)d_in[2];   // [R][B][H]
    const float* Wref = (const float*)d_in[3];   // [H][H]
    const float* bref = (const float*)d_in[4];   // [H]
    const float* Wihf = (const float*)d_in[5];   // [G][DIN]
    const float* Whhf = (const float*)d_in[6];   // [G][HD]
    const float* bihf = (const float*)d_in[7];
    const float* bhhf = (const float*)d_in[8];
    const float* Wihb = (const float*)d_in[9];
    const float* Whhb = (const float*)d_in[10];
    const float* bihb = (const float*)d_in[11];
    const float* bhhb = (const float*)d_in[12];
    float* out = (float*)d_out;                  // [R][B][2*HD]

    float* ws = (float*)d_ws;
    // workspace layout (floats), with aliasing:
    float* hs  = ws + 0L;                         // 8388608   [B][S][H]
    float* l   = ws + 8388608L;                   // 8388608   [B][S][R] (a_r in place)
    float* as_ = ws + 16777216L;                  // 8388608   [B][S][R]
    float* cat = ws + 25165824L;                  // 16777216  [B][2H][S]
    float* cr  = hs;                              // 8388608   [B][R][2H]  (hs dead after step 4)
    float* bin = cat;                             // 12582912  [T][B][DIN] (cat dead after step 6)
    float* xgf = l;                               // 8388608   [T][B][G]   (l dead after step 6)
    float* xgb = as_;                             // 8388608   [T][B][G]   (as_ dead after step 5)
    unsigned* WB = (unsigned*)(ws + 41943040L);   // 262144 u32: 2 dir x 32 q2 x 1024 g x uint4

    // 0) one-time W_hh transpose + bf16 pack
    transpose_w_bf16<<<dim3(4, 32, 2), 256, 0, stream>>>(Whhf, Whhb, WB);

    // 1) h_s = tanh(src . Wref^T + bref)   [B*S, 512] k=512
    gemm_mk_nk<1, 1><<<dim3(8, 256, 1), 256, 0, stream>>>(
        src, H_, 0, Wref, H_, 0, hs, H_, 0, bref, nullptr, B_ * S_, H_, H_);

    // 2) l[b] = h_s[b] . h_r[b]^T   M=1024 N=512 K=512, batched over b
    gemm_mk_nk<0, 0><<<dim3(8, 16, B_), 256, 0, stream>>>(
        hs, H_, (long)S_ * H_, ref, (long)B_ * H_, H_, l, R_, (long)S_ * R_,
        nullptr, nullptr, S_, R_, H_);

    // 3) a_s = softmax over s (columns), then a_r = softmax over r in place
    softmax_cols<<<dim3(R_ / 128, B_), 512, 0, stream>>>(l, as_);
    softmax_rows<<<(B_ * S_) / 4, 256, 0, stream>>>(l);

    // 4) cat rows 0..511 = h_s transposed
    transpose_hs<<<dim3(S_ / 32, H_ / 32, B_), dim3(32, 8), 0, stream>>>(hs, cat);

    // 5) cat rows 512..1023: c_s[b,h,s] = sum_r ref[r,b,h]*a_s[b,s,r]
    gemm_km_nk<<<dim3(16, 8, B_), 256, 0, stream>>>(
        ref, (long)B_ * H_, H_, as_, R_, (long)S_ * R_,
        cat + (long)H_ * S_, S_, (long)2 * H_ * S_, H_, S_, R_);

    // 6) c_r[b,r,k] = sum_s cat[b,k,s]*a_r[b,s,r]   M=512 N=1024 K=1024
    gemm_km_nk<<<dim3(16, 8, B_), 256, 0, stream>>>(
        l, R_, (long)S_ * R_, cat, S_, (long)2 * H_ * S_,
        cr, 2 * H_, (long)R_ * 2 * H_, R_, 2 * H_, S_);

    // 7) bilstm_in
    build_bin<<<(R_ * B_ * DIN_ / 4 + 255) / 256, 256, 0, stream>>>(cr, ref, bin);

    // 8) xg = bin . W_ih^T + b_ih + b_hh  (both directions)
    gemm_mk_nk<2, 0><<<dim3(16, 128, 1), 256, 0, stream>>>(
        bin, DIN_, 0, Wihf, DIN_, 0, xgf, G_, 0, bihf, bhhf, R_ * B_, G_, DIN_);
    gemm_mk_nk<2, 0><<<dim3(16, 128, 1), 256, 0, stream>>>(
        bin, DIN_, 0, Wihb, DIN_, 0, xgb, G_, 0, bihb, bhhb, R_ * B_, G_, DIN_);

    // 9) bi-LSTM scan: 16 independent (dir, batch-pair) blocks, zero sync
    lstm_scan_b<<<dim3(16), dim3(512), 0, stream>>>(xgf, xgb, WB, out);
}

// Round 12
// 6520.879 us; speedup vs baseline: 1.6644x; 1.0456x over previous
//
#include <hip/hip_runtime.h>
#include <hip/hip_bf16.h>
#include <math.h>

#define B_   16
#define S_   1024
#define R_   512
#define H_   512
#define HD_  256
#define G_   1024
#define DIN_ 1536

// ---------------------------------------------------------------------------
// Tiled fp32 GEMM:  C[m][n] = sum_k A(m,k) * B(n,k)
// ---------------------------------------------------------------------------
template<int EPI, int REMAP_A>
__global__ __launch_bounds__(256) void gemm_mk_nk(
    const float* __restrict__ A, long a_rs, long a_bs,
    const float* __restrict__ Bm, long b_rs, long b_bs,
    float* __restrict__ C, long c_rs, long c_bs,
    const float* __restrict__ bias, const float* __restrict__ bias2,
    int M, int N, int K)
{
    __shared__ float As[16][68];
    __shared__ float Bs[16][68];
    const int bb = blockIdx.z;
    const float* Ab = A + (long)bb * a_bs;
    const float* Bb = Bm + (long)bb * b_bs;
    float* Cb = C + (long)bb * c_bs;
    const int m0 = blockIdx.y * 64, n0 = blockIdx.x * 64;
    const int tid = threadIdx.x;
    const int tx = tid & 15, ty = tid >> 4;
    const int lr = tid >> 2;          // tile row 0..63
    const int lk = (tid & 3) << 2;    // k offset 0..12

    long arow;
    {
        int m = m0 + lr;
        if (REMAP_A) arow = (long)((m % S_) * B_ + (m / S_)) * a_rs;
        else         arow = (long)m * a_rs;
    }
    const long brow = (long)(n0 + lr) * b_rs;

    float acc[4][4] = {};
    for (int k0 = 0; k0 < K; k0 += 16) {
        float4 av = *(const float4*)(Ab + arow + k0 + lk);
        float4 bv = *(const float4*)(Bb + brow + k0 + lk);
        As[lk + 0][lr] = av.x; As[lk + 1][lr] = av.y;
        As[lk + 2][lr] = av.z; As[lk + 3][lr] = av.w;
        Bs[lk + 0][lr] = bv.x; Bs[lk + 1][lr] = bv.y;
        Bs[lk + 2][lr] = bv.z; Bs[lk + 3][lr] = bv.w;
        __syncthreads();
#pragma unroll
        for (int kk = 0; kk < 16; ++kk) {
            float4 a = *(const float4*)&As[kk][ty << 2];
            float4 b = *(const float4*)&Bs[kk][tx << 2];
            acc[0][0] += a.x * b.x; acc[0][1] += a.x * b.y; acc[0][2] += a.x * b.z; acc[0][3] += a.x * b.w;
            acc[1][0] += a.y * b.x; acc[1][1] += a.y * b.y; acc[1][2] += a.y * b.z; acc[1][3] += a.y * b.w;
            acc[2][0] += a.z * b.x; acc[2][1] += a.z * b.y; acc[2][2] += a.z * b.z; acc[2][3] += a.z * b.w;
            acc[3][0] += a.w * b.x; acc[3][1] += a.w * b.y; acc[3][2] += a.w * b.z; acc[3][3] += a.w * b.w;
        }
        __syncthreads();
    }
#pragma unroll
    for (int i = 0; i < 4; ++i) {
        const int m = m0 + (ty << 2) + i;
#pragma unroll
        for (int j = 0; j < 4; ++j) {
            const int n = n0 + (tx << 2) + j;
            float v = acc[i][j];
            if (EPI == 1) v = tanhf(v + bias[n]);
            else if (EPI == 2) v += bias[n] + bias2[n];
            Cb[(long)m * c_rs + n] = v;
        }
    }
}

// ---------------------------------------------------------------------------
// Tiled fp32 GEMM:  C[m][n] = sum_k A(k,m) * B(n,k)
// ---------------------------------------------------------------------------
__global__ __launch_bounds__(256) void gemm_km_nk(
    const float* __restrict__ A, long a_ks, long a_bs,
    const float* __restrict__ Bm, long b_rs, long b_bs,
    float* __restrict__ C, long c_rs, long c_bs,
    int M, int N, int K)
{
    __shared__ float As[16][68];
    __shared__ float Bs[16][68];
    const int bb = blockIdx.z;
    const float* Ab = A + (long)bb * a_bs;
    const float* Bb = Bm + (long)bb * b_bs;
    float* Cb = C + (long)bb * c_bs;
    const int m0 = blockIdx.y * 64, n0 = blockIdx.x * 64;
    const int tid = threadIdx.x;
    const int tx = tid & 15, ty = tid >> 4;
    const int lr = tid >> 2;            // B tile row (n) 0..63
    const int lk = (tid & 3) << 2;      // B k offset
    const int alk = tid >> 4;           // A k row 0..15
    const int alm = (tid & 15) << 2;    // A m offset
    const long brow = (long)(n0 + lr) * b_rs;

    float acc[4][4] = {};
    for (int k0 = 0; k0 < K; k0 += 16) {
        float4 av = *(const float4*)(Ab + (long)(k0 + alk) * a_ks + m0 + alm);
        *(float4*)&As[alk][alm] = av;
        float4 bv = *(const float4*)(Bb + brow + k0 + lk);
        Bs[lk + 0][lr] = bv.x; Bs[lk + 1][lr] = bv.y;
        Bs[lk + 2][lr] = bv.z; Bs[lk + 3][lr] = bv.w;
        __syncthreads();
#pragma unroll
        for (int kk = 0; kk < 16; ++kk) {
            float4 a = *(const float4*)&As[kk][ty << 2];
            float4 b = *(const float4*)&Bs[kk][tx << 2];
            acc[0][0] += a.x * b.x; acc[0][1] += a.x * b.y; acc[0][2] += a.x * b.z; acc[0][3] += a.x * b.w;
            acc[1][0] += a.y * b.x; acc[1][1] += a.y * b.y; acc[1][2] += a.y * b.z; acc[1][3] += a.y * b.w;
            acc[2][0] += a.z * b.x; acc[2][1] += a.z * b.y; acc[2][2] += a.z * b.z; acc[2][3] += a.z * b.w;
            acc[3][0] += a.w * b.x; acc[3][1] += a.w * b.y; acc[3][2] += a.w * b.z; acc[3][3] += a.w * b.w;
        }
        __syncthreads();
    }
#pragma unroll
    for (int i = 0; i < 4; ++i) {
        const int m = m0 + (ty << 2) + i;
#pragma unroll
        for (int j = 0; j < 4; ++j) {
            const int n = n0 + (tx << 2) + j;
            Cb[(long)m * c_rs + n] = acc[i][j];
        }
    }
}

// ---------------------------------------------------------------------------
// Softmax over r (last axis, contiguous, 512 elems): one wave per row, in-place
// ---------------------------------------------------------------------------
__global__ __launch_bounds__(256) void softmax_rows(float* __restrict__ l)
{
    const int lane = threadIdx.x & 63;
    const int wv = threadIdx.x >> 6;
    const long row = (long)blockIdx.x * 4 + wv;
    float* p = l + row * R_;
    float4 v0 = ((const float4*)p)[lane * 2];
    float4 v1 = ((const float4*)p)[lane * 2 + 1];
    float m = fmaxf(fmaxf(fmaxf(v0.x, v0.y), fmaxf(v0.z, v0.w)),
                    fmaxf(fmaxf(v1.x, v1.y), fmaxf(v1.z, v1.w)));
#pragma unroll
    for (int o = 32; o; o >>= 1) m = fmaxf(m, __shfl_xor(m, o));
    v0.x = __expf(v0.x - m); v0.y = __expf(v0.y - m);
    v0.z = __expf(v0.z - m); v0.w = __expf(v0.w - m);
    v1.x = __expf(v1.x - m); v1.y = __expf(v1.y - m);
    v1.z = __expf(v1.z - m); v1.w = __expf(v1.w - m);
    float s = v0.x + v0.y + v0.z + v0.w + v1.x + v1.y + v1.z + v1.w;
#pragma unroll
    for (int o = 32; o; o >>= 1) s += __shfl_xor(s, o);
    const float inv = 1.f / s;
    v0.x *= inv; v0.y *= inv; v0.z *= inv; v0.w *= inv;
    v1.x *= inv; v1.y *= inv; v1.z *= inv; v1.w *= inv;
    ((float4*)p)[lane * 2] = v0;
    ((float4*)p)[lane * 2 + 1] = v1;
}

// ---------------------------------------------------------------------------
// Softmax over s (axis 1, stride R): 512 threads = 128 cols x 4 s-groups
// ---------------------------------------------------------------------------
__global__ __launch_bounds__(512) void softmax_cols(const float* __restrict__ l,
                                                    float* __restrict__ as_)
{
    const int b = blockIdx.y;
    const int rl = threadIdx.x & 127;
    const int r = blockIdx.x * 128 + rl;
    const int sg = threadIdx.x >> 7;           // 0..3
    const int s0 = sg * (S_ / 4), s1 = s0 + S_ / 4;
    const float* base = l + (long)b * S_ * R_ + r;
    __shared__ float red[4][128];

    float pm = -1e30f;
    for (int s = s0; s < s1; ++s) pm = fmaxf(pm, base[(long)s * R_]);
    red[sg][rl] = pm;
    __syncthreads();
    const float m = fmaxf(fmaxf(red[0][rl], red[1][rl]), fmaxf(red[2][rl], red[3][rl]));
    __syncthreads();

    float ps = 0.f;
    for (int s = s0; s < s1; ++s) ps += __expf(base[(long)s * R_] - m);
    red[sg][rl] = ps;
    __syncthreads();
    const float inv = 1.f / (red[0][rl] + red[1][rl] + red[2][rl] + red[3][rl]);

    float* ob = as_ + (long)b * S_ * R_ + r;
    for (int s = s0; s < s1; ++s) ob[(long)s * R_] = __expf(base[(long)s * R_] - m) * inv;
}

// ---------------------------------------------------------------------------
// cat[b][h][s] = h_s[b][s][h]  (s_t half of cat_sc), 32x32 LDS tile transpose
// ---------------------------------------------------------------------------
__global__ __launch_bounds__(256) void transpose_hs(const float* __restrict__ hs,
                                                    float* __restrict__ cat)
{
    __shared__ float tile[32][33];
    const int b = blockIdx.z;
    const int s0 = blockIdx.x * 32, h0 = blockIdx.y * 32;
    const int tx = threadIdx.x, ty = threadIdx.y;
#pragma unroll
    for (int i = 0; i < 32; i += 8)
        tile[ty + i][tx] = hs[((long)b * S_ + s0 + ty + i) * H_ + h0 + tx];
    __syncthreads();
#pragma unroll
    for (int i = 0; i < 32; i += 8)
        cat[((long)b * 2 * H_ + h0 + ty + i) * S_ + s0 + tx] = tile[tx][ty + i];
}

// ---------------------------------------------------------------------------
// bin[t][b][0:1024] = c_r[b][t][:]; bin[t][b][1024:1536] = ref[t][b][:]
// ---------------------------------------------------------------------------
__global__ __launch_bounds__(256) void build_bin(const float* __restrict__ cr,
                                                 const float* __restrict__ ref,
                                                 float* __restrict__ bin)
{
    const long idx4 = (long)blockIdx.x * blockDim.x + threadIdx.x;
    if (idx4 >= (long)R_ * B_ * DIN_ / 4) return;
    const long f = idx4 * 4;
    const int d = (int)(f % DIN_);
    const long tb = f / DIN_;
    const int b = (int)(tb % B_);
    const int t = (int)(tb / B_);
    float4 v;
    if (d < 2 * H_) v = *(const float4*)(cr + ((long)b * R_ + t) * (2 * H_) + d);
    else            v = *(const float4*)(ref + ((long)t * B_ + b) * H_ + (d - 2 * H_));
    *(float4*)(bin + f) = v;
}

// ---------------------------------------------------------------------------
// One-time W_hh transpose + bf16(RTN) pack:
// WB[dir][q2][g] = uint4 of 8 bf16 = Whh_dir[g][8*q2 .. 8*q2+8)
// ---------------------------------------------------------------------------
__device__ inline unsigned pk_bf16(float lo, float hi)
{
    __hip_bfloat16 l = __float2bfloat16(lo);
    __hip_bfloat16 h = __float2bfloat16(hi);
    unsigned short ul, uh;
    __builtin_memcpy(&ul, &l, 2);
    __builtin_memcpy(&uh, &h, 2);
    return (unsigned)ul | ((unsigned)uh << 16);
}

__global__ __launch_bounds__(256) void transpose_w_bf16(
    const float* __restrict__ Whh_f, const float* __restrict__ Whh_b,
    unsigned* __restrict__ WB)
{
    const int g = blockIdx.x * 256 + threadIdx.x;   // 0..1023
    const int q2 = blockIdx.y;                      // 0..31
    const int dir = blockIdx.z;
    const float* W = dir ? Whh_b : Whh_f;
    const float4 a = *(const float4*)(W + (long)g * HD_ + q2 * 8);
    const float4 b = *(const float4*)(W + (long)g * HD_ + q2 * 8 + 4);
    uint4 u;
    u.x = pk_bf16(a.x, a.y);
    u.y = pk_bf16(a.z, a.w);
    u.z = pk_bf16(b.x, b.y);
    u.w = pk_bf16(b.z, b.w);
    *((uint4*)WB + ((long)dir * 32 + q2) * 1024 + g) = u;
}

// ---------------------------------------------------------------------------
// Bi-LSTM scan, BATCH-PARTITIONED (zero cross-block sync), v4 (fixed macro):
//   (1) 4-deep W register pipeline with exact slot rotation; next-step tiles
//       issue BEFORE the LDS/cell phases (W addrs step-invariant).
//   (2) 6 of 32 W q2-tiles cached in LDS (96 KB): global stream 512 ->
//       416 KB/step/CU.
//   (3) k-split remap to 2 x 256: p_lds 16 KB, 2-way reduce.
// LDS: 96 + 16 + 2 = 114 KB. Block (dir,bg) = batches {2bg,2bg+1}; 16 blocks.
// ---------------------------------------------------------------------------
__device__ inline float sig_(float x) { return 1.f / (1.f + __expf(-x)); }
__device__ inline float tanh_(float x) {
    float ax = fabsf(x);
    float t = 1.f - 2.f / (1.f + __expf(2.f * ax));
    return copysignf(t, x);
}

// unpack one W k-octet (8 bf16) and FMA into both batches' accumulators.
// NOTE: param named WV (not `w`) — a param named `w` gets substituted into
// the `.w` member accesses (R11 compile failure).
#define FMA_ROW(WV, A0, A1)                                               \
    {                                                                     \
        const uint4 w_ = (WV);                                            \
        const float w0 = __uint_as_float(w_.x << 16);                     \
        const float w1 = __uint_as_float(w_.x & 0xffff0000u);             \
        const float w2 = __uint_as_float(w_.y << 16);                     \
        const float w3 = __uint_as_float(w_.y & 0xffff0000u);             \
        const float w4 = __uint_as_float(w_.z << 16);                     \
        const float w5 = __uint_as_float(w_.z & 0xffff0000u);             \
        const float w6 = __uint_as_float(w_.w << 16);                     \
        const float w7 = __uint_as_float(w_.w & 0xffff0000u);             \
        A0 += w0 * ha0.x + w1 * ha0.y + w2 * ha0.z + w3 * ha0.w           \
            + w4 * hb0.x + w5 * hb0.y + w6 * hb0.z + w7 * hb0.w;          \
        A1 += w0 * ha1.x + w1 * ha1.y + w2 * ha1.z + w3 * ha1.w           \
            + w4 * hb1.x + w5 * hb1.y + w6 * hb1.z + w7 * hb1.w;          \
    }

__global__ __launch_bounds__(512) void lstm_scan_b(
    const float* __restrict__ xg_f, const float* __restrict__ xg_b,
    const unsigned* __restrict__ WBu, float* __restrict__ out)
{
    const int blk = blockIdx.x;
    const int dir = blk >> 3;
    const int b0 = (blk & 7) * 2;
    const float* xg = dir ? xg_b : xg_f;
    const uint4* Wg = (const uint4*)WBu + (long)dir * 32768;   // 32 q2 x 1024 rows

    __shared__ uint4 Wc[6144];            // 96 KB: q2 tiles {0,1,2} per ks
    __shared__ float h_lds[2][256];       // 2 KB
    __shared__ float p_lds[2][2][1024];   // 16 KB [ks][batch][gate-row]

    const int tid = threadIdx.x;
    const int ks = tid >> 8;              // 0..1 (wave-uniform)
    const int go = tid & 255;             // h-column / row offset
    const int cbb = tid >> 8;             // cell batch 0..1
    const int cn = tid & 255;             // cell column

    // one-time: fill Wc with q2 tiles {ks*16+0, +1, +2} for both ks
    for (int idx = tid; idx < 6144; idx += 512) {
        const int tix = idx >> 10, r = idx & 1023;
        const int ksf = tix / 3, qf = tix - ksf * 3;
        Wc[idx] = Wg[(ksf * 16 + qf) * 1024 + r];
    }
    h_lds[tid >> 8][tid & 255] = 0.f;
    float c_reg = 0.f;
    __syncthreads();

    // 4-deep prologue: global q2 tiles q=3..6 into slots 0..3
    uint4 wbuf[4][4];
#pragma unroll
    for (int j0 = 0; j0 < 4; ++j0) {
        const uint4* wp = Wg + (ks * 16 + 3 + j0) * 1024 + go;
#pragma unroll
        for (int ri = 0; ri < 4; ++ri) wbuf[j0][ri] = wp[ri * 256];
    }

    for (int t = 0; t < R_; ++t) {
        const int tt = dir ? (R_ - 1 - t) : t;
        const long xb = ((long)tt * B_ + b0 + cbb) * G_ + cn;
        const float xgi = xg[xb];
        const float xgf2 = xg[xb + 256];
        const float xgg = xg[xb + 512];
        const float xgo = xg[xb + 768];

        float acc0[4] = {}, acc1[4] = {};
        // 13 global phases q = 3..15, 4-deep rotation
#pragma unroll
        for (int j = 0; j < 13; ++j) {
            const int q = 3 + j;
            const int bi = j & 3;
            const int ko = ks * 128 + q * 8;
            const float4 ha0 = *(const float4*)&h_lds[0][ko];
            const float4 hb0 = *(const float4*)&h_lds[0][ko + 4];
            const float4 ha1 = *(const float4*)&h_lds[1][ko];
            const float4 hb1 = *(const float4*)&h_lds[1][ko + 4];
#pragma unroll
            for (int ri = 0; ri < 4; ++ri)
                FMA_ROW(wbuf[bi][ri], acc0[ri], acc1[ri]);
            if (j + 4 < 13) {
                const uint4* wp = Wg + (ks * 16 + q + 4) * 1024 + go;
#pragma unroll
                for (int ri = 0; ri < 4; ++ri) wbuf[bi][ri] = wp[ri * 256];
            }
        }
        // issue next step's q=3..6 now (latency hides under LDS+cell phases)
#pragma unroll
        for (int j0 = 0; j0 < 4; ++j0) {
            const uint4* wp = Wg + (ks * 16 + 3 + j0) * 1024 + go;
#pragma unroll
            for (int ri = 0; ri < 4; ++ri) wbuf[j0][ri] = wp[ri * 256];
        }
        // 3 LDS-cached phases q = 0..2
#pragma unroll
        for (int q = 0; q < 3; ++q) {
            const int ko = ks * 128 + q * 8;
            const float4 ha0 = *(const float4*)&h_lds[0][ko];
            const float4 hb0 = *(const float4*)&h_lds[0][ko + 4];
            const float4 ha1 = *(const float4*)&h_lds[1][ko];
            const float4 hb1 = *(const float4*)&h_lds[1][ko + 4];
            const int tb0 = (ks * 3 + q) << 10;
#pragma unroll
            for (int ri = 0; ri < 4; ++ri) {
                FMA_ROW(Wc[tb0 + ri * 256 + go], acc0[ri], acc1[ri]);
            }
        }
#pragma unroll
        for (int ri = 0; ri < 4; ++ri) {
            p_lds[ks][0][ri * 256 + go] = acc0[ri];
            p_lds[ks][1][ri * 256 + go] = acc1[ri];
        }
        __syncthreads();

        // fused 2-way reduce + cell update: thread = (cbb, cn)
        {
            const float iv = xgi  + p_lds[0][cbb][cn]       + p_lds[1][cbb][cn];
            const float fv = xgf2 + p_lds[0][cbb][256 + cn] + p_lds[1][cbb][256 + cn];
            const float gv = xgg  + p_lds[0][cbb][512 + cn] + p_lds[1][cbb][512 + cn];
            const float ov = xgo  + p_lds[0][cbb][768 + cn] + p_lds[1][cbb][768 + cn];
            c_reg = sig_(fv) * c_reg + sig_(iv) * tanh_(gv);
            const float h = sig_(ov) * tanh_(c_reg);
            h_lds[cbb][cn] = h;
            out[((long)tt * B_ + b0 + cbb) * (2 * HD_) + dir * HD_ + cn] = h;
        }
        __syncthreads();
    }
}

// ---------------------------------------------------------------------------
extern "C" void kernel_launch(void* const* d_in, const int* in_sizes, int n_in,
                              void* d_out, int out_size, void* d_ws, size_t ws_size,
                              hipStream_t stream)
{
    const float* src  = (const float*)d_in[1];   // [S][B][H]
    const float* ref  = (const float*)d_in[2];   // [R][B][H]
    const float* Wref = (const float*)d_in[3];   // [H][H]
    const float* bref = (const float*)d_in[4];   // [H]
    const float* Wihf = (const float*)d_in[5];   // [G][DIN]
    const float* Whhf = (const float*)d_in[6];   // [G][HD]
    const float* bihf = (const float*)d_in[7];
    const float* bhhf = (const float*)d_in[8];
    const float* Wihb = (const float*)d_in[9];
    const float* Whhb = (const float*)d_in[10];
    const float* bihb = (const float*)d_in[11];
    const float* bhhb = (const float*)d_in[12];
    float* out = (float*)d_out;                  // [R][B][2*HD]

    float* ws = (float*)d_ws;
    // workspace layout (floats), with aliasing:
    float* hs  = ws + 0L;                         // 8388608   [B][S][H]
    float* l   = ws + 8388608L;                   // 8388608   [B][S][R] (a_r in place)
    float* as_ = ws + 16777216L;                  // 8388608   [B][S][R]
    float* cat = ws + 25165824L;                  // 16777216  [B][2H][S]
    float* cr  = hs;                              // 8388608   [B][R][2H]  (hs dead after step 4)
    float* bin = cat;                             // 12582912  [T][B][DIN] (cat dead after step 6)
    float* xgf = l;                               // 8388608   [T][B][G]   (l dead after step 6)
    float* xgb = as_;                             // 8388608   [T][B][G]   (as_ dead after step 5)
    unsigned* WB = (unsigned*)(ws + 41943040L);   // 262144 u32: 2 dir x 32 q2 x 1024 g x uint4

    // 0) one-time W_hh transpose + bf16 pack
    transpose_w_bf16<<<dim3(4, 32, 2), 256, 0, stream>>>(Whhf, Whhb, WB);

    // 1) h_s = tanh(src . Wref^T + bref)   [B*S, 512] k=512
    gemm_mk_nk<1, 1><<<dim3(8, 256, 1), 256, 0, stream>>>(
        src, H_, 0, Wref, H_, 0, hs, H_, 0, bref, nullptr, B_ * S_, H_, H_);

    // 2) l[b] = h_s[b] . h_r[b]^T   M=1024 N=512 K=512, batched over b
    gemm_mk_nk<0, 0><<<dim3(8, 16, B_), 256, 0, stream>>>(
        hs, H_, (long)S_ * H_, ref, (long)B_ * H_, H_, l, R_, (long)S_ * R_,
        nullptr, nullptr, S_, R_, H_);

    // 3) a_s = softmax over s (columns), then a_r = softmax over r in place
    softmax_cols<<<dim3(R_ / 128, B_), 512, 0, stream>>>(l, as_);
    softmax_rows<<<(B_ * S_) / 4, 256, 0, stream>>>(l);

    // 4) cat rows 0..511 = h_s transposed
    transpose_hs<<<dim3(S_ / 32, H_ / 32, B_), dim3(32, 8), 0, stream>>>(hs, cat);

    // 5) cat rows 512..1023: c_s[b,h,s] = sum_r ref[r,b,h]*a_s[b,s,r]
    gemm_km_nk<<<dim3(16, 8, B_), 256, 0, stream>>>(
        ref, (long)B_ * H_, H_, as_, R_, (long)S_ * R_,
        cat + (long)H_ * S_, S_, (long)2 * H_ * S_, H_, S_, R_);

    // 6) c_r[b,r,k] = sum_s cat[b,k,s]*a_r[b,s,r]   M=512 N=1024 K=1024
    gemm_km_nk<<<dim3(16, 8, B_), 256, 0, stream>>>(
        l, R_, (long)S_ * R_, cat, S_, (long)2 * H_ * S_,
        cr, 2 * H_, (long)R_ * 2 * H_, R_, 2 * H_, S_);

    // 7) bilstm_in
    build_bin<<<(R_ * B_ * DIN_ / 4 + 255) / 256, 256, 0, stream>>>(cr, ref, bin);

    // 8) xg = bin . W_ih^T + b_ih + b_hh  (both directions)
    gemm_mk_nk<2, 0><<<dim3(16, 128, 1), 256, 0, stream>>>(
        bin, DIN_, 0, Wihf, DIN_, 0, xgf, G_, 0, bihf, bhhf, R_ * B_, G_, DIN_);
    gemm_mk_nk<2, 0><<<dim3(16, 128, 1), 256, 0, stream>>>(
        bin, DIN_, 0, Wihb, DIN_, 0, xgb, G_, 0, bihb, bhhb, R_ * B_, G_, DIN_);

    // 9) bi-LSTM scan: 16 independent (dir, batch-pair) blocks, zero sync
    lstm_scan_b<<<dim3(16), dim3(512), 0, stream>>>(xgf, xgb, WB, out);
}

// Round 13
// 4885.728 us; speedup vs baseline: 2.2214x; 1.3347x over previous
//
#include <hip/hip_runtime.h>
#include <hip/hip_bf16.h>
#include <math.h>

#define B_   16
#define S_   1024
#define R_   512
#define H_   512
#define HD_  256
#define G_   1024
#define DIN_ 1536

// ---------------------------------------------------------------------------
// Tiled fp32 GEMM:  C[m][n] = sum_k A(m,k) * B(n,k)
// ---------------------------------------------------------------------------
template<int EPI, int REMAP_A>
__global__ __launch_bounds__(256) void gemm_mk_nk(
    const float* __restrict__ A, long a_rs, long a_bs,
    const float* __restrict__ Bm, long b_rs, long b_bs,
    float* __restrict__ C, long c_rs, long c_bs,
    const float* __restrict__ bias, const float* __restrict__ bias2,
    int M, int N, int K)
{
    __shared__ float As[16][68];
    __shared__ float Bs[16][68];
    const int bb = blockIdx.z;
    const float* Ab = A + (long)bb * a_bs;
    const float* Bb = Bm + (long)bb * b_bs;
    float* Cb = C + (long)bb * c_bs;
    const int m0 = blockIdx.y * 64, n0 = blockIdx.x * 64;
    const int tid = threadIdx.x;
    const int tx = tid & 15, ty = tid >> 4;
    const int lr = tid >> 2;          // tile row 0..63
    const int lk = (tid & 3) << 2;    // k offset 0..12

    long arow;
    {
        int m = m0 + lr;
        if (REMAP_A) arow = (long)((m % S_) * B_ + (m / S_)) * a_rs;
        else         arow = (long)m * a_rs;
    }
    const long brow = (long)(n0 + lr) * b_rs;

    float acc[4][4] = {};
    for (int k0 = 0; k0 < K; k0 += 16) {
        float4 av = *(const float4*)(Ab + arow + k0 + lk);
        float4 bv = *(const float4*)(Bb + brow + k0 + lk);
        As[lk + 0][lr] = av.x; As[lk + 1][lr] = av.y;
        As[lk + 2][lr] = av.z; As[lk + 3][lr] = av.w;
        Bs[lk + 0][lr] = bv.x; Bs[lk + 1][lr] = bv.y;
        Bs[lk + 2][lr] = bv.z; Bs[lk + 3][lr] = bv.w;
        __syncthreads();
#pragma unroll
        for (int kk = 0; kk < 16; ++kk) {
            float4 a = *(const float4*)&As[kk][ty << 2];
            float4 b = *(const float4*)&Bs[kk][tx << 2];
            acc[0][0] += a.x * b.x; acc[0][1] += a.x * b.y; acc[0][2] += a.x * b.z; acc[0][3] += a.x * b.w;
            acc[1][0] += a.y * b.x; acc[1][1] += a.y * b.y; acc[1][2] += a.y * b.z; acc[1][3] += a.y * b.w;
            acc[2][0] += a.z * b.x; acc[2][1] += a.z * b.y; acc[2][2] += a.z * b.z; acc[2][3] += a.z * b.w;
            acc[3][0] += a.w * b.x; acc[3][1] += a.w * b.y; acc[3][2] += a.w * b.z; acc[3][3] += a.w * b.w;
        }
        __syncthreads();
    }
#pragma unroll
    for (int i = 0; i < 4; ++i) {
        const int m = m0 + (ty << 2) + i;
#pragma unroll
        for (int j = 0; j < 4; ++j) {
            const int n = n0 + (tx << 2) + j;
            float v = acc[i][j];
            if (EPI == 1) v = tanhf(v + bias[n]);
            else if (EPI == 2) v += bias[n] + bias2[n];
            Cb[(long)m * c_rs + n] = v;
        }
    }
}

// ---------------------------------------------------------------------------
// Tiled fp32 GEMM:  C[m][n] = sum_k A(k,m) * B(n,k)
// ---------------------------------------------------------------------------
__global__ __launch_bounds__(256) void gemm_km_nk(
    const float* __restrict__ A, long a_ks, long a_bs,
    const float* __restrict__ Bm, long b_rs, long b_bs,
    float* __restrict__ C, long c_rs, long c_bs,
    int M, int N, int K)
{
    __shared__ float As[16][68];
    __shared__ float Bs[16][68];
    const int bb = blockIdx.z;
    const float* Ab = A + (long)bb * a_bs;
    const float* Bb = Bm + (long)bb * b_bs;
    float* Cb = C + (long)bb * c_bs;
    const int m0 = blockIdx.y * 64, n0 = blockIdx.x * 64;
    const int tid = threadIdx.x;
    const int tx = tid & 15, ty = tid >> 4;
    const int lr = tid >> 2;            // B tile row (n) 0..63
    const int lk = (tid & 3) << 2;      // B k offset
    const int alk = tid >> 4;           // A k row 0..15
    const int alm = (tid & 15) << 2;    // A m offset
    const long brow = (long)(n0 + lr) * b_rs;

    float acc[4][4] = {};
    for (int k0 = 0; k0 < K; k0 += 16) {
        float4 av = *(const float4*)(Ab + (long)(k0 + alk) * a_ks + m0 + alm);
        *(float4*)&As[alk][alm] = av;
        float4 bv = *(const float4*)(Bb + brow + k0 + lk);
        Bs[lk + 0][lr] = bv.x; Bs[lk + 1][lr] = bv.y;
        Bs[lk + 2][lr] = bv.z; Bs[lk + 3][lr] = bv.w;
        __syncthreads();
#pragma unroll
        for (int kk = 0; kk < 16; ++kk) {
            float4 a = *(const float4*)&As[kk][ty << 2];
            float4 b = *(const float4*)&Bs[kk][tx << 2];
            acc[0][0] += a.x * b.x; acc[0][1] += a.x * b.y; acc[0][2] += a.x * b.z; acc[0][3] += a.x * b.w;
            acc[1][0] += a.y * b.x; acc[1][1] += a.y * b.y; acc[1][2] += a.y * b.z; acc[1][3] += a.y * b.w;
            acc[2][0] += a.z * b.x; acc[2][1] += a.z * b.y; acc[2][2] += a.z * b.z; acc[2][3] += a.z * b.w;
            acc[3][0] += a.w * b.x; acc[3][1] += a.w * b.y; acc[3][2] += a.w * b.z; acc[3][3] += a.w * b.w;
        }
        __syncthreads();
    }
#pragma unroll
    for (int i = 0; i < 4; ++i) {
        const int m = m0 + (ty << 2) + i;
#pragma unroll
        for (int j = 0; j < 4; ++j) {
            const int n = n0 + (tx << 2) + j;
            Cb[(long)m * c_rs + n] = acc[i][j];
        }
    }
}

// ---------------------------------------------------------------------------
// Softmax over r (last axis, contiguous, 512 elems): one wave per row, in-place
// ---------------------------------------------------------------------------
__global__ __launch_bounds__(256) void softmax_rows(float* __restrict__ l)
{
    const int lane = threadIdx.x & 63;
    const int wv = threadIdx.x >> 6;
    const long row = (long)blockIdx.x * 4 + wv;
    float* p = l + row * R_;
    float4 v0 = ((const float4*)p)[lane * 2];
    float4 v1 = ((const float4*)p)[lane * 2 + 1];
    float m = fmaxf(fmaxf(fmaxf(v0.x, v0.y), fmaxf(v0.z, v0.w)),
                    fmaxf(fmaxf(v1.x, v1.y), fmaxf(v1.z, v1.w)));
#pragma unroll
    for (int o = 32; o; o >>= 1) m = fmaxf(m, __shfl_xor(m, o));
    v0.x = __expf(v0.x - m); v0.y = __expf(v0.y - m);
    v0.z = __expf(v0.z - m); v0.w = __expf(v0.w - m);
    v1.x = __expf(v1.x - m); v1.y = __expf(v1.y - m);
    v1.z = __expf(v1.z - m); v1.w = __expf(v1.w - m);
    float s = v0.x + v0.y + v0.z + v0.w + v1.x + v1.y + v1.z + v1.w;
#pragma unroll
    for (int o = 32; o; o >>= 1) s += __shfl_xor(s, o);
    const float inv = 1.f / s;
    v0.x *= inv; v0.y *= inv; v0.z *= inv; v0.w *= inv;
    v1.x *= inv; v1.y *= inv; v1.z *= inv; v1.w *= inv;
    ((float4*)p)[lane * 2] = v0;
    ((float4*)p)[lane * 2 + 1] = v1;
}

// ---------------------------------------------------------------------------
// Softmax over s (axis 1, stride R): 512 threads = 128 cols x 4 s-groups
// ---------------------------------------------------------------------------
__global__ __launch_bounds__(512) void softmax_cols(const float* __restrict__ l,
                                                    float* __restrict__ as_)
{
    const int b = blockIdx.y;
    const int rl = threadIdx.x & 127;
    const int r = blockIdx.x * 128 + rl;
    const int sg = threadIdx.x >> 7;           // 0..3
    const int s0 = sg * (S_ / 4), s1 = s0 + S_ / 4;
    const float* base = l + (long)b * S_ * R_ + r;
    __shared__ float red[4][128];

    float pm = -1e30f;
    for (int s = s0; s < s1; ++s) pm = fmaxf(pm, base[(long)s * R_]);
    red[sg][rl] = pm;
    __syncthreads();
    const float m = fmaxf(fmaxf(red[0][rl], red[1][rl]), fmaxf(red[2][rl], red[3][rl]));
    __syncthreads();

    float ps = 0.f;
    for (int s = s0; s < s1; ++s) ps += __expf(base[(long)s * R_] - m);
    red[sg][rl] = ps;
    __syncthreads();
    const float inv = 1.f / (red[0][rl] + red[1][rl] + red[2][rl] + red[3][rl]);

    float* ob = as_ + (long)b * S_ * R_ + r;
    for (int s = s0; s < s1; ++s) ob[(long)s * R_] = __expf(base[(long)s * R_] - m) * inv;
}

// ---------------------------------------------------------------------------
// cat[b][h][s] = h_s[b][s][h]  (s_t half of cat_sc), 32x32 LDS tile transpose
// ---------------------------------------------------------------------------
__global__ __launch_bounds__(256) void transpose_hs(const float* __restrict__ hs,
                                                    float* __restrict__ cat)
{
    __shared__ float tile[32][33];
    const int b = blockIdx.z;
    const int s0 = blockIdx.x * 32, h0 = blockIdx.y * 32;
    const int tx = threadIdx.x, ty = threadIdx.y;
#pragma unroll
    for (int i = 0; i < 32; i += 8)
        tile[ty + i][tx] = hs[((long)b * S_ + s0 + ty + i) * H_ + h0 + tx];
    __syncthreads();
#pragma unroll
    for (int i = 0; i < 32; i += 8)
        cat[((long)b * 2 * H_ + h0 + ty + i) * S_ + s0 + tx] = tile[tx][ty + i];
}

// ---------------------------------------------------------------------------
// bin[t][b][0:1024] = c_r[b][t][:]; bin[t][b][1024:1536] = ref[t][b][:]
// ---------------------------------------------------------------------------
__global__ __launch_bounds__(256) void build_bin(const float* __restrict__ cr,
                                                 const float* __restrict__ ref,
                                                 float* __restrict__ bin)
{
    const long idx4 = (long)blockIdx.x * blockDim.x + threadIdx.x;
    if (idx4 >= (long)R_ * B_ * DIN_ / 4) return;
    const long f = idx4 * 4;
    const int d = (int)(f % DIN_);
    const long tb = f / DIN_;
    const int b = (int)(tb % B_);
    const int t = (int)(tb / B_);
    float4 v;
    if (d < 2 * H_) v = *(const float4*)(cr + ((long)b * R_ + t) * (2 * H_) + d);
    else            v = *(const float4*)(ref + ((long)t * B_ + b) * H_ + (d - 2 * H_));
    *(float4*)(bin + f) = v;
}

// ---------------------------------------------------------------------------
// One-time W_hh transpose + bf16(RTN) pack:
// WB[dir][q2][g] = uint4 of 8 bf16 = Whh_dir[g][8*q2 .. 8*q2+8)
// q2 = 4*kk + kgroup matches the MFMA B-fragment layout directly:
// B-frag(tile n, K-step kk): lane l reads WB[4*kk + (l>>4)][16n + (l&15)].
// ---------------------------------------------------------------------------
__device__ inline unsigned pk_bf16(float lo, float hi)
{
    __hip_bfloat16 l = __float2bfloat16(lo);
    __hip_bfloat16 h = __float2bfloat16(hi);
    unsigned short ul, uh;
    __builtin_memcpy(&ul, &l, 2);
    __builtin_memcpy(&uh, &h, 2);
    return (unsigned)ul | ((unsigned)uh << 16);
}

__global__ __launch_bounds__(256) void transpose_w_bf16(
    const float* __restrict__ Whh_f, const float* __restrict__ Whh_b,
    unsigned* __restrict__ WB)
{
    const int g = blockIdx.x * 256 + threadIdx.x;   // 0..1023
    const int q2 = blockIdx.y;                      // 0..31
    const int dir = blockIdx.z;
    const float* W = dir ? Whh_b : Whh_f;
    const float4 a = *(const float4*)(W + (long)g * HD_ + q2 * 8);
    const float4 b = *(const float4*)(W + (long)g * HD_ + q2 * 8 + 4);
    uint4 u;
    u.x = pk_bf16(a.x, a.y);
    u.y = pk_bf16(a.z, a.w);
    u.z = pk_bf16(b.x, b.y);
    u.w = pk_bf16(b.z, b.w);
    *((uint4*)WB + ((long)dir * 32 + q2) * 1024 + g) = u;
}

// ---------------------------------------------------------------------------
// Bi-LSTM scan v5 — MFMA, one block per DIRECTION (M=16 batches = one M-tile).
// R12 showed the fp32-VALU scan floors at ~4.5us/step (unpack+FMA issue).
// MFMA collapses compute to 512 mfma_16x16x32 per step (~0.27us/CU) and
// needs NO cross-block sync: 2 blocks x 512 thr (8 waves).
// Wave w owns gate-COLUMNS 32w..32w+31 across all 4 gates
// (tiles {2w,2w+1, +16, +32, +48...}) -> cell update is wave-local.
// W supply per step: kk0-1 register-resident (64 VGPR/wave), kk2-3 LDS
// (128 KB, filled once), kk4-7 streamed from L2 (256 KB/step ~1.7us).
// h: bf16 in double-buffered LDS (row pad 264 -> 2-way banks = free);
// ONE barrier per step. Fragment layouts per guide §3 (m89-verified):
//  A: m=lane&15 (batch), k=(lane>>4)*8+j ; B: n=lane&15 (gatecol), same k;
//  D: col=lane&15, row=(lane>>4)*4+reg.
// ---------------------------------------------------------------------------
__device__ inline float sig_(float x) { return 1.f / (1.f + __expf(-x)); }
__device__ inline float tanh_(float x) {
    float ax = fabsf(x);
    float t = 1.f - 2.f / (1.f + __expf(2.f * ax));
    return copysignf(t, x);
}

typedef __attribute__((ext_vector_type(4))) float f32x4;
typedef __attribute__((ext_vector_type(8))) short bf16x8;

__device__ inline bf16x8 u4_to_b8(uint4 u)
{
    bf16x8 r;
    __builtin_memcpy(&r, &u, 16);
    return r;
}

// 8 MFMAs of one K-step; BEXPR may use loop var j
#define MFMA8(KK, BEXPR)                                                     \
    {                                                                        \
        const bf16x8 a_ = *(const bf16x8*)(hrow + 32 * (KK));                \
        _Pragma("unroll")                                                    \
        for (int j = 0; j < 8; ++j)                                          \
            acc[j] = __builtin_amdgcn_mfma_f32_16x16x32_bf16(                \
                a_, u4_to_b8(BEXPR), acc[j], 0, 0, 0);                       \
    }

__global__ __launch_bounds__(512, 2) void lstm_scan_m(
    const float* __restrict__ xg_f, const float* __restrict__ xg_b,
    const uint4* __restrict__ WBu, float* __restrict__ out)
{
    const int dir = blockIdx.x;
    const float* xg = dir ? xg_b : xg_f;
    const uint4* Wg = WBu + (long)dir * 32768;     // [q2 0..31][row 0..1023]

    __shared__ uint4 Wc[8192];                      // 128 KB: q2 8..15 (kk 2,3)
    __shared__ unsigned short hp[2][16 * 264];      // 16.5 KB bf16 h, dbuf

    const int tid = threadIdx.x;
    const int lane = tid & 63, w = tid >> 6;
    const int lcol = lane & 15, lkg = lane >> 4;

    // fill Wc (q2 8..15 is contiguous at offset 8192) + zero h_0
    for (int i = tid; i < 8192; i += 512) Wc[i] = Wg[8192 + i];
    for (int i = tid; i < 16 * 264; i += 512) hp[0][i] = 0;

    // wave w's 8 tiles: n_j = (j>>1)*16 + 2w + (j&1); nb = 16*n_j + lcol
    int nb[8];
#pragma unroll
    for (int j = 0; j < 8; ++j)
        nb[j] = ((((j >> 1) << 4) + 2 * w + (j & 1)) << 4) + lcol;

    // register-resident W: kk 0,1 (q2 = 4*kk + lkg)
    uint4 wreg[8][2];
#pragma unroll
    for (int kk = 0; kk < 2; ++kk)
#pragma unroll
        for (int j = 0; j < 8; ++j)
            wreg[j][kk] = Wg[(4 * kk + lkg) * 1024 + nb[j]];

    float c_reg[2][4] = {};
    uint4 sbA[8], sbB[8];
    __syncthreads();

    for (int t = 0; t < R_; ++t) {
        const int tt = dir ? (R_ - 1 - t) : t;
        const int p = t & 1;
        const unsigned short* hrow = &hp[p][lcol * 264 + lkg * 8];

        f32x4 acc[8];
#pragma unroll
        for (int j = 0; j < 8; ++j) acc[j] = (f32x4){0.f, 0.f, 0.f, 0.f};

        // stream kk=4 (q2 16..19)
#pragma unroll
        for (int j = 0; j < 8; ++j) sbA[j] = Wg[(16 + lkg) * 1024 + nb[j]];
        MFMA8(0, wreg[j][0])
        MFMA8(1, wreg[j][1])
        // stream kk=5
#pragma unroll
        for (int j = 0; j < 8; ++j) sbB[j] = Wg[(20 + lkg) * 1024 + nb[j]];
        MFMA8(4, sbA[j])
        // stream kk=6 (reuse sbA)
#pragma unroll
        for (int j = 0; j < 8; ++j) sbA[j] = Wg[(24 + lkg) * 1024 + nb[j]];
        MFMA8(2, Wc[lkg * 1024 + nb[j]])
        MFMA8(5, sbB[j])
        // stream kk=7 (reuse sbB)
#pragma unroll
        for (int j = 0; j < 8; ++j) sbB[j] = Wg[(28 + lkg) * 1024 + nb[j]];
        MFMA8(3, Wc[(4 + lkg) * 1024 + nb[j]])
        MFMA8(6, sbA[j])
        MFMA8(7, sbB[j])

        // cell phase: lane owns cells (batch = lkg*4+r, col = 32w+16jj+lcol)
#pragma unroll
        for (int jj = 0; jj < 2; ++jj) {
#pragma unroll
            for (int r = 0; r < 4; ++r) {
                const int batch = lkg * 4 + r;
                const int col = 32 * w + 16 * jj + lcol;
                const long xb = ((long)tt * B_ + batch) * G_ + col;
                const float iv = acc[0 + jj][r] + xg[xb];
                const float fv = acc[2 + jj][r] + xg[xb + 256];
                const float gv = acc[4 + jj][r] + xg[xb + 512];
                const float ov = acc[6 + jj][r] + xg[xb + 768];
                float c = sig_(fv) * c_reg[jj][r] + sig_(iv) * tanh_(gv);
                c_reg[jj][r] = c;
                const float h = sig_(ov) * tanh_(c);
                out[((long)tt * B_ + batch) * (2 * HD_) + dir * HD_ + col] = h;
                unsigned u = __float_as_uint(h);
                u += 0x7FFFu + ((u >> 16) & 1);          // RTN to bf16
                hp[p ^ 1][batch * 264 + col] = (unsigned short)(u >> 16);
            }
        }
        __syncthreads();
    }
}

// ---------------------------------------------------------------------------
extern "C" void kernel_launch(void* const* d_in, const int* in_sizes, int n_in,
                              void* d_out, int out_size, void* d_ws, size_t ws_size,
                              hipStream_t stream)
{
    const float* src  = (const float*)d_in[1];   // [S][B][H]
    const float* ref  = (const float*)d_in[2];   // [R][B][H]
    const float* Wref = (const float*)d_in[3];   // [H][H]
    const float* bref = (const float*)d_in[4];   // [H]
    const float* Wihf = (const float*)d_in[5];   // [G][DIN]
    const float* Whhf = (const float*)d_in[6];   // [G][HD]
    const float* bihf = (const float*)d_in[7];
    const float* bhhf = (const float*)d_in[8];
    const float* Wihb = (const float*)d_in[9];
    const float* Whhb = (const float*)d_in[10];
    const float* bihb = (const float*)d_in[11];
    const float* bhhb = (const float*)d_in[12];
    float* out = (float*)d_out;                  // [R][B][2*HD]

    float* ws = (float*)d_ws;
    // workspace layout (floats), with aliasing:
    float* hs  = ws + 0L;                         // 8388608   [B][S][H]
    float* l   = ws + 8388608L;                   // 8388608   [B][S][R] (a_r in place)
    float* as_ = ws + 16777216L;                  // 8388608   [B][S][R]
    float* cat = ws + 25165824L;                  // 16777216  [B][2H][S]
    float* cr  = hs;                              // 8388608   [B][R][2H]  (hs dead after step 4)
    float* bin = cat;                             // 12582912  [T][B][DIN] (cat dead after step 6)
    float* xgf = l;                               // 8388608   [T][B][G]   (l dead after step 6)
    float* xgb = as_;                             // 8388608   [T][B][G]   (as_ dead after step 5)
    unsigned* WB = (unsigned*)(ws + 41943040L);   // 262144 u32: 2 dir x 32 q2 x 1024 g x uint4

    // 0) one-time W_hh transpose + bf16 pack
    transpose_w_bf16<<<dim3(4, 32, 2), 256, 0, stream>>>(Whhf, Whhb, WB);

    // 1) h_s = tanh(src . Wref^T + bref)   [B*S, 512] k=512
    gemm_mk_nk<1, 1><<<dim3(8, 256, 1), 256, 0, stream>>>(
        src, H_, 0, Wref, H_, 0, hs, H_, 0, bref, nullptr, B_ * S_, H_, H_);

    // 2) l[b] = h_s[b] . h_r[b]^T   M=1024 N=512 K=512, batched over b
    gemm_mk_nk<0, 0><<<dim3(8, 16, B_), 256, 0, stream>>>(
        hs, H_, (long)S_ * H_, ref, (long)B_ * H_, H_, l, R_, (long)S_ * R_,
        nullptr, nullptr, S_, R_, H_);

    // 3) a_s = softmax over s (columns), then a_r = softmax over r in place
    softmax_cols<<<dim3(R_ / 128, B_), 512, 0, stream>>>(l, as_);
    softmax_rows<<<(B_ * S_) / 4, 256, 0, stream>>>(l);

    // 4) cat rows 0..511 = h_s transposed
    transpose_hs<<<dim3(S_ / 32, H_ / 32, B_), dim3(32, 8), 0, stream>>>(hs, cat);

    // 5) cat rows 512..1023: c_s[b,h,s] = sum_r ref[r,b,h]*a_s[b,s,r]
    gemm_km_nk<<<dim3(16, 8, B_), 256, 0, stream>>>(
        ref, (long)B_ * H_, H_, as_, R_, (long)S_ * R_,
        cat + (long)H_ * S_, S_, (long)2 * H_ * S_, H_, S_, R_);

    // 6) c_r[b,r,k] = sum_s cat[b,k,s]*a_r[b,s,r]   M=512 N=1024 K=1024
    gemm_km_nk<<<dim3(16, 8, B_), 256, 0, stream>>>(
        l, R_, (long)S_ * R_, cat, S_, (long)2 * H_ * S_,
        cr, 2 * H_, (long)R_ * 2 * H_, R_, 2 * H_, S_);

    // 7) bilstm_in
    build_bin<<<(R_ * B_ * DIN_ / 4 + 255) / 256, 256, 0, stream>>>(cr, ref, bin);

    // 8) xg = bin . W_ih^T + b_ih + b_hh  (both directions)
    gemm_mk_nk<2, 0><<<dim3(16, 128, 1), 256, 0, stream>>>(
        bin, DIN_, 0, Wihf, DIN_, 0, xgf, G_, 0, bihf, bhhf, R_ * B_, G_, DIN_);
    gemm_mk_nk<2, 0><<<dim3(16, 128, 1), 256, 0, stream>>>(
        bin, DIN_, 0, Wihb, DIN_, 0, xgb, G_, 0, bihb, bhhb, R_ * B_, G_, DIN_);

    // 9) bi-LSTM scan: 2 independent direction blocks, MFMA, zero sync
    lstm_scan_m<<<dim3(2), dim3(512), 0, stream>>>(xgf, xgb, (const uint4*)WB, out);
}

// Round 14
// 4491.798 us; speedup vs baseline: 2.4162x; 1.0877x over previous
//
#include <hip/hip_runtime.h>
#include <hip/hip_bf16.h>
#include <math.h>

#define B_   16
#define S_   1024
#define R_   512
#define H_   512
#define HD_  256
#define G_   1024
#define DIN_ 1536

// ---------------------------------------------------------------------------
// Tiled fp32 GEMM:  C[m][n] = sum_k A(m,k) * B(n,k)
// ---------------------------------------------------------------------------
template<int EPI, int REMAP_A>
__global__ __launch_bounds__(256) void gemm_mk_nk(
    const float* __restrict__ A, long a_rs, long a_bs,
    const float* __restrict__ Bm, long b_rs, long b_bs,
    float* __restrict__ C, long c_rs, long c_bs,
    const float* __restrict__ bias, const float* __restrict__ bias2,
    int M, int N, int K)
{
    __shared__ float As[16][68];
    __shared__ float Bs[16][68];
    const int bb = blockIdx.z;
    const float* Ab = A + (long)bb * a_bs;
    const float* Bb = Bm + (long)bb * b_bs;
    float* Cb = C + (long)bb * c_bs;
    const int m0 = blockIdx.y * 64, n0 = blockIdx.x * 64;
    const int tid = threadIdx.x;
    const int tx = tid & 15, ty = tid >> 4;
    const int lr = tid >> 2;          // tile row 0..63
    const int lk = (tid & 3) << 2;    // k offset 0..12

    long arow;
    {
        int m = m0 + lr;
        if (REMAP_A) arow = (long)((m % S_) * B_ + (m / S_)) * a_rs;
        else         arow = (long)m * a_rs;
    }
    const long brow = (long)(n0 + lr) * b_rs;

    float acc[4][4] = {};
    for (int k0 = 0; k0 < K; k0 += 16) {
        float4 av = *(const float4*)(Ab + arow + k0 + lk);
        float4 bv = *(const float4*)(Bb + brow + k0 + lk);
        As[lk + 0][lr] = av.x; As[lk + 1][lr] = av.y;
        As[lk + 2][lr] = av.z; As[lk + 3][lr] = av.w;
        Bs[lk + 0][lr] = bv.x; Bs[lk + 1][lr] = bv.y;
        Bs[lk + 2][lr] = bv.z; Bs[lk + 3][lr] = bv.w;
        __syncthreads();
#pragma unroll
        for (int kk = 0; kk < 16; ++kk) {
            float4 a = *(const float4*)&As[kk][ty << 2];
            float4 b = *(const float4*)&Bs[kk][tx << 2];
            acc[0][0] += a.x * b.x; acc[0][1] += a.x * b.y; acc[0][2] += a.x * b.z; acc[0][3] += a.x * b.w;
            acc[1][0] += a.y * b.x; acc[1][1] += a.y * b.y; acc[1][2] += a.y * b.z; acc[1][3] += a.y * b.w;
            acc[2][0] += a.z * b.x; acc[2][1] += a.z * b.y; acc[2][2] += a.z * b.z; acc[2][3] += a.z * b.w;
            acc[3][0] += a.w * b.x; acc[3][1] += a.w * b.y; acc[3][2] += a.w * b.z; acc[3][3] += a.w * b.w;
        }
        __syncthreads();
    }
#pragma unroll
    for (int i = 0; i < 4; ++i) {
        const int m = m0 + (ty << 2) + i;
#pragma unroll
        for (int j = 0; j < 4; ++j) {
            const int n = n0 + (tx << 2) + j;
            float v = acc[i][j];
            if (EPI == 1) v = tanhf(v + bias[n]);
            else if (EPI == 2) v += bias[n] + bias2[n];
            Cb[(long)m * c_rs + n] = v;
        }
    }
}

// ---------------------------------------------------------------------------
// Tiled fp32 GEMM:  C[m][n] = sum_k A(k,m) * B(n,k)
// ---------------------------------------------------------------------------
__global__ __launch_bounds__(256) void gemm_km_nk(
    const float* __restrict__ A, long a_ks, long a_bs,
    const float* __restrict__ Bm, long b_rs, long b_bs,
    float* __restrict__ C, long c_rs, long c_bs,
    int M, int N, int K)
{
    __shared__ float As[16][68];
    __shared__ float Bs[16][68];
    const int bb = blockIdx.z;
    const float* Ab = A + (long)bb * a_bs;
    const float* Bb = Bm + (long)bb * b_bs;
    float* Cb = C + (long)bb * c_bs;
    const int m0 = blockIdx.y * 64, n0 = blockIdx.x * 64;
    const int tid = threadIdx.x;
    const int tx = tid & 15, ty = tid >> 4;
    const int lr = tid >> 2;            // B tile row (n) 0..63
    const int lk = (tid & 3) << 2;      // B k offset
    const int alk = tid >> 4;           // A k row 0..15
    const int alm = (tid & 15) << 2;    // A m offset
    const long brow = (long)(n0 + lr) * b_rs;

    float acc[4][4] = {};
    for (int k0 = 0; k0 < K; k0 += 16) {
        float4 av = *(const float4*)(Ab + (long)(k0 + alk) * a_ks + m0 + alm);
        *(float4*)&As[alk][alm] = av;
        float4 bv = *(const float4*)(Bb + brow + k0 + lk);
        Bs[lk + 0][lr] = bv.x; Bs[lk + 1][lr] = bv.y;
        Bs[lk + 2][lr] = bv.z; Bs[lk + 3][lr] = bv.w;
        __syncthreads();
#pragma unroll
        for (int kk = 0; kk < 16; ++kk) {
            float4 a = *(const float4*)&As[kk][ty << 2];
            float4 b = *(const float4*)&Bs[kk][tx << 2];
            acc[0][0] += a.x * b.x; acc[0][1] += a.x * b.y; acc[0][2] += a.x * b.z; acc[0][3] += a.x * b.w;
            acc[1][0] += a.y * b.x; acc[1][1] += a.y * b.y; acc[1][2] += a.y * b.z; acc[1][3] += a.y * b.w;
            acc[2][0] += a.z * b.x; acc[2][1] += a.z * b.y; acc[2][2] += a.z * b.z; acc[2][3] += a.z * b.w;
            acc[3][0] += a.w * b.x; acc[3][1] += a.w * b.y; acc[3][2] += a.w * b.z; acc[3][3] += a.w * b.w;
        }
        __syncthreads();
    }
#pragma unroll
    for (int i = 0; i < 4; ++i) {
        const int m = m0 + (ty << 2) + i;
#pragma unroll
        for (int j = 0; j < 4; ++j) {
            const int n = n0 + (tx << 2) + j;
            Cb[(long)m * c_rs + n] = acc[i][j];
        }
    }
}

// ---------------------------------------------------------------------------
// Softmax over r (last axis, contiguous, 512 elems): one wave per row, in-place
// ---------------------------------------------------------------------------
__global__ __launch_bounds__(256) void softmax_rows(float* __restrict__ l)
{
    const int lane = threadIdx.x & 63;
    const int wv = threadIdx.x >> 6;
    const long row = (long)blockIdx.x * 4 + wv;
    float* p = l + row * R_;
    float4 v0 = ((const float4*)p)[lane * 2];
    float4 v1 = ((const float4*)p)[lane * 2 + 1];
    float m = fmaxf(fmaxf(fmaxf(v0.x, v0.y), fmaxf(v0.z, v0.w)),
                    fmaxf(fmaxf(v1.x, v1.y), fmaxf(v1.z, v1.w)));
#pragma unroll
    for (int o = 32; o; o >>= 1) m = fmaxf(m, __shfl_xor(m, o));
    v0.x = __expf(v0.x - m); v0.y = __expf(v0.y - m);
    v0.z = __expf(v0.z - m); v0.w = __expf(v0.w - m);
    v1.x = __expf(v1.x - m); v1.y = __expf(v1.y - m);
    v1.z = __expf(v1.z - m); v1.w = __expf(v1.w - m);
    float s = v0.x + v0.y + v0.z + v0.w + v1.x + v1.y + v1.z + v1.w;
#pragma unroll
    for (int o = 32; o; o >>= 1) s += __shfl_xor(s, o);
    const float inv = 1.f / s;
    v0.x *= inv; v0.y *= inv; v0.z *= inv; v0.w *= inv;
    v1.x *= inv; v1.y *= inv; v1.z *= inv; v1.w *= inv;
    ((float4*)p)[lane * 2] = v0;
    ((float4*)p)[lane * 2 + 1] = v1;
}

// ---------------------------------------------------------------------------
// Softmax over s (axis 1, stride R): 512 threads = 128 cols x 4 s-groups
// ---------------------------------------------------------------------------
__global__ __launch_bounds__(512) void softmax_cols(const float* __restrict__ l,
                                                    float* __restrict__ as_)
{
    const int b = blockIdx.y;
    const int rl = threadIdx.x & 127;
    const int r = blockIdx.x * 128 + rl;
    const int sg = threadIdx.x >> 7;           // 0..3
    const int s0 = sg * (S_ / 4), s1 = s0 + S_ / 4;
    const float* base = l + (long)b * S_ * R_ + r;
    __shared__ float red[4][128];

    float pm = -1e30f;
    for (int s = s0; s < s1; ++s) pm = fmaxf(pm, base[(long)s * R_]);
    red[sg][rl] = pm;
    __syncthreads();
    const float m = fmaxf(fmaxf(red[0][rl], red[1][rl]), fmaxf(red[2][rl], red[3][rl]));
    __syncthreads();

    float ps = 0.f;
    for (int s = s0; s < s1; ++s) ps += __expf(base[(long)s * R_] - m);
    red[sg][rl] = ps;
    __syncthreads();
    const float inv = 1.f / (red[0][rl] + red[1][rl] + red[2][rl] + red[3][rl]);

    float* ob = as_ + (long)b * S_ * R_ + r;
    for (int s = s0; s < s1; ++s) ob[(long)s * R_] = __expf(base[(long)s * R_] - m) * inv;
}

// ---------------------------------------------------------------------------
// cat[b][h][s] = h_s[b][s][h]  (s_t half of cat_sc), 32x32 LDS tile transpose
// ---------------------------------------------------------------------------
__global__ __launch_bounds__(256) void transpose_hs(const float* __restrict__ hs,
                                                    float* __restrict__ cat)
{
    __shared__ float tile[32][33];
    const int b = blockIdx.z;
    const int s0 = blockIdx.x * 32, h0 = blockIdx.y * 32;
    const int tx = threadIdx.x, ty = threadIdx.y;
#pragma unroll
    for (int i = 0; i < 32; i += 8)
        tile[ty + i][tx] = hs[((long)b * S_ + s0 + ty + i) * H_ + h0 + tx];
    __syncthreads();
#pragma unroll
    for (int i = 0; i < 32; i += 8)
        cat[((long)b * 2 * H_ + h0 + ty + i) * S_ + s0 + tx] = tile[tx][ty + i];
}

// ---------------------------------------------------------------------------
// bf16 RTN pack helpers
// ---------------------------------------------------------------------------
__device__ inline unsigned pk_bf16(float lo, float hi)
{
    __hip_bfloat16 l = __float2bfloat16(lo);
    __hip_bfloat16 h = __float2bfloat16(hi);
    unsigned short ul, uh;
    __builtin_memcpy(&ul, &l, 2);
    __builtin_memcpy(&uh, &h, 2);
    return (unsigned)ul | ((unsigned)uh << 16);
}

// generic fp32 -> bf16 pack, 4 elems/thread
__global__ __launch_bounds__(256) void pack_bf16(const float* __restrict__ src,
                                                 unsigned short* __restrict__ dst,
                                                 long n4)
{
    const long i = (long)blockIdx.x * 256 + threadIdx.x;
    if (i >= n4) return;
    const float4 v = *((const float4*)src + i);
    uint2 u;
    u.x = pk_bf16(v.x, v.y);
    u.y = pk_bf16(v.z, v.w);
    *((uint2*)dst + i) = u;
}

// ---------------------------------------------------------------------------
// bin_bf16[t*B+b][0:1024] = bf16(c_r[b][t][:]); [1024:1536] = bf16(ref[t][b][:])
// ---------------------------------------------------------------------------
__global__ __launch_bounds__(256) void build_bin(const float* __restrict__ cr,
                                                 const float* __restrict__ ref,
                                                 unsigned short* __restrict__ binb)
{
    const long idx4 = (long)blockIdx.x * blockDim.x + threadIdx.x;
    if (idx4 >= (long)R_ * B_ * DIN_ / 4) return;
    const long f = idx4 * 4;
    const int d = (int)(f % DIN_);
    const long tb = f / DIN_;
    const int b = (int)(tb % B_);
    const int t = (int)(tb / B_);
    float4 v;
    if (d < 2 * H_) v = *(const float4*)(cr + ((long)b * R_ + t) * (2 * H_) + d);
    else            v = *(const float4*)(ref + ((long)t * B_ + b) * H_ + (d - 2 * H_));
    uint2 u;
    u.x = pk_bf16(v.x, v.y);
    u.y = pk_bf16(v.z, v.w);
    *((uint2*)binb + idx4) = u;
}

// ---------------------------------------------------------------------------
// One-time W_hh transpose + bf16(RTN) pack:
// WB[dir][q2][g] = uint4 of 8 bf16 = Whh_dir[g][8*q2 .. 8*q2+8)
// q2 = 4*kk + kgroup matches the MFMA B-fragment layout directly.
// ---------------------------------------------------------------------------
__global__ __launch_bounds__(256) void transpose_w_bf16(
    const float* __restrict__ Whh_f, const float* __restrict__ Whh_b,
    unsigned* __restrict__ WB)
{
    const int g = blockIdx.x * 256 + threadIdx.x;   // 0..1023
    const int q2 = blockIdx.y;                      // 0..31
    const int dir = blockIdx.z;
    const float* W = dir ? Whh_b : Whh_f;
    const float4 a = *(const float4*)(W + (long)g * HD_ + q2 * 8);
    const float4 b = *(const float4*)(W + (long)g * HD_ + q2 * 8 + 4);
    uint4 u;
    u.x = pk_bf16(a.x, a.y);
    u.y = pk_bf16(a.z, a.w);
    u.z = pk_bf16(b.x, b.y);
    u.w = pk_bf16(b.z, b.w);
    *((uint4*)WB + ((long)dir * 32 + q2) * 1024 + g) = u;
}

typedef __attribute__((ext_vector_type(4))) float f32x4;
typedef __attribute__((ext_vector_type(8))) short bf16x8;

__device__ inline bf16x8 u4_to_b8(uint4 u)
{
    bf16x8 r;
    __builtin_memcpy(&r, &u, 16);
    return r;
}

// ---------------------------------------------------------------------------
// Step-8 GEMM via MFMA: xg[m][n] = sum_k bin_bf[m][k]*Wih_bf[n][k] + bias(n)
// M=8192 (t*B+b), N=1024, K=1536; grid (N/64, M/64, 2 dirs), 256 thr.
// Wave w: N-tile n0+16w; 4 M-tiles. Global-fed (bin L3-resident, W L2).
// Fragment mapping per guide §3 (m89-verified, same as lstm_scan_m).
// ---------------------------------------------------------------------------
__global__ __launch_bounds__(256) void gemm_xg_mfma(
    const unsigned short* __restrict__ binb, const unsigned short* __restrict__ Wb,
    const float* __restrict__ bihf, const float* __restrict__ bhhf,
    const float* __restrict__ bihb, const float* __restrict__ bhhb,
    float* __restrict__ xgf2, float* __restrict__ xgb2)
{
    const int dir = blockIdx.z;
    const int n0 = blockIdx.x * 64;
    const int m0 = blockIdx.y * 64;
    const int lane = threadIdx.x & 63, w = threadIdx.x >> 6;
    const int lr = lane & 15, lk = lane >> 4;
    const unsigned short* Wd = Wb + (long)dir * G_ * DIN_;
    const float* bi = dir ? bihb : bihf;
    const float* bh = dir ? bhhb : bhhf;
    float* xg = dir ? xgb2 : xgf2;

    const int n = n0 + 16 * w + lr;
    const unsigned short* bp = Wd + (long)n * DIN_ + lk * 8;
    const unsigned short* ap = binb + (long)(m0 + lr) * DIN_ + lk * 8;

    f32x4 acc[4];
#pragma unroll
    for (int mi = 0; mi < 4; ++mi) acc[mi] = (f32x4){0.f, 0.f, 0.f, 0.f};

    for (int k0 = 0; k0 < DIN_; k0 += 32) {
        const bf16x8 bfr = *(const bf16x8*)(bp + k0);
#pragma unroll
        for (int mi = 0; mi < 4; ++mi) {
            const bf16x8 afr = *(const bf16x8*)(ap + (long)mi * 16 * DIN_ + k0);
            acc[mi] = __builtin_amdgcn_mfma_f32_16x16x32_bf16(afr, bfr, acc[mi], 0, 0, 0);
        }
    }
    const float bias = bi[n] + bh[n];
#pragma unroll
    for (int mi = 0; mi < 4; ++mi)
#pragma unroll
        for (int r = 0; r < 4; ++r) {
            const int m = m0 + 16 * mi + lk * 4 + r;
            xg[(long)m * G_ + n] = acc[mi][r] + bias;
        }
}

// ---------------------------------------------------------------------------
// Bi-LSTM scan v6 — MFMA, one block per DIRECTION. R13 showed the step is
// W-SUPPLY bound: 256 KB/step streamed at ~50 GB/s eff = 5us of the 6.5us
// step. v6 shifts residency up: kk0-3 in REGISTERS (wreg 8x4 = 128 VGPR),
// kk4-5 in LDS (128 KB), stream only kk6-7 (128 KB/step) with both
// buffers issued at the TOP of the step (covered by ~600cy of reg/LDS MFMAs).
// Everything else identical to v5 (one barrier/step, wave-local cell).
// ---------------------------------------------------------------------------
__device__ inline float sig_(float x) { return 1.f / (1.f + __expf(-x)); }
__device__ inline float tanh_(float x) {
    float ax = fabsf(x);
    float t = 1.f - 2.f / (1.f + __expf(2.f * ax));
    return copysignf(t, x);
}

#define MFMA8(KK, BEXPR)                                                     \
    {                                                                        \
        const bf16x8 a_ = *(const bf16x8*)(hrow + 32 * (KK));                \
        _Pragma("unroll")                                                    \
        for (int j = 0; j < 8; ++j)                                          \
            acc[j] = __builtin_amdgcn_mfma_f32_16x16x32_bf16(                \
                a_, u4_to_b8(BEXPR), acc[j], 0, 0, 0);                       \
    }

__global__ __launch_bounds__(512, 2) void lstm_scan_m(
    const float* __restrict__ xg_f, const float* __restrict__ xg_b,
    const uint4* __restrict__ WBu, float* __restrict__ out)
{
    const int dir = blockIdx.x;
    const float* xg = dir ? xg_b : xg_f;
    const uint4* Wg = WBu + (long)dir * 32768;     // [q2 0..31][row 0..1023]

    __shared__ uint4 Wc[8192];                      // 128 KB: q2 16..23 (kk 4,5)
    __shared__ unsigned short hp[2][16 * 264];      // 16.5 KB bf16 h, dbuf

    const int tid = threadIdx.x;
    const int lane = tid & 63, w = tid >> 6;
    const int lcol = lane & 15, lkg = lane >> 4;

    // fill Wc (q2 16..23 at offset 16384) + zero h_0
    for (int i = tid; i < 8192; i += 512) Wc[i] = Wg[16384 + i];
    for (int i = tid; i < 16 * 264; i += 512) hp[0][i] = 0;

    // wave w's 8 tiles: n_j = (j>>1)*16 + 2w + (j&1); nb = 16*n_j + lcol
    int nb[8];
#pragma unroll
    for (int j = 0; j < 8; ++j)
        nb[j] = ((((j >> 1) << 4) + 2 * w + (j & 1)) << 4) + lcol;

    // register-resident W: kk 0..3 (q2 = 4*kk + lkg)
    uint4 wreg[8][4];
#pragma unroll
    for (int kk = 0; kk < 4; ++kk)
#pragma unroll
        for (int j = 0; j < 8; ++j)
            wreg[j][kk] = Wg[(4 * kk + lkg) * 1024 + nb[j]];

    float c_reg[2][4] = {};
    uint4 sbA[8], sbB[8];
    __syncthreads();

    for (int t = 0; t < R_; ++t) {
        const int tt = dir ? (R_ - 1 - t) : t;
        const int p = t & 1;
        const unsigned short* hrow = &hp[p][lcol * 264 + lkg * 8];

        f32x4 acc[8];
#pragma unroll
        for (int j = 0; j < 8; ++j) acc[j] = (f32x4){0.f, 0.f, 0.f, 0.f};

        // issue BOTH streamed kk tiles up front (kk6: q2 24..27, kk7: 28..31)
#pragma unroll
        for (int j = 0; j < 8; ++j) sbA[j] = Wg[(24 + lkg) * 1024 + nb[j]];
#pragma unroll
        for (int j = 0; j < 8; ++j) sbB[j] = Wg[(28 + lkg) * 1024 + nb[j]];

        MFMA8(0, wreg[j][0])
        MFMA8(1, wreg[j][1])
        MFMA8(2, wreg[j][2])
        MFMA8(3, wreg[j][3])
        MFMA8(4, Wc[lkg * 1024 + nb[j]])
        MFMA8(5, Wc[(4 + lkg) * 1024 + nb[j]])
        MFMA8(6, sbA[j])
        MFMA8(7, sbB[j])

        // cell phase: lane owns cells (batch = lkg*4+r, col = 32w+16jj+lcol)
#pragma unroll
        for (int jj = 0; jj < 2; ++jj) {
#pragma unroll
            for (int r = 0; r < 4; ++r) {
                const int batch = lkg * 4 + r;
                const int col = 32 * w + 16 * jj + lcol;
                const long xb = ((long)tt * B_ + batch) * G_ + col;
                const float iv = acc[0 + jj][r] + xg[xb];
                const float fv = acc[2 + jj][r] + xg[xb + 256];
                const float gv = acc[4 + jj][r] + xg[xb + 512];
                const float ov = acc[6 + jj][r] + xg[xb + 768];
                float c = sig_(fv) * c_reg[jj][r] + sig_(iv) * tanh_(gv);
                c_reg[jj][r] = c;
                const float h = sig_(ov) * tanh_(c);
                out[((long)tt * B_ + batch) * (2 * HD_) + dir * HD_ + col] = h;
                unsigned u = __float_as_uint(h);
                u += 0x7FFFu + ((u >> 16) & 1);          // RTN to bf16
                hp[p ^ 1][batch * 264 + col] = (unsigned short)(u >> 16);
            }
        }
        __syncthreads();
    }
}

// ---------------------------------------------------------------------------
extern "C" void kernel_launch(void* const* d_in, const int* in_sizes, int n_in,
                              void* d_out, int out_size, void* d_ws, size_t ws_size,
                              hipStream_t stream)
{
    const float* src  = (const float*)d_in[1];   // [S][B][H]
    const float* ref  = (const float*)d_in[2];   // [R][B][H]
    const float* Wref = (const float*)d_in[3];   // [H][H]
    const float* bref = (const float*)d_in[4];   // [H]
    const float* Wihf = (const float*)d_in[5];   // [G][DIN]
    const float* Whhf = (const float*)d_in[6];   // [G][HD]
    const float* bihf = (const float*)d_in[7];
    const float* bhhf = (const float*)d_in[8];
    const float* Wihb = (const float*)d_in[9];
    const float* Whhb = (const float*)d_in[10];
    const float* bihb = (const float*)d_in[11];
    const float* bhhb = (const float*)d_in[12];
    float* out = (float*)d_out;                  // [R][B][2*HD]

    float* ws = (float*)d_ws;
    // workspace layout (floats), with aliasing:
    float* hs  = ws + 0L;                         // 8388608   [B][S][H]
    float* l   = ws + 8388608L;                   // 8388608   [B][S][R] (a_r in place)
    float* as_ = ws + 16777216L;                  // 8388608   [B][S][R]
    float* cat = ws + 25165824L;                  // 16777216  [B][2H][S]
    float* cr  = hs;                              // 8388608   [B][R][2H]  (hs dead after step 4)
    unsigned short* binb = (unsigned short*)cat;  // 25.2 MB bf16 [T*B][DIN] (cat dead after step 6)
    float* xgf = l;                               // 8388608   [T][B][G]   (l dead after step 6)
    float* xgb = as_;                             // 8388608   [T][B][G]   (as_ dead after step 5)
    unsigned* WB = (unsigned*)(ws + 41943040L);   // 1 MB: scan W bf16 (2 dir x 32 q2 x 1024 x uint4)
    unsigned short* Wib = (unsigned short*)(ws + 42205184L);  // 6 MB: W_ih bf16, both dirs

    // 0) one-time weight packs
    transpose_w_bf16<<<dim3(4, 32, 2), 256, 0, stream>>>(Whhf, Whhb, WB);
    pack_bf16<<<dim3((G_ * DIN_ / 4 + 255) / 256), 256, 0, stream>>>(
        Wihf, Wib, (long)G_ * DIN_ / 4);
    pack_bf16<<<dim3((G_ * DIN_ / 4 + 255) / 256), 256, 0, stream>>>(
        Wihb, Wib + (long)G_ * DIN_, (long)G_ * DIN_ / 4);

    // 1) h_s = tanh(src . Wref^T + bref)   [B*S, 512] k=512
    gemm_mk_nk<1, 1><<<dim3(8, 256, 1), 256, 0, stream>>>(
        src, H_, 0, Wref, H_, 0, hs, H_, 0, bref, nullptr, B_ * S_, H_, H_);

    // 2) l[b] = h_s[b] . h_r[b]^T   M=1024 N=512 K=512, batched over b
    gemm_mk_nk<0, 0><<<dim3(8, 16, B_), 256, 0, stream>>>(
        hs, H_, (long)S_ * H_, ref, (long)B_ * H_, H_, l, R_, (long)S_ * R_,
        nullptr, nullptr, S_, R_, H_);

    // 3) a_s = softmax over s (columns), then a_r = softmax over r in place
    softmax_cols<<<dim3(R_ / 128, B_), 512, 0, stream>>>(l, as_);
    softmax_rows<<<(B_ * S_) / 4, 256, 0, stream>>>(l);

    // 4) cat rows 0..511 = h_s transposed
    transpose_hs<<<dim3(S_ / 32, H_ / 32, B_), dim3(32, 8), 0, stream>>>(hs, cat);

    // 5) cat rows 512..1023: c_s[b,h,s] = sum_r ref[r,b,h]*a_s[b,s,r]
    gemm_km_nk<<<dim3(16, 8, B_), 256, 0, stream>>>(
        ref, (long)B_ * H_, H_, as_, R_, (long)S_ * R_,
        cat + (long)H_ * S_, S_, (long)2 * H_ * S_, H_, S_, R_);

    // 6) c_r[b,r,k] = sum_s cat[b,k,s]*a_r[b,s,r]   M=512 N=1024 K=1024
    gemm_km_nk<<<dim3(16, 8, B_), 256, 0, stream>>>(
        l, R_, (long)S_ * R_, cat, S_, (long)2 * H_ * S_,
        cr, 2 * H_, (long)R_ * 2 * H_, R_, 2 * H_, S_);

    // 7) bilstm_in -> bf16  (NOTE: overwrites cat region; cat dead after 6)
    build_bin<<<(R_ * B_ * DIN_ / 4 + 255) / 256, 256, 0, stream>>>(cr, ref, binb);

    // 8) xg = bin . W_ih^T + b_ih + b_hh  via MFMA, both dirs in one grid
    gemm_xg_mfma<<<dim3(G_ / 64, R_ * B_ / 64, 2), 256, 0, stream>>>(
        binb, Wib, bihf, bhhf, bihb, bhhb, xgf, xgb);

    // 9) bi-LSTM scan: 2 independent direction blocks, MFMA, zero sync
    lstm_scan_m<<<dim3(2), dim3(512), 0, stream>>>(xgf, xgb, (const uint4*)WB, out);
}

// Round 15
// 4374.763 us; speedup vs baseline: 2.4809x; 1.0268x over previous
//
#include <hip/hip_runtime.h>
#include <hip/hip_bf16.h>
#include <math.h>

#define B_   16
#define S_   1024
#define R_   512
#define H_   512
#define HD_  256
#define G_   1024
#define DIN_ 1536

// ---------------------------------------------------------------------------
// Tiled fp32 GEMM:  C[m][n] = sum_k A(m,k) * B(n,k)
// ---------------------------------------------------------------------------
template<int EPI, int REMAP_A>
__global__ __launch_bounds__(256) void gemm_mk_nk(
    const float* __restrict__ A, long a_rs, long a_bs,
    const float* __restrict__ Bm, long b_rs, long b_bs,
    float* __restrict__ C, long c_rs, long c_bs,
    const float* __restrict__ bias, const float* __restrict__ bias2,
    int M, int N, int K)
{
    __shared__ float As[16][68];
    __shared__ float Bs[16][68];
    const int bb = blockIdx.z;
    const float* Ab = A + (long)bb * a_bs;
    const float* Bb = Bm + (long)bb * b_bs;
    float* Cb = C + (long)bb * c_bs;
    const int m0 = blockIdx.y * 64, n0 = blockIdx.x * 64;
    const int tid = threadIdx.x;
    const int tx = tid & 15, ty = tid >> 4;
    const int lr = tid >> 2;          // tile row 0..63
    const int lk = (tid & 3) << 2;    // k offset 0..12

    long arow;
    {
        int m = m0 + lr;
        if (REMAP_A) arow = (long)((m % S_) * B_ + (m / S_)) * a_rs;
        else         arow = (long)m * a_rs;
    }
    const long brow = (long)(n0 + lr) * b_rs;

    float acc[4][4] = {};
    for (int k0 = 0; k0 < K; k0 += 16) {
        float4 av = *(const float4*)(Ab + arow + k0 + lk);
        float4 bv = *(const float4*)(Bb + brow + k0 + lk);
        As[lk + 0][lr] = av.x; As[lk + 1][lr] = av.y;
        As[lk + 2][lr] = av.z; As[lk + 3][lr] = av.w;
        Bs[lk + 0][lr] = bv.x; Bs[lk + 1][lr] = bv.y;
        Bs[lk + 2][lr] = bv.z; Bs[lk + 3][lr] = bv.w;
        __syncthreads();
#pragma unroll
        for (int kk = 0; kk < 16; ++kk) {
            float4 a = *(const float4*)&As[kk][ty << 2];
            float4 b = *(const float4*)&Bs[kk][tx << 2];
            acc[0][0] += a.x * b.x; acc[0][1] += a.x * b.y; acc[0][2] += a.x * b.z; acc[0][3] += a.x * b.w;
            acc[1][0] += a.y * b.x; acc[1][1] += a.y * b.y; acc[1][2] += a.y * b.z; acc[1][3] += a.y * b.w;
            acc[2][0] += a.z * b.x; acc[2][1] += a.z * b.y; acc[2][2] += a.z * b.z; acc[2][3] += a.z * b.w;
            acc[3][0] += a.w * b.x; acc[3][1] += a.w * b.y; acc[3][2] += a.w * b.z; acc[3][3] += a.w * b.w;
        }
        __syncthreads();
    }
#pragma unroll
    for (int i = 0; i < 4; ++i) {
        const int m = m0 + (ty << 2) + i;
#pragma unroll
        for (int j = 0; j < 4; ++j) {
            const int n = n0 + (tx << 2) + j;
            float v = acc[i][j];
            if (EPI == 1) v = tanhf(v + bias[n]);
            else if (EPI == 2) v += bias[n] + bias2[n];
            Cb[(long)m * c_rs + n] = v;
        }
    }
}

// ---------------------------------------------------------------------------
// Tiled fp32 GEMM:  C[m][n] = sum_k A(k,m) * B(n,k)
// ---------------------------------------------------------------------------
__global__ __launch_bounds__(256) void gemm_km_nk(
    const float* __restrict__ A, long a_ks, long a_bs,
    const float* __restrict__ Bm, long b_rs, long b_bs,
    float* __restrict__ C, long c_rs, long c_bs,
    int M, int N, int K)
{
    __shared__ float As[16][68];
    __shared__ float Bs[16][68];
    const int bb = blockIdx.z;
    const float* Ab = A + (long)bb * a_bs;
    const float* Bb = Bm + (long)bb * b_bs;
    float* Cb = C + (long)bb * c_bs;
    const int m0 = blockIdx.y * 64, n0 = blockIdx.x * 64;
    const int tid = threadIdx.x;
    const int tx = tid & 15, ty = tid >> 4;
    const int lr = tid >> 2;            // B tile row (n) 0..63
    const int lk = (tid & 3) << 2;      // B k offset
    const int alk = tid >> 4;           // A k row 0..15
    const int alm = (tid & 15) << 2;    // A m offset
    const long brow = (long)(n0 + lr) * b_rs;

    float acc[4][4] = {};
    for (int k0 = 0; k0 < K; k0 += 16) {
        float4 av = *(const float4*)(Ab + (long)(k0 + alk) * a_ks + m0 + alm);
        *(float4*)&As[alk][alm] = av;
        float4 bv = *(const float4*)(Bb + brow + k0 + lk);
        Bs[lk + 0][lr] = bv.x; Bs[lk + 1][lr] = bv.y;
        Bs[lk + 2][lr] = bv.z; Bs[lk + 3][lr] = bv.w;
        __syncthreads();
#pragma unroll
        for (int kk = 0; kk < 16; ++kk) {
            float4 a = *(const float4*)&As[kk][ty << 2];
            float4 b = *(const float4*)&Bs[kk][tx << 2];
            acc[0][0] += a.x * b.x; acc[0][1] += a.x * b.y; acc[0][2] += a.x * b.z; acc[0][3] += a.x * b.w;
            acc[1][0] += a.y * b.x; acc[1][1] += a.y * b.y; acc[1][2] += a.y * b.z; acc[1][3] += a.y * b.w;
            acc[2][0] += a.z * b.x; acc[2][1] += a.z * b.y; acc[2][2] += a.z * b.z; acc[2][3] += a.z * b.w;
            acc[3][0] += a.w * b.x; acc[3][1] += a.w * b.y; acc[3][2] += a.w * b.z; acc[3][3] += a.w * b.w;
        }
        __syncthreads();
    }
#pragma unroll
    for (int i = 0; i < 4; ++i) {
        const int m = m0 + (ty << 2) + i;
#pragma unroll
        for (int j = 0; j < 4; ++j) {
            const int n = n0 + (tx << 2) + j;
            Cb[(long)m * c_rs + n] = acc[i][j];
        }
    }
}

// ---------------------------------------------------------------------------
// Softmax over r (last axis, contiguous, 512 elems): one wave per row, in-place
// ---------------------------------------------------------------------------
__global__ __launch_bounds__(256) void softmax_rows(float* __restrict__ l)
{
    const int lane = threadIdx.x & 63;
    const int wv = threadIdx.x >> 6;
    const long row = (long)blockIdx.x * 4 + wv;
    float* p = l + row * R_;
    float4 v0 = ((const float4*)p)[lane * 2];
    float4 v1 = ((const float4*)p)[lane * 2 + 1];
    float m = fmaxf(fmaxf(fmaxf(v0.x, v0.y), fmaxf(v0.z, v0.w)),
                    fmaxf(fmaxf(v1.x, v1.y), fmaxf(v1.z, v1.w)));
#pragma unroll
    for (int o = 32; o; o >>= 1) m = fmaxf(m, __shfl_xor(m, o));
    v0.x = __expf(v0.x - m); v0.y = __expf(v0.y - m);
    v0.z = __expf(v0.z - m); v0.w = __expf(v0.w - m);
    v1.x = __expf(v1.x - m); v1.y = __expf(v1.y - m);
    v1.z = __expf(v1.z - m); v1.w = __expf(v1.w - m);
    float s = v0.x + v0.y + v0.z + v0.w + v1.x + v1.y + v1.z + v1.w;
#pragma unroll
    for (int o = 32; o; o >>= 1) s += __shfl_xor(s, o);
    const float inv = 1.f / s;
    v0.x *= inv; v0.y *= inv; v0.z *= inv; v0.w *= inv;
    v1.x *= inv; v1.y *= inv; v1.z *= inv; v1.w *= inv;
    ((float4*)p)[lane * 2] = v0;
    ((float4*)p)[lane * 2 + 1] = v1;
}

// ---------------------------------------------------------------------------
// Softmax over s (axis 1, stride R): 512 threads = 128 cols x 4 s-groups
// ---------------------------------------------------------------------------
__global__ __launch_bounds__(512) void softmax_cols(const float* __restrict__ l,
                                                    float* __restrict__ as_)
{
    const int b = blockIdx.y;
    const int rl = threadIdx.x & 127;
    const int r = blockIdx.x * 128 + rl;
    const int sg = threadIdx.x >> 7;           // 0..3
    const int s0 = sg * (S_ / 4), s1 = s0 + S_ / 4;
    const float* base = l + (long)b * S_ * R_ + r;
    __shared__ float red[4][128];

    float pm = -1e30f;
    for (int s = s0; s < s1; ++s) pm = fmaxf(pm, base[(long)s * R_]);
    red[sg][rl] = pm;
    __syncthreads();
    const float m = fmaxf(fmaxf(red[0][rl], red[1][rl]), fmaxf(red[2][rl], red[3][rl]));
    __syncthreads();

    float ps = 0.f;
    for (int s = s0; s < s1; ++s) ps += __expf(base[(long)s * R_] - m);
    red[sg][rl] = ps;
    __syncthreads();
    const float inv = 1.f / (red[0][rl] + red[1][rl] + red[2][rl] + red[3][rl]);

    float* ob = as_ + (long)b * S_ * R_ + r;
    for (int s = s0; s < s1; ++s) ob[(long)s * R_] = __expf(base[(long)s * R_] - m) * inv;
}

// ---------------------------------------------------------------------------
// cat[b][h][s] = h_s[b][s][h]  (s_t half of cat_sc), 32x32 LDS tile transpose
// ---------------------------------------------------------------------------
__global__ __launch_bounds__(256) void transpose_hs(const float* __restrict__ hs,
                                                    float* __restrict__ cat)
{
    __shared__ float tile[32][33];
    const int b = blockIdx.z;
    const int s0 = blockIdx.x * 32, h0 = blockIdx.y * 32;
    const int tx = threadIdx.x, ty = threadIdx.y;
#pragma unroll
    for (int i = 0; i < 32; i += 8)
        tile[ty + i][tx] = hs[((long)b * S_ + s0 + ty + i) * H_ + h0 + tx];
    __syncthreads();
#pragma unroll
    for (int i = 0; i < 32; i += 8)
        cat[((long)b * 2 * H_ + h0 + ty + i) * S_ + s0 + tx] = tile[tx][ty + i];
}

// ---------------------------------------------------------------------------
// bf16 RTN pack helpers
// ---------------------------------------------------------------------------
__device__ inline unsigned pk_bf16(float lo, float hi)
{
    __hip_bfloat16 l = __float2bfloat16(lo);
    __hip_bfloat16 h = __float2bfloat16(hi);
    unsigned short ul, uh;
    __builtin_memcpy(&ul, &l, 2);
    __builtin_memcpy(&uh, &h, 2);
    return (unsigned)ul | ((unsigned)uh << 16);
}

// generic fp32 -> bf16 pack, 4 elems/thread
__global__ __launch_bounds__(256) void pack_bf16(const float* __restrict__ src,
                                                 unsigned short* __restrict__ dst,
                                                 long n4)
{
    const long i = (long)blockIdx.x * 256 + threadIdx.x;
    if (i >= n4) return;
    const float4 v = *((const float4*)src + i);
    uint2 u;
    u.x = pk_bf16(v.x, v.y);
    u.y = pk_bf16(v.z, v.w);
    *((uint2*)dst + i) = u;
}

// ---------------------------------------------------------------------------
// bin_bf16[t*B+b][0:1024] = bf16(c_r[b][t][:]); [1024:1536] = bf16(ref[t][b][:])
// ---------------------------------------------------------------------------
__global__ __launch_bounds__(256) void build_bin(const float* __restrict__ cr,
                                                 const float* __restrict__ ref,
                                                 unsigned short* __restrict__ binb)
{
    const long idx4 = (long)blockIdx.x * blockDim.x + threadIdx.x;
    if (idx4 >= (long)R_ * B_ * DIN_ / 4) return;
    const long f = idx4 * 4;
    const int d = (int)(f % DIN_);
    const long tb = f / DIN_;
    const int b = (int)(tb % B_);
    const int t = (int)(tb / B_);
    float4 v;
    if (d < 2 * H_) v = *(const float4*)(cr + ((long)b * R_ + t) * (2 * H_) + d);
    else            v = *(const float4*)(ref + ((long)t * B_ + b) * H_ + (d - 2 * H_));
    uint2 u;
    u.x = pk_bf16(v.x, v.y);
    u.y = pk_bf16(v.z, v.w);
    *((uint2*)binb + idx4) = u;
}

// ---------------------------------------------------------------------------
// One-time W_hh transpose + bf16(RTN) pack:
// WB[dir][q2][g] = uint4 of 8 bf16 = Whh_dir[g][8*q2 .. 8*q2+8)
// q2 = 4*kk + kgroup matches the MFMA B-fragment layout directly.
// ---------------------------------------------------------------------------
__global__ __launch_bounds__(256) void transpose_w_bf16(
    const float* __restrict__ Whh_f, const float* __restrict__ Whh_b,
    unsigned* __restrict__ WB)
{
    const int g = blockIdx.x * 256 + threadIdx.x;   // 0..1023
    const int q2 = blockIdx.y;                      // 0..31
    const int dir = blockIdx.z;
    const float* W = dir ? Whh_b : Whh_f;
    const float4 a = *(const float4*)(W + (long)g * HD_ + q2 * 8);
    const float4 b = *(const float4*)(W + (long)g * HD_ + q2 * 8 + 4);
    uint4 u;
    u.x = pk_bf16(a.x, a.y);
    u.y = pk_bf16(a.z, a.w);
    u.z = pk_bf16(b.x, b.y);
    u.w = pk_bf16(b.z, b.w);
    *((uint4*)WB + ((long)dir * 32 + q2) * 1024 + g) = u;
}

typedef __attribute__((ext_vector_type(4))) float f32x4;
typedef __attribute__((ext_vector_type(8))) short bf16x8;

__device__ inline bf16x8 u4_to_b8(uint4 u)
{
    bf16x8 r;
    __builtin_memcpy(&r, &u, 16);
    return r;
}

// ---------------------------------------------------------------------------
// Step-8 GEMM via MFMA: xg[m][n] = sum_k bin_bf[m][k]*Wih_bf[n][k] + bias(n)
// ---------------------------------------------------------------------------
__global__ __launch_bounds__(256) void gemm_xg_mfma(
    const unsigned short* __restrict__ binb, const unsigned short* __restrict__ Wb,
    const float* __restrict__ bihf, const float* __restrict__ bhhf,
    const float* __restrict__ bihb, const float* __restrict__ bhhb,
    float* __restrict__ xgf2, float* __restrict__ xgb2)
{
    const int dir = blockIdx.z;
    const int n0 = blockIdx.x * 64;
    const int m0 = blockIdx.y * 64;
    const int lane = threadIdx.x & 63, w = threadIdx.x >> 6;
    const int lr = lane & 15, lk = lane >> 4;
    const unsigned short* Wd = Wb + (long)dir * G_ * DIN_;
    const float* bi = dir ? bihb : bihf;
    const float* bh = dir ? bhhb : bhhf;
    float* xg = dir ? xgb2 : xgf2;

    const int n = n0 + 16 * w + lr;
    const unsigned short* bp = Wd + (long)n * DIN_ + lk * 8;
    const unsigned short* ap = binb + (long)(m0 + lr) * DIN_ + lk * 8;

    f32x4 acc[4];
#pragma unroll
    for (int mi = 0; mi < 4; ++mi) acc[mi] = (f32x4){0.f, 0.f, 0.f, 0.f};

    for (int k0 = 0; k0 < DIN_; k0 += 32) {
        const bf16x8 bfr = *(const bf16x8*)(bp + k0);
#pragma unroll
        for (int mi = 0; mi < 4; ++mi) {
            const bf16x8 afr = *(const bf16x8*)(ap + (long)mi * 16 * DIN_ + k0);
            acc[mi] = __builtin_amdgcn_mfma_f32_16x16x32_bf16(afr, bfr, acc[mi], 0, 0, 0);
        }
    }
    const float bias = bi[n] + bh[n];
#pragma unroll
    for (int mi = 0; mi < 4; ++mi)
#pragma unroll
        for (int r = 0; r < 4; ++r) {
            const int m = m0 + 16 * mi + lk * 4 + r;
            xg[(long)m * G_ + n] = acc[mi][r] + bias;
        }
}

// ---------------------------------------------------------------------------
// Bi-LSTM scan v7 — MFMA, one block/direction, 1024 threads (16 waves).
// R13/R14 post-mortem: the compiler DEMOTED the big wreg arrays (VGPR=128,
// FETCH identical both rounds) -> every phase re-loaded W from L2 with
// exposed latency. v7 engineers for the 128-VGPR cap:
//  - 16 waves x 4 tiles (one 16-col slice x 4 gates) -> cell wave-local,
//    acc only 16 VGPRs, 2x TLP for latency hiding
//  - THREE 4-uint4 rotating stream slots (48 VGPR, no demote risk) over the
//    6 streamed kk {0,1,2,3,6,7}, issue >= 2 phases ahead; next step's
//    first 3 kk issue BEFORE cell so the barrier vmcnt drain is covered
//  - kk4-5 stay in 128 KB LDS Wc; xg prefetched at step top
// ---------------------------------------------------------------------------
__device__ inline float sig_(float x) { return 1.f / (1.f + __expf(-x)); }
__device__ inline float tanh_(float x) {
    float ax = fabsf(x);
    float t = 1.f - 2.f / (1.f + __expf(2.f * ax));
    return copysignf(t, x);
}

// 4 MFMAs of one K-step (4 tiles/wave); BEXPR may use loop var j
#define MFMA4(KK, BEXPR)                                                     \
    {                                                                        \
        const bf16x8 a_ = *(const bf16x8*)(hrow + 32 * (KK));                \
        _Pragma("unroll")                                                    \
        for (int j = 0; j < 4; ++j)                                          \
            acc[j] = __builtin_amdgcn_mfma_f32_16x16x32_bf16(                \
                a_, u4_to_b8(BEXPR), acc[j], 0, 0, 0);                       \
    }

#define LOADS(S, Q2)                                                         \
    {                                                                        \
        _Pragma("unroll")                                                    \
        for (int j = 0; j < 4; ++j) S[j] = Wg[((Q2) + lkg) * 1024 + nb[j]];  \
    }

__global__ __launch_bounds__(1024, 4) void lstm_scan_m(
    const float* __restrict__ xg_f, const float* __restrict__ xg_b,
    const uint4* __restrict__ WBu, float* __restrict__ out)
{
    const int dir = blockIdx.x;
    const float* xg = dir ? xg_b : xg_f;
    const uint4* Wg = WBu + (long)dir * 32768;     // [q2 0..31][row 0..1023]

    __shared__ uint4 Wc[8192];                      // 128 KB: q2 16..23 (kk 4,5)
    __shared__ unsigned short hp[2][16 * 264];      // 16.9 KB bf16 h, dbuf

    const int tid = threadIdx.x;
    const int lane = tid & 63, w = tid >> 6;        // w = 0..15 (col-slice)
    const int lcol = lane & 15, lkg = lane >> 4;

    for (int i = tid; i < 8192; i += 1024) Wc[i] = Wg[16384 + i];
    for (int i = tid; i < 16 * 264; i += 1024) hp[0][i] = 0;

    // wave w's 4 tiles: T_j = 16*j + w (gate j, col-slice w)
    int nb[4];
#pragma unroll
    for (int j = 0; j < 4; ++j) nb[j] = ((16 * j + w) << 4) + lcol;

    float c_reg[4] = {};
    uint4 s0[4], s1[4], s2[4];
    __syncthreads();

    // prologue: first 3 streamed kk in flight
    LOADS(s0, 0)    // kk0
    LOADS(s1, 4)    // kk1
    LOADS(s2, 8)    // kk2

    for (int t = 0; t < R_; ++t) {
        const int tt = dir ? (R_ - 1 - t) : t;
        const int p = t & 1;
        const unsigned short* hrow = &hp[p][lcol * 264 + lkg * 8];

        // prefetch xg for the cell phase (HBM latency hides under the dot)
        float xgv[4][4];
#pragma unroll
        for (int g = 0; g < 4; ++g)
#pragma unroll
            for (int r = 0; r < 4; ++r)
                xgv[g][r] = xg[((long)tt * B_ + lkg * 4 + r) * G_
                               + g * 256 + 16 * w + lcol];

        f32x4 acc[4];
#pragma unroll
        for (int j = 0; j < 4; ++j) acc[j] = (f32x4){0.f, 0.f, 0.f, 0.f};

        MFMA4(4, Wc[lkg * 1024 + nb[j]])         // LDS-fed, covers s0..s2
        MFMA4(5, Wc[(4 + lkg) * 1024 + nb[j]])
        MFMA4(0, s0[j])
        LOADS(s0, 12)   // kk3
        MFMA4(1, s1[j])
        LOADS(s1, 24)   // kk6
        MFMA4(2, s2[j])
        LOADS(s2, 28)   // kk7
        MFMA4(3, s0[j])
        MFMA4(6, s1[j])
        MFMA4(7, s2[j])
        // next step's first 3 kk: complete during cell + barrier drain
        LOADS(s0, 0)
        LOADS(s1, 4)
        LOADS(s2, 8)

        // cell: lane owns (batch = lkg*4+r, col = 16w + lcol), 4 cells
#pragma unroll
        for (int r = 0; r < 4; ++r) {
            const int batch = lkg * 4 + r;
            const int col = 16 * w + lcol;
            const float iv = acc[0][r] + xgv[0][r];
            const float fv = acc[1][r] + xgv[1][r];
            const float gv = acc[2][r] + xgv[2][r];
            const float ov = acc[3][r] + xgv[3][r];
            float c = sig_(fv) * c_reg[r] + sig_(iv) * tanh_(gv);
            c_reg[r] = c;
            const float h = sig_(ov) * tanh_(c);
            out[((long)tt * B_ + batch) * (2 * HD_) + dir * HD_ + col] = h;
            unsigned u = __float_as_uint(h);
            u += 0x7FFFu + ((u >> 16) & 1);          // RTN to bf16
            hp[p ^ 1][batch * 264 + col] = (unsigned short)(u >> 16);
        }
        __syncthreads();
    }
}

// ---------------------------------------------------------------------------
extern "C" void kernel_launch(void* const* d_in, const int* in_sizes, int n_in,
                              void* d_out, int out_size, void* d_ws, size_t ws_size,
                              hipStream_t stream)
{
    const float* src  = (const float*)d_in[1];   // [S][B][H]
    const float* ref  = (const float*)d_in[2];   // [R][B][H]
    const float* Wref = (const float*)d_in[3];   // [H][H]
    const float* bref = (const float*)d_in[4];   // [H]
    const float* Wihf = (const float*)d_in[5];   // [G][DIN]
    const float* Whhf = (const float*)d_in[6];   // [G][HD]
    const float* bihf = (const float*)d_in[7];
    const float* bhhf = (const float*)d_in[8];
    const float* Wihb = (const float*)d_in[9];
    const float* Whhb = (const float*)d_in[10];
    const float* bihb = (const float*)d_in[11];
    const float* bhhb = (const float*)d_in[12];
    float* out = (float*)d_out;                  // [R][B][2*HD]

    float* ws = (float*)d_ws;
    // workspace layout (floats), with aliasing:
    float* hs  = ws + 0L;                         // 8388608   [B][S][H]
    float* l   = ws + 8388608L;                   // 8388608   [B][S][R] (a_r in place)
    float* as_ = ws + 16777216L;                  // 8388608   [B][S][R]
    float* cat = ws + 25165824L;                  // 16777216  [B][2H][S]
    float* cr  = hs;                              // 8388608   [B][R][2H]  (hs dead after step 4)
    unsigned short* binb = (unsigned short*)cat;  // 25.2 MB bf16 [T*B][DIN] (cat dead after step 6)
    float* xgf = l;                               // 8388608   [T][B][G]   (l dead after step 6)
    float* xgb = as_;                             // 8388608   [T][B][G]   (as_ dead after step 5)
    unsigned* WB = (unsigned*)(ws + 41943040L);   // 1 MB: scan W bf16 (2 dir x 32 q2 x 1024 x uint4)
    unsigned short* Wib = (unsigned short*)(ws + 42205184L);  // 6 MB: W_ih bf16, both dirs

    // 0) one-time weight packs
    transpose_w_bf16<<<dim3(4, 32, 2), 256, 0, stream>>>(Whhf, Whhb, WB);
    pack_bf16<<<dim3((G_ * DIN_ / 4 + 255) / 256), 256, 0, stream>>>(
        Wihf, Wib, (long)G_ * DIN_ / 4);
    pack_bf16<<<dim3((G_ * DIN_ / 4 + 255) / 256), 256, 0, stream>>>(
        Wihb, Wib + (long)G_ * DIN_, (long)G_ * DIN_ / 4);

    // 1) h_s = tanh(src . Wref^T + bref)   [B*S, 512] k=512
    gemm_mk_nk<1, 1><<<dim3(8, 256, 1), 256, 0, stream>>>(
        src, H_, 0, Wref, H_, 0, hs, H_, 0, bref, nullptr, B_ * S_, H_, H_);

    // 2) l[b] = h_s[b] . h_r[b]^T   M=1024 N=512 K=512, batched over b
    gemm_mk_nk<0, 0><<<dim3(8, 16, B_), 256, 0, stream>>>(
        hs, H_, (long)S_ * H_, ref, (long)B_ * H_, H_, l, R_, (long)S_ * R_,
        nullptr, nullptr, S_, R_, H_);

    // 3) a_s = softmax over s (columns), then a_r = softmax over r in place
    softmax_cols<<<dim3(R_ / 128, B_), 512, 0, stream>>>(l, as_);
    softmax_rows<<<(B_ * S_) / 4, 256, 0, stream>>>(l);

    // 4) cat rows 0..511 = h_s transposed
    transpose_hs<<<dim3(S_ / 32, H_ / 32, B_), dim3(32, 8), 0, stream>>>(hs, cat);

    // 5) cat rows 512..1023: c_s[b,h,s] = sum_r ref[r,b,h]*a_s[b,s,r]
    gemm_km_nk<<<dim3(16, 8, B_), 256, 0, stream>>>(
        ref, (long)B_ * H_, H_, as_, R_, (long)S_ * R_,
        cat + (long)H_ * S_, S_, (long)2 * H_ * S_, H_, S_, R_);

    // 6) c_r[b,r,k] = sum_s cat[b,k,s]*a_r[b,s,r]   M=512 N=1024 K=1024
    gemm_km_nk<<<dim3(16, 8, B_), 256, 0, stream>>>(
        l, R_, (long)S_ * R_, cat, S_, (long)2 * H_ * S_,
        cr, 2 * H_, (long)R_ * 2 * H_, R_, 2 * H_, S_);

    // 7) bilstm_in -> bf16  (NOTE: overwrites cat region; cat dead after 6)
    build_bin<<<(R_ * B_ * DIN_ / 4 + 255) / 256, 256, 0, stream>>>(cr, ref, binb);

    // 8) xg = bin . W_ih^T + b_ih + b_hh  via MFMA, both dirs in one grid
    gemm_xg_mfma<<<dim3(G_ / 64, R_ * B_ / 64, 2), 256, 0, stream>>>(
        binb, Wib, bihf, bhhf, bihb, bhhb, xgf, xgb);

    // 9) bi-LSTM scan: 2 independent direction blocks, MFMA, 16 waves, zero sync
    lstm_scan_m<<<dim3(2), dim3(1024), 0, stream>>>(xgf, xgb, (const uint4*)WB, out);
}

// Round 17
// 4327.864 us; speedup vs baseline: 2.5077x; 1.0108x over previous
//
#include <hip/hip_runtime.h>
#include <hip/hip_bf16.h>
#include <math.h>

#define B_   16
#define S_   1024
#define R_   512
#define H_   512
#define HD_  256
#define G_   1024
#define DIN_ 1536

// ---------------------------------------------------------------------------
// Tiled fp32 GEMM:  C[m][n] = sum_k A(m,k) * B(n,k)
// ---------------------------------------------------------------------------
template<int EPI, int REMAP_A>
__global__ __launch_bounds__(256) void gemm_mk_nk(
    const float* __restrict__ A, long a_rs, long a_bs,
    const float* __restrict__ Bm, long b_rs, long b_bs,
    float* __restrict__ C, long c_rs, long c_bs,
    const float* __restrict__ bias, const float* __restrict__ bias2,
    int M, int N, int K)
{
    __shared__ float As[16][68];
    __shared__ float Bs[16][68];
    const int bb = blockIdx.z;
    const float* Ab = A + (long)bb * a_bs;
    const float* Bb = Bm + (long)bb * b_bs;
    float* Cb = C + (long)bb * c_bs;
    const int m0 = blockIdx.y * 64, n0 = blockIdx.x * 64;
    const int tid = threadIdx.x;
    const int tx = tid & 15, ty = tid >> 4;
    const int lr = tid >> 2;          // tile row 0..63
    const int lk = (tid & 3) << 2;    // k offset 0..12

    long arow;
    {
        int m = m0 + lr;
        if (REMAP_A) arow = (long)((m % S_) * B_ + (m / S_)) * a_rs;
        else         arow = (long)m * a_rs;
    }
    const long brow = (long)(n0 + lr) * b_rs;

    float acc[4][4] = {};
    for (int k0 = 0; k0 < K; k0 += 16) {
        float4 av = *(const float4*)(Ab + arow + k0 + lk);
        float4 bv = *(const float4*)(Bb + brow + k0 + lk);
        As[lk + 0][lr] = av.x; As[lk + 1][lr] = av.y;
        As[lk + 2][lr] = av.z; As[lk + 3][lr] = av.w;
        Bs[lk + 0][lr] = bv.x; Bs[lk + 1][lr] = bv.y;
        Bs[lk + 2][lr] = bv.z; Bs[lk + 3][lr] = bv.w;
        __syncthreads();
#pragma unroll
        for (int kk = 0; kk < 16; ++kk) {
            float4 a = *(const float4*)&As[kk][ty << 2];
            float4 b = *(const float4*)&Bs[kk][tx << 2];
            acc[0][0] += a.x * b.x; acc[0][1] += a.x * b.y; acc[0][2] += a.x * b.z; acc[0][3] += a.x * b.w;
            acc[1][0] += a.y * b.x; acc[1][1] += a.y * b.y; acc[1][2] += a.y * b.z; acc[1][3] += a.y * b.w;
            acc[2][0] += a.z * b.x; acc[2][1] += a.z * b.y; acc[2][2] += a.z * b.z; acc[2][3] += a.z * b.w;
            acc[3][0] += a.w * b.x; acc[3][1] += a.w * b.y; acc[3][2] += a.w * b.z; acc[3][3] += a.w * b.w;
        }
        __syncthreads();
    }
#pragma unroll
    for (int i = 0; i < 4; ++i) {
        const int m = m0 + (ty << 2) + i;
#pragma unroll
        for (int j = 0; j < 4; ++j) {
            const int n = n0 + (tx << 2) + j;
            float v = acc[i][j];
            if (EPI == 1) v = tanhf(v + bias[n]);
            else if (EPI == 2) v += bias[n] + bias2[n];
            Cb[(long)m * c_rs + n] = v;
        }
    }
}

// ---------------------------------------------------------------------------
// Tiled fp32 GEMM:  C[m][n] = sum_k A(k,m) * B(n,k)
// ---------------------------------------------------------------------------
__global__ __launch_bounds__(256) void gemm_km_nk(
    const float* __restrict__ A, long a_ks, long a_bs,
    const float* __restrict__ Bm, long b_rs, long b_bs,
    float* __restrict__ C, long c_rs, long c_bs,
    int M, int N, int K)
{
    __shared__ float As[16][68];
    __shared__ float Bs[16][68];
    const int bb = blockIdx.z;
    const float* Ab = A + (long)bb * a_bs;
    const float* Bb = Bm + (long)bb * b_bs;
    float* Cb = C + (long)bb * c_bs;
    const int m0 = blockIdx.y * 64, n0 = blockIdx.x * 64;
    const int tid = threadIdx.x;
    const int tx = tid & 15, ty = tid >> 4;
    const int lr = tid >> 2;            // B tile row (n) 0..63
    const int lk = (tid & 3) << 2;      // B k offset
    const int alk = tid >> 4;           // A k row 0..15
    const int alm = (tid & 15) << 2;    // A m offset
    const long brow = (long)(n0 + lr) * b_rs;

    float acc[4][4] = {};
    for (int k0 = 0; k0 < K; k0 += 16) {
        float4 av = *(const float4*)(Ab + (long)(k0 + alk) * a_ks + m0 + alm);
        *(float4*)&As[alk][alm] = av;
        float4 bv = *(const float4*)(Bb + brow + k0 + lk);
        Bs[lk + 0][lr] = bv.x; Bs[lk + 1][lr] = bv.y;
        Bs[lk + 2][lr] = bv.z; Bs[lk + 3][lr] = bv.w;
        __syncthreads();
#pragma unroll
        for (int kk = 0; kk < 16; ++kk) {
            float4 a = *(const float4*)&As[kk][ty << 2];
            float4 b = *(const float4*)&Bs[kk][tx << 2];
            acc[0][0] += a.x * b.x; acc[0][1] += a.x * b.y; acc[0][2] += a.x * b.z; acc[0][3] += a.x * b.w;
            acc[1][0] += a.y * b.x; acc[1][1] += a.y * b.y; acc[1][2] += a.y * b.z; acc[1][3] += a.y * b.w;
            acc[2][0] += a.z * b.x; acc[2][1] += a.z * b.y; acc[2][2] += a.z * b.z; acc[2][3] += a.z * b.w;
            acc[3][0] += a.w * b.x; acc[3][1] += a.w * b.y; acc[3][2] += a.w * b.z; acc[3][3] += a.w * b.w;
        }
        __syncthreads();
    }
#pragma unroll
    for (int i = 0; i < 4; ++i) {
        const int m = m0 + (ty << 2) + i;
#pragma unroll
        for (int j = 0; j < 4; ++j) {
            const int n = n0 + (tx << 2) + j;
            Cb[(long)m * c_rs + n] = acc[i][j];
        }
    }
}

// ---------------------------------------------------------------------------
// Softmax over r (last axis, contiguous, 512 elems): one wave per row, in-place
// ---------------------------------------------------------------------------
__global__ __launch_bounds__(256) void softmax_rows(float* __restrict__ l)
{
    const int lane = threadIdx.x & 63;
    const int wv = threadIdx.x >> 6;
    const long row = (long)blockIdx.x * 4 + wv;
    float* p = l + row * R_;
    float4 v0 = ((const float4*)p)[lane * 2];
    float4 v1 = ((const float4*)p)[lane * 2 + 1];
    float m = fmaxf(fmaxf(fmaxf(v0.x, v0.y), fmaxf(v0.z, v0.w)),
                    fmaxf(fmaxf(v1.x, v1.y), fmaxf(v1.z, v1.w)));
#pragma unroll
    for (int o = 32; o; o >>= 1) m = fmaxf(m, __shfl_xor(m, o));
    v0.x = __expf(v0.x - m); v0.y = __expf(v0.y - m);
    v0.z = __expf(v0.z - m); v0.w = __expf(v0.w - m);
    v1.x = __expf(v1.x - m); v1.y = __expf(v1.y - m);
    v1.z = __expf(v1.z - m); v1.w = __expf(v1.w - m);
    float s = v0.x + v0.y + v0.z + v0.w + v1.x + v1.y + v1.z + v1.w;
#pragma unroll
    for (int o = 32; o; o >>= 1) s += __shfl_xor(s, o);
    const float inv = 1.f / s;
    v0.x *= inv; v0.y *= inv; v0.z *= inv; v0.w *= inv;
    v1.x *= inv; v1.y *= inv; v1.z *= inv; v1.w *= inv;
    ((float4*)p)[lane * 2] = v0;
    ((float4*)p)[lane * 2 + 1] = v1;
}

// ---------------------------------------------------------------------------
// Softmax over s (axis 1, stride R): 512 threads = 128 cols x 4 s-groups
// ---------------------------------------------------------------------------
__global__ __launch_bounds__(512) void softmax_cols(const float* __restrict__ l,
                                                    float* __restrict__ as_)
{
    const int b = blockIdx.y;
    const int rl = threadIdx.x & 127;
    const int r = blockIdx.x * 128 + rl;
    const int sg = threadIdx.x >> 7;           // 0..3
    const int s0 = sg * (S_ / 4), s1 = s0 + S_ / 4;
    const float* base = l + (long)b * S_ * R_ + r;
    __shared__ float red[4][128];

    float pm = -1e30f;
    for (int s = s0; s < s1; ++s) pm = fmaxf(pm, base[(long)s * R_]);
    red[sg][rl] = pm;
    __syncthreads();
    const float m = fmaxf(fmaxf(red[0][rl], red[1][rl]), fmaxf(red[2][rl], red[3][rl]));
    __syncthreads();

    float ps = 0.f;
    for (int s = s0; s < s1; ++s) ps += __expf(base[(long)s * R_] - m);
    red[sg][rl] = ps;
    __syncthreads();
    const float inv = 1.f / (red[0][rl] + red[1][rl] + red[2][rl] + red[3][rl]);

    float* ob = as_ + (long)b * S_ * R_ + r;
    for (int s = s0; s < s1; ++s) ob[(long)s * R_] = __expf(base[(long)s * R_] - m) * inv;
}

// ---------------------------------------------------------------------------
// cat[b][h][s] = h_s[b][s][h]  (s_t half of cat_sc), 32x32 LDS tile transpose
// ---------------------------------------------------------------------------
__global__ __launch_bounds__(256) void transpose_hs(const float* __restrict__ hs,
                                                    float* __restrict__ cat)
{
    __shared__ float tile[32][33];
    const int b = blockIdx.z;
    const int s0 = blockIdx.x * 32, h0 = blockIdx.y * 32;
    const int tx = threadIdx.x, ty = threadIdx.y;
#pragma unroll
    for (int i = 0; i < 32; i += 8)
        tile[ty + i][tx] = hs[((long)b * S_ + s0 + ty + i) * H_ + h0 + tx];
    __syncthreads();
#pragma unroll
    for (int i = 0; i < 32; i += 8)
        cat[((long)b * 2 * H_ + h0 + ty + i) * S_ + s0 + tx] = tile[tx][ty + i];
}

// ---------------------------------------------------------------------------
// bf16 RTN pack helpers
// ---------------------------------------------------------------------------
__device__ inline unsigned pk_bf16(float lo, float hi)
{
    __hip_bfloat16 l = __float2bfloat16(lo);
    __hip_bfloat16 h = __float2bfloat16(hi);
    unsigned short ul, uh;
    __builtin_memcpy(&ul, &l, 2);
    __builtin_memcpy(&uh, &h, 2);
    return (unsigned)ul | ((unsigned)uh << 16);
}

// generic fp32 -> bf16 pack, 4 elems/thread
__global__ __launch_bounds__(256) void pack_bf16(const float* __restrict__ src,
                                                 unsigned short* __restrict__ dst,
                                                 long n4)
{
    const long i = (long)blockIdx.x * 256 + threadIdx.x;
    if (i >= n4) return;
    const float4 v = *((const float4*)src + i);
    uint2 u;
    u.x = pk_bf16(v.x, v.y);
    u.y = pk_bf16(v.z, v.w);
    *((uint2*)dst + i) = u;
}

// ---------------------------------------------------------------------------
// bin_bf16[t*B+b][0:1024] = bf16(c_r[b][t][:]); [1024:1536] = bf16(ref[t][b][:])
// ---------------------------------------------------------------------------
__global__ __launch_bounds__(256) void build_bin(const float* __restrict__ cr,
                                                 const float* __restrict__ ref,
                                                 unsigned short* __restrict__ binb)
{
    const long idx4 = (long)blockIdx.x * blockDim.x + threadIdx.x;
    if (idx4 >= (long)R_ * B_ * DIN_ / 4) return;
    const long f = idx4 * 4;
    const int d = (int)(f % DIN_);
    const long tb = f / DIN_;
    const int b = (int)(tb % B_);
    const int t = (int)(tb / B_);
    float4 v;
    if (d < 2 * H_) v = *(const float4*)(cr + ((long)b * R_ + t) * (2 * H_) + d);
    else            v = *(const float4*)(ref + ((long)t * B_ + b) * H_ + (d - 2 * H_));
    uint2 u;
    u.x = pk_bf16(v.x, v.y);
    u.y = pk_bf16(v.z, v.w);
    *((uint2*)binb + idx4) = u;
}

// ---------------------------------------------------------------------------
// One-time W_hh transpose + bf16(RTN) pack:
// WB[dir][q2][g] = uint4 of 8 bf16 = Whh_dir[g][8*q2 .. 8*q2+8)
// q2 = 4*kk + kgroup matches the MFMA B-fragment layout directly.
// ---------------------------------------------------------------------------
__global__ __launch_bounds__(256) void transpose_w_bf16(
    const float* __restrict__ Whh_f, const float* __restrict__ Whh_b,
    unsigned* __restrict__ WB)
{
    const int g = blockIdx.x * 256 + threadIdx.x;   // 0..1023
    const int q2 = blockIdx.y;                      // 0..31
    const int dir = blockIdx.z;
    const float* W = dir ? Whh_b : Whh_f;
    const float4 a = *(const float4*)(W + (long)g * HD_ + q2 * 8);
    const float4 b = *(const float4*)(W + (long)g * HD_ + q2 * 8 + 4);
    uint4 u;
    u.x = pk_bf16(a.x, a.y);
    u.y = pk_bf16(a.z, a.w);
    u.z = pk_bf16(b.x, b.y);
    u.w = pk_bf16(b.z, b.w);
    *((uint4*)WB + ((long)dir * 32 + q2) * 1024 + g) = u;
}

typedef __attribute__((ext_vector_type(4))) float f32x4;
typedef __attribute__((ext_vector_type(8))) short bf16x8;

__device__ inline bf16x8 u4_to_b8(uint4 u)
{
    bf16x8 r;
    __builtin_memcpy(&r, &u, 16);
    return r;
}

// remat-proof 16B load (asm volatile cannot be re-executed by the compiler)
__device__ inline uint4 ld_g16(const uint4* p)
{
    uint4 r;
    asm volatile("global_load_dwordx4 %0, %1, off" : "=v"(r) : "v"(p));
    return r;
}

// ---------------------------------------------------------------------------
// Step-8 GEMM via MFMA: xg[m][n] = sum_k bin_bf[m][k]*Wih_bf[n][k] + bias(n)
// ---------------------------------------------------------------------------
__global__ __launch_bounds__(256) void gemm_xg_mfma(
    const unsigned short* __restrict__ binb, const unsigned short* __restrict__ Wb,
    const float* __restrict__ bihf, const float* __restrict__ bhhf,
    const float* __restrict__ bihb, const float* __restrict__ bhhb,
    float* __restrict__ xgf2, float* __restrict__ xgb2)
{
    const int dir = blockIdx.z;
    const int n0 = blockIdx.x * 64;
    const int m0 = blockIdx.y * 64;
    const int lane = threadIdx.x & 63, w = threadIdx.x >> 6;
    const int lr = lane & 15, lk = lane >> 4;
    const unsigned short* Wd = Wb + (long)dir * G_ * DIN_;
    const float* bi = dir ? bihb : bihf;
    const float* bh = dir ? bhhb : bhhf;
    float* xg = dir ? xgb2 : xgf2;

    const int n = n0 + 16 * w + lr;
    const unsigned short* bp = Wd + (long)n * DIN_ + lk * 8;
    const unsigned short* ap = binb + (long)(m0 + lr) * DIN_ + lk * 8;

    f32x4 acc[4];
#pragma unroll
    for (int mi = 0; mi < 4; ++mi) acc[mi] = (f32x4){0.f, 0.f, 0.f, 0.f};

    for (int k0 = 0; k0 < DIN_; k0 += 32) {
        const bf16x8 bfr = *(const bf16x8*)(bp + k0);
#pragma unroll
        for (int mi = 0; mi < 4; ++mi) {
            const bf16x8 afr = *(const bf16x8*)(ap + (long)mi * 16 * DIN_ + k0);
            acc[mi] = __builtin_amdgcn_mfma_f32_16x16x32_bf16(afr, bfr, acc[mi], 0, 0, 0);
        }
    }
    const float bias = bi[n] + bh[n];
#pragma unroll
    for (int mi = 0; mi < 4; ++mi)
#pragma unroll
        for (int r = 0; r < 4; ++r) {
            const int m = m0 + 16 * mi + lk * 4 + r;
            xg[(long)m * G_ + n] = acc[mi][r] + bias;
        }
}

// ---------------------------------------------------------------------------
// Bi-LSTM scan v9 — MFMA, one block/direction, 8 waves (512 thr).
// R16 failure diagnosed as SPILL-RACE: 128 asm-loaded VGPRs pushed total
// pressure past 256; spill stores read asm-written regs with no vmcnt wait
// (compiler can't see inside asm) -> stale data spilled. v9 is spill-proof:
//  - kk0..1 forced resident via asm volatile: only 64 VGPRs, issued BEFORE
//    any other memory traffic, then s_waitcnt vmcnt(0) + sched_barrier(0)
//  - kk4..5 in 128 KB LDS (filled after the forced loads complete)
//  - kk2,3,6,7 streamed (256 KB/step) via two rotating 8-uint4 buffers;
//    first two issued at step top under the resident/LDS MFMA cover
// Static VGPR estimate ~217 < 256 (launch_bounds (512,2)) -> no spill.
// Index algebra byte-identical to R13/R15 (HW-verified).
// ---------------------------------------------------------------------------
__device__ inline float sig_(float x) { return 1.f / (1.f + __expf(-x)); }
__device__ inline float tanh_(float x) {
    float ax = fabsf(x);
    float t = 1.f - 2.f / (1.f + __expf(2.f * ax));
    return copysignf(t, x);
}

// 8 MFMAs of one K-step (8 tiles/wave); BEXPR may use loop var j
#define MFMA8(KK, BEXPR)                                                     \
    {                                                                        \
        const bf16x8 a_ = *(const bf16x8*)(hrow + 32 * (KK));                \
        _Pragma("unroll")                                                    \
        for (int j = 0; j < 8; ++j)                                          \
            acc[j] = __builtin_amdgcn_mfma_f32_16x16x32_bf16(                \
                a_, u4_to_b8(BEXPR), acc[j], 0, 0, 0);                       \
    }

__global__ __launch_bounds__(512, 2) void lstm_scan_m(
    const float* __restrict__ xg_f, const float* __restrict__ xg_b,
    const uint4* __restrict__ WBu, float* __restrict__ out)
{
    const int dir = blockIdx.x;
    const float* xg = dir ? xg_b : xg_f;
    const uint4* Wg = WBu + (long)dir * 32768;     // [q2 0..31][row 0..1023]

    __shared__ uint4 WcL[8192];                     // 128 KB: q2 16..23 (kk 4,5)
    __shared__ unsigned short hp[2][16 * 264];      // 16.9 KB bf16 h, dbuf

    const int tid = threadIdx.x;
    const int lane = tid & 63, w = tid >> 6;        // 8 waves
    const int lcol = lane & 15, lkg = lane >> 4;

    // wave w's 8 tiles: n_j = (j>>1)*16 + 2w + (j&1); nb = 16*n_j + lcol
    int nb[8];
#pragma unroll
    for (int j = 0; j < 8; ++j)
        nb[j] = ((((j >> 1) << 4) + 2 * w + (j & 1)) << 4) + lcol;

    // FORCED-resident W kk0..1 (64 VGPR) — FIRST memory traffic in the
    // kernel, drained before anything else can force a spill of them.
    uint4 wres[16];
#pragma unroll
    for (int kk = 0; kk < 2; ++kk)
#pragma unroll
        for (int j = 0; j < 8; ++j)
            wres[kk * 8 + j] = ld_g16(&Wg[(4 * kk + lkg) * 1024 + nb[j]]);
    asm volatile("s_waitcnt vmcnt(0)" ::: "memory");
    __builtin_amdgcn_sched_barrier(0);

    // now the LDS cache fill + h zero init
    for (int i = tid; i < 8192; i += 512) WcL[i] = Wg[16384 + i];
    for (int i = tid; i < 16 * 264; i += 512) hp[0][i] = 0;

    float c_reg[2][4] = {};
    uint4 sA[8], sB[8];
    __syncthreads();

    for (int t = 0; t < R_; ++t) {
        const int tt = dir ? (R_ - 1 - t) : t;
        const int p = t & 1;
        const unsigned short* hrow = &hp[p][lcol * 264 + lkg * 8];

        // prefetch xg gates i,g (HBM latency hides under the dot)
        float xgv[2][4][2];
#pragma unroll
        for (int jj = 0; jj < 2; ++jj)
#pragma unroll
            for (int r = 0; r < 4; ++r) {
                const long xb = ((long)tt * B_ + lkg * 4 + r) * G_
                                + 32 * w + 16 * jj + lcol;
                xgv[jj][r][0] = xg[xb];          // gate i
                xgv[jj][r][1] = xg[xb + 512];    // gate g
            }

        f32x4 acc[8];
#pragma unroll
        for (int j = 0; j < 8; ++j) acc[j] = (f32x4){0.f, 0.f, 0.f, 0.f};

        // issue kk2 (q2 8..11) and kk3 (q2 12..15) at step top
#pragma unroll
        for (int j = 0; j < 8; ++j) sA[j] = Wg[(8 + lkg) * 1024 + nb[j]];
#pragma unroll
        for (int j = 0; j < 8; ++j) sB[j] = Wg[(12 + lkg) * 1024 + nb[j]];

        MFMA8(0, wres[0 * 8 + j])                // resident
        MFMA8(1, wres[1 * 8 + j])                // resident
        MFMA8(4, WcL[lkg * 1024 + nb[j]])        // LDS
        MFMA8(5, WcL[(4 + lkg) * 1024 + nb[j]])  // LDS (covers sA/sB flight)
        MFMA8(2, sA[j])
#pragma unroll
        for (int j = 0; j < 8; ++j) sA[j] = Wg[(24 + lkg) * 1024 + nb[j]];  // kk6
        MFMA8(3, sB[j])
#pragma unroll
        for (int j = 0; j < 8; ++j) sB[j] = Wg[(28 + lkg) * 1024 + nb[j]];  // kk7
        MFMA8(6, sA[j])
        MFMA8(7, sB[j])

        // cell phase: lane owns cells (batch = lkg*4+r, col = 32w+16jj+lcol)
#pragma unroll
        for (int jj = 0; jj < 2; ++jj) {
#pragma unroll
            for (int r = 0; r < 4; ++r) {
                const int batch = lkg * 4 + r;
                const int col = 32 * w + 16 * jj + lcol;
                const long xb = ((long)tt * B_ + batch) * G_ + col;
                const float iv = acc[0 + jj][r] + xgv[jj][r][0];
                const float fv = acc[2 + jj][r] + xg[xb + 256];
                const float gv = acc[4 + jj][r] + xgv[jj][r][1];
                const float ov = acc[6 + jj][r] + xg[xb + 768];
                float c = sig_(fv) * c_reg[jj][r] + sig_(iv) * tanh_(gv);
                c_reg[jj][r] = c;
                const float h = sig_(ov) * tanh_(c);
                out[((long)tt * B_ + batch) * (2 * HD_) + dir * HD_ + col] = h;
                unsigned u = __float_as_uint(h);
                u += 0x7FFFu + ((u >> 16) & 1);          // RTN to bf16
                hp[p ^ 1][batch * 264 + col] = (unsigned short)(u >> 16);
            }
        }
        __syncthreads();
    }
}

// ---------------------------------------------------------------------------
extern "C" void kernel_launch(void* const* d_in, const int* in_sizes, int n_in,
                              void* d_out, int out_size, void* d_ws, size_t ws_size,
                              hipStream_t stream)
{
    const float* src  = (const float*)d_in[1];   // [S][B][H]
    const float* ref  = (const float*)d_in[2];   // [R][B][H]
    const float* Wref = (const float*)d_in[3];   // [H][H]
    const float* bref = (const float*)d_in[4];   // [H]
    const float* Wihf = (const float*)d_in[5];   // [G][DIN]
    const float* Whhf = (const float*)d_in[6];   // [G][HD]
    const float* bihf = (const float*)d_in[7];
    const float* bhhf = (const float*)d_in[8];
    const float* Wihb = (const float*)d_in[9];
    const float* Whhb = (const float*)d_in[10];
    const float* bihb = (const float*)d_in[11];
    const float* bhhb = (const float*)d_in[12];
    float* out = (float*)d_out;                  // [R][B][2*HD]

    float* ws = (float*)d_ws;
    // workspace layout (floats), with aliasing:
    float* hs  = ws + 0L;                         // 8388608   [B][S][H]
    float* l   = ws + 8388608L;                   // 8388608   [B][S][R] (a_r in place)
    float* as_ = ws + 16777216L;                  // 8388608   [B][S][R]
    float* cat = ws + 25165824L;                  // 16777216  [B][2H][S]
    float* cr  = hs;                              // 8388608   [B][R][2H]  (hs dead after step 4)
    unsigned short* binb = (unsigned short*)cat;  // 25.2 MB bf16 [T*B][DIN] (cat dead after step 6)
    float* xgf = l;                               // 8388608   [T][B][G]   (l dead after step 6)
    float* xgb = as_;                             // 8388608   [T][B][G]   (as_ dead after step 5)
    unsigned* WB = (unsigned*)(ws + 41943040L);   // 1 MB: scan W bf16 (2 dir x 32 q2 x 1024 x uint4)
    unsigned short* Wib = (unsigned short*)(ws + 42205184L);  // 6 MB: W_ih bf16, both dirs

    // 0) one-time weight packs
    transpose_w_bf16<<<dim3(4, 32, 2), 256, 0, stream>>>(Whhf, Whhb, WB);
    pack_bf16<<<dim3((G_ * DIN_ / 4 + 255) / 256), 256, 0, stream>>>(
        Wihf, Wib, (long)G_ * DIN_ / 4);
    pack_bf16<<<dim3((G_ * DIN_ / 4 + 255) / 256), 256, 0, stream>>>(
        Wihb, Wib + (long)G_ * DIN_, (long)G_ * DIN_ / 4);

    // 1) h_s = tanh(src . Wref^T + bref)   [B*S, 512] k=512
    gemm_mk_nk<1, 1><<<dim3(8, 256, 1), 256, 0, stream>>>(
        src, H_, 0, Wref, H_, 0, hs, H_, 0, bref, nullptr, B_ * S_, H_, H_);

    // 2) l[b] = h_s[b] . h_r[b]^T   M=1024 N=512 K=512, batched over b
    gemm_mk_nk<0, 0><<<dim3(8, 16, B_), 256, 0, stream>>>(
        hs, H_, (long)S_ * H_, ref, (long)B_ * H_, H_, l, R_, (long)S_ * R_,
        nullptr, nullptr, S_, R_, H_);

    // 3) a_s = softmax over s (columns), then a_r = softmax over r in place
    softmax_cols<<<dim3(R_ / 128, B_), 512, 0, stream>>>(l, as_);
    softmax_rows<<<(B_ * S_) / 4, 256, 0, stream>>>(l);

    // 4) cat rows 0..511 = h_s transposed
    transpose_hs<<<dim3(S_ / 32, H_ / 32, B_), dim3(32, 8), 0, stream>>>(hs, cat);

    // 5) cat rows 512..1023: c_s[b,h,s] = sum_r ref[r,b,h]*a_s[b,s,r]
    gemm_km_nk<<<dim3(16, 8, B_), 256, 0, stream>>>(
        ref, (long)B_ * H_, H_, as_, R_, (long)S_ * R_,
        cat + (long)H_ * S_, S_, (long)2 * H_ * S_, H_, S_, R_);

    // 6) c_r[b,r,k] = sum_s cat[b,k,s]*a_r[b,s,r]   M=512 N=1024 K=1024
    gemm_km_nk<<<dim3(16, 8, B_), 256, 0, stream>>>(
        l, R_, (long)S_ * R_, cat, S_, (long)2 * H_ * S_,
        cr, 2 * H_, (long)R_ * 2 * H_, R_, 2 * H_, S_);

    // 7) bilstm_in -> bf16  (NOTE: overwrites cat region; cat dead after 6)
    build_bin<<<(R_ * B_ * DIN_ / 4 + 255) / 256, 256, 0, stream>>>(cr, ref, binb);

    // 8) xg = bin . W_ih^T + b_ih + b_hh  via MFMA, both dirs in one grid
    gemm_xg_mfma<<<dim3(G_ / 64, R_ * B_ / 64, 2), 256, 0, stream>>>(
        binb, Wib, bihf, bhhf, bihb, bhhb, xgf, xgb);

    // 9) bi-LSTM scan: 2 direction blocks, MFMA, spill-proof forced residency
    lstm_scan_m<<<dim3(2), dim3(512), 0, stream>>>(xgf, xgb, (const uint4*)WB, out);
}

// Round 18
// 2864.486 us; speedup vs baseline: 3.7889x; 1.5109x over previous
//
#include <hip/hip_runtime.h>
#include <hip/hip_bf16.h>
#include <math.h>

#define B_   16
#define S_   1024
#define R_   512
#define H_   512
#define HD_  256
#define G_   1024
#define DIN_ 1536

// ---------------------------------------------------------------------------
// Tiled fp32 GEMM:  C[m][n] = sum_k A(m,k) * B(n,k)   (steps 1 and 2 only)
// ---------------------------------------------------------------------------
template<int EPI, int REMAP_A>
__global__ __launch_bounds__(256) void gemm_mk_nk(
    const float* __restrict__ A, long a_rs, long a_bs,
    const float* __restrict__ Bm, long b_rs, long b_bs,
    float* __restrict__ C, long c_rs, long c_bs,
    const float* __restrict__ bias,
    int M, int N, int K)
{
    __shared__ float As[16][68];
    __shared__ float Bs[16][68];
    const int bb = blockIdx.z;
    const float* Ab = A + (long)bb * a_bs;
    const float* Bb = Bm + (long)bb * b_bs;
    float* Cb = C + (long)bb * c_bs;
    const int m0 = blockIdx.y * 64, n0 = blockIdx.x * 64;
    const int tid = threadIdx.x;
    const int tx = tid & 15, ty = tid >> 4;
    const int lr = tid >> 2;          // tile row 0..63
    const int lk = (tid & 3) << 2;    // k offset 0..12

    long arow;
    {
        int m = m0 + lr;
        if (REMAP_A) arow = (long)((m % S_) * B_ + (m / S_)) * a_rs;
        else         arow = (long)m * a_rs;
    }
    const long brow = (long)(n0 + lr) * b_rs;

    float acc[4][4] = {};
    for (int k0 = 0; k0 < K; k0 += 16) {
        float4 av = *(const float4*)(Ab + arow + k0 + lk);
        float4 bv = *(const float4*)(Bb + brow + k0 + lk);
        As[lk + 0][lr] = av.x; As[lk + 1][lr] = av.y;
        As[lk + 2][lr] = av.z; As[lk + 3][lr] = av.w;
        Bs[lk + 0][lr] = bv.x; Bs[lk + 1][lr] = bv.y;
        Bs[lk + 2][lr] = bv.z; Bs[lk + 3][lr] = bv.w;
        __syncthreads();
#pragma unroll
        for (int kk = 0; kk < 16; ++kk) {
            float4 a = *(const float4*)&As[kk][ty << 2];
            float4 b = *(const float4*)&Bs[kk][tx << 2];
            acc[0][0] += a.x * b.x; acc[0][1] += a.x * b.y; acc[0][2] += a.x * b.z; acc[0][3] += a.x * b.w;
            acc[1][0] += a.y * b.x; acc[1][1] += a.y * b.y; acc[1][2] += a.y * b.z; acc[1][3] += a.y * b.w;
            acc[2][0] += a.z * b.x; acc[2][1] += a.z * b.y; acc[2][2] += a.z * b.z; acc[2][3] += a.z * b.w;
            acc[3][0] += a.w * b.x; acc[3][1] += a.w * b.y; acc[3][2] += a.w * b.z; acc[3][3] += a.w * b.w;
        }
        __syncthreads();
    }
#pragma unroll
    for (int i = 0; i < 4; ++i) {
        const int m = m0 + (ty << 2) + i;
#pragma unroll
        for (int j = 0; j < 4; ++j) {
            const int n = n0 + (tx << 2) + j;
            float v = acc[i][j];
            if (EPI == 1) v = tanhf(v + bias[n]);
            Cb[(long)m * c_rs + n] = v;
        }
    }
}

// ---------------------------------------------------------------------------
// bf16 helpers
// ---------------------------------------------------------------------------
__device__ inline unsigned short bf16_rtn(float x)
{
    unsigned u = __float_as_uint(x);
    u += 0x7FFFu + ((u >> 16) & 1);
    return (unsigned short)(u >> 16);
}

__device__ inline unsigned pk_bf16(float lo, float hi)
{
    return (unsigned)bf16_rtn(lo) | ((unsigned)bf16_rtn(hi) << 16);
}

// generic fp32 -> bf16 pack, 4 elems/thread
__global__ __launch_bounds__(256) void pack_bf16(const float* __restrict__ src,
                                                 unsigned short* __restrict__ dst,
                                                 long n4)
{
    const long i = (long)blockIdx.x * 256 + threadIdx.x;
    if (i >= n4) return;
    const float4 v = *((const float4*)src + i);
    uint2 u;
    u.x = pk_bf16(v.x, v.y);
    u.y = pk_bf16(v.z, v.w);
    *((uint2*)dst + i) = u;
}

// ---------------------------------------------------------------------------
// Softmax over r (last axis, contiguous, 512): one wave per row, in-place
// ---------------------------------------------------------------------------
__global__ __launch_bounds__(256) void softmax_rows(float* __restrict__ l)
{
    const int lane = threadIdx.x & 63;
    const int wv = threadIdx.x >> 6;
    const long row = (long)blockIdx.x * 4 + wv;
    float* p = l + row * R_;
    float4 v0 = ((const float4*)p)[lane * 2];
    float4 v1 = ((const float4*)p)[lane * 2 + 1];
    float m = fmaxf(fmaxf(fmaxf(v0.x, v0.y), fmaxf(v0.z, v0.w)),
                    fmaxf(fmaxf(v1.x, v1.y), fmaxf(v1.z, v1.w)));
#pragma unroll
    for (int o = 32; o; o >>= 1) m = fmaxf(m, __shfl_xor(m, o));
    v0.x = __expf(v0.x - m); v0.y = __expf(v0.y - m);
    v0.z = __expf(v0.z - m); v0.w = __expf(v0.w - m);
    v1.x = __expf(v1.x - m); v1.y = __expf(v1.y - m);
    v1.z = __expf(v1.z - m); v1.w = __expf(v1.w - m);
    float s = v0.x + v0.y + v0.z + v0.w + v1.x + v1.y + v1.z + v1.w;
#pragma unroll
    for (int o = 32; o; o >>= 1) s += __shfl_xor(s, o);
    const float inv = 1.f / s;
    v0.x *= inv; v0.y *= inv; v0.z *= inv; v0.w *= inv;
    v1.x *= inv; v1.y *= inv; v1.z *= inv; v1.w *= inv;
    ((float4*)p)[lane * 2] = v0;
    ((float4*)p)[lane * 2 + 1] = v1;
}

// ---------------------------------------------------------------------------
// Softmax over s (axis 1, stride R) -> bf16 output
// ---------------------------------------------------------------------------
__global__ __launch_bounds__(512) void softmax_cols(const float* __restrict__ l,
                                                    unsigned short* __restrict__ asb)
{
    const int b = blockIdx.y;
    const int rl = threadIdx.x & 127;
    const int r = blockIdx.x * 128 + rl;
    const int sg = threadIdx.x >> 7;           // 0..3
    const int s0 = sg * (S_ / 4), s1 = s0 + S_ / 4;
    const float* base = l + (long)b * S_ * R_ + r;
    __shared__ float red[4][128];

    float pm = -1e30f;
    for (int s = s0; s < s1; ++s) pm = fmaxf(pm, base[(long)s * R_]);
    red[sg][rl] = pm;
    __syncthreads();
    const float m = fmaxf(fmaxf(red[0][rl], red[1][rl]), fmaxf(red[2][rl], red[3][rl]));
    __syncthreads();

    float ps = 0.f;
    for (int s = s0; s < s1; ++s) ps += __expf(base[(long)s * R_] - m);
    red[sg][rl] = ps;
    __syncthreads();
    const float inv = 1.f / (red[0][rl] + red[1][rl] + red[2][rl] + red[3][rl]);

    unsigned short* ob = asb + (long)b * S_ * R_ + r;
    for (int s = s0; s < s1; ++s)
        ob[(long)s * R_] = bf16_rtn(__expf(base[(long)s * R_] - m) * inv);
}

// ---------------------------------------------------------------------------
// cat_bf rows 0..511: cat_bf[b][h][s] = bf16(h_s[b][s][h])
// ---------------------------------------------------------------------------
__global__ __launch_bounds__(256) void transpose_hs(const float* __restrict__ hs,
                                                    unsigned short* __restrict__ catb)
{
    __shared__ float tile[32][33];
    const int b = blockIdx.z;
    const int s0 = blockIdx.x * 32, h0 = blockIdx.y * 32;
    const int tx = threadIdx.x, ty = threadIdx.y;
#pragma unroll
    for (int i = 0; i < 32; i += 8)
        tile[ty + i][tx] = hs[((long)b * S_ + s0 + ty + i) * H_ + h0 + tx];
    __syncthreads();
#pragma unroll
    for (int i = 0; i < 32; i += 8)
        catb[((long)b * 2 * H_ + h0 + ty + i) * S_ + s0 + tx] = bf16_rtn(tile[tx][ty + i]);
}

// ---------------------------------------------------------------------------
// refT_bf[b][h][r] = bf16(ref[r][b][h])
// ---------------------------------------------------------------------------
__global__ __launch_bounds__(256) void transpose_ref(const float* __restrict__ ref,
                                                     unsigned short* __restrict__ refT)
{
    __shared__ float tile[32][33];
    const int b = blockIdx.z;
    const int r0 = blockIdx.x * 32, h0 = blockIdx.y * 32;
    const int tx = threadIdx.x, ty = threadIdx.y;
#pragma unroll
    for (int i = 0; i < 32; i += 8)
        tile[ty + i][tx] = ref[((long)(r0 + ty + i) * B_ + b) * H_ + h0 + tx];
    __syncthreads();
#pragma unroll
    for (int i = 0; i < 32; i += 8)
        refT[((long)b * H_ + h0 + ty + i) * R_ + r0 + tx] = bf16_rtn(tile[tx][ty + i]);
}

// ---------------------------------------------------------------------------
// a_rT_bf[b][r][s] = bf16(l[b][s][r])   (l holds a_r after softmax_rows)
// ---------------------------------------------------------------------------
__global__ __launch_bounds__(256) void transpose_arT(const float* __restrict__ l,
                                                     unsigned short* __restrict__ arT)
{
    __shared__ float tile[32][33];
    const int b = blockIdx.z;
    const int s0 = blockIdx.x * 32, r0 = blockIdx.y * 32;
    const int tx = threadIdx.x, ty = threadIdx.y;
#pragma unroll
    for (int i = 0; i < 32; i += 8)
        tile[ty + i][tx] = l[((long)b * S_ + s0 + ty + i) * R_ + r0 + tx];
    __syncthreads();
#pragma unroll
    for (int i = 0; i < 32; i += 8)
        arT[((long)b * R_ + r0 + ty + i) * S_ + s0 + tx] = bf16_rtn(tile[tx][ty + i]);
}

// ---------------------------------------------------------------------------
// bin_bf16[t*B+b][0:1024] = bf16(c_r[b][t][:]); [1024:1536] = bf16(ref[t][b][:])
// ---------------------------------------------------------------------------
__global__ __launch_bounds__(256) void build_bin(const float* __restrict__ cr,
                                                 const float* __restrict__ ref,
                                                 unsigned short* __restrict__ binb)
{
    const long idx4 = (long)blockIdx.x * blockDim.x + threadIdx.x;
    if (idx4 >= (long)R_ * B_ * DIN_ / 4) return;
    const long f = idx4 * 4;
    const int d = (int)(f % DIN_);
    const long tb = f / DIN_;
    const int b = (int)(tb % B_);
    const int t = (int)(tb / B_);
    float4 v;
    if (d < 2 * H_) v = *(const float4*)(cr + ((long)b * R_ + t) * (2 * H_) + d);
    else            v = *(const float4*)(ref + ((long)t * B_ + b) * H_ + (d - 2 * H_));
    uint2 u;
    u.x = pk_bf16(v.x, v.y);
    u.y = pk_bf16(v.z, v.w);
    *((uint2*)binb + idx4) = u;
}

// ---------------------------------------------------------------------------
// One-time W_hh transpose + bf16 pack: WB[dir][q2][g] (q2 = 4*kk + kgroup)
// ---------------------------------------------------------------------------
__global__ __launch_bounds__(256) void transpose_w_bf16(
    const float* __restrict__ Whh_f, const float* __restrict__ Whh_b,
    unsigned* __restrict__ WB)
{
    const int g = blockIdx.x * 256 + threadIdx.x;   // 0..1023
    const int q2 = blockIdx.y;                      // 0..31
    const int dir = blockIdx.z;
    const float* W = dir ? Whh_b : Whh_f;
    const float4 a = *(const float4*)(W + (long)g * HD_ + q2 * 8);
    const float4 b = *(const float4*)(W + (long)g * HD_ + q2 * 8 + 4);
    uint4 u;
    u.x = pk_bf16(a.x, a.y);
    u.y = pk_bf16(a.z, a.w);
    u.z = pk_bf16(b.x, b.y);
    u.w = pk_bf16(b.z, b.w);
    *((uint4*)WB + ((long)dir * 32 + q2) * 1024 + g) = u;
}

typedef __attribute__((ext_vector_type(4))) float f32x4;
typedef __attribute__((ext_vector_type(8))) short bf16x8;

__device__ inline bf16x8 u4_to_b8(uint4 u)
{
    bf16x8 r;
    __builtin_memcpy(&r, &u, 16);
    return r;
}

// ---------------------------------------------------------------------------
// Generic bf16 MFMA GEMM, 64x64 tile, batched, both operands k-contiguous.
// CT=0: bf16 row-major C[m][n]. CT=1: fp32 TRANSPOSED write C[n][m] (float4).
// Fragment mapping per guide §3 (m89-verified; same as gemm_xg_mfma).
// ---------------------------------------------------------------------------
template<int CT>
__global__ __launch_bounds__(256) void gemm56(
    const unsigned short* __restrict__ A, long a_bs, int lda,
    const unsigned short* __restrict__ Bm, long b_bs, int ldb,
    void* __restrict__ Cv, long c_bs, int ldc, int K)
{
    const int bb = blockIdx.z;
    const int n0 = blockIdx.x * 64, m0 = blockIdx.y * 64;
    const int lane = threadIdx.x & 63, w = threadIdx.x >> 6;
    const int lr = lane & 15, lk = lane >> 4;
    const unsigned short* ap = A + bb * a_bs + (long)(m0 + lr) * lda + lk * 8;
    const unsigned short* bp = Bm + bb * b_bs + (long)(n0 + 16 * w + lr) * ldb + lk * 8;

    f32x4 acc[4];
#pragma unroll
    for (int mi = 0; mi < 4; ++mi) acc[mi] = (f32x4){0.f, 0.f, 0.f, 0.f};

    for (int k0 = 0; k0 < K; k0 += 32) {
        const bf16x8 bfr = *(const bf16x8*)(bp + k0);
#pragma unroll
        for (int mi = 0; mi < 4; ++mi) {
            const bf16x8 afr = *(const bf16x8*)(ap + (long)mi * 16 * lda + k0);
            acc[mi] = __builtin_amdgcn_mfma_f32_16x16x32_bf16(afr, bfr, acc[mi], 0, 0, 0);
        }
    }
    const int n = n0 + 16 * w + lr;
    if (CT == 0) {
        unsigned short* C = (unsigned short*)Cv + bb * c_bs;
#pragma unroll
        for (int mi = 0; mi < 4; ++mi)
#pragma unroll
            for (int r = 0; r < 4; ++r)
                C[(long)(m0 + 16 * mi + lk * 4 + r) * ldc + n] = bf16_rtn(acc[mi][r]);
    } else {
        float* C = (float*)Cv + bb * c_bs;
#pragma unroll
        for (int mi = 0; mi < 4; ++mi) {
            float4 v = make_float4(acc[mi][0], acc[mi][1], acc[mi][2], acc[mi][3]);
            *(float4*)&C[(long)n * ldc + m0 + 16 * mi + lk * 4] = v;
        }
    }
}

// ---------------------------------------------------------------------------
// Step-8 GEMM via MFMA: xg[m][n] = sum_k bin_bf[m][k]*Wih_bf[n][k] + bias(n)
// ---------------------------------------------------------------------------
__global__ __launch_bounds__(256) void gemm_xg_mfma(
    const unsigned short* __restrict__ binb, const unsigned short* __restrict__ Wb,
    const float* __restrict__ bihf, const float* __restrict__ bhhf,
    const float* __restrict__ bihb, const float* __restrict__ bhhb,
    float* __restrict__ xgf2, float* __restrict__ xgb2)
{
    const int dir = blockIdx.z;
    const int n0 = blockIdx.x * 64;
    const int m0 = blockIdx.y * 64;
    const int lane = threadIdx.x & 63, w = threadIdx.x >> 6;
    const int lr = lane & 15, lk = lane >> 4;
    const unsigned short* Wd = Wb + (long)dir * G_ * DIN_;
    const float* bi = dir ? bihb : bihf;
    const float* bh = dir ? bhhb : bhhf;
    float* xg = dir ? xgb2 : xgf2;

    const int n = n0 + 16 * w + lr;
    const unsigned short* bp = Wd + (long)n * DIN_ + lk * 8;
    const unsigned short* ap = binb + (long)(m0 + lr) * DIN_ + lk * 8;

    f32x4 acc[4];
#pragma unroll
    for (int mi = 0; mi < 4; ++mi) acc[mi] = (f32x4){0.f, 0.f, 0.f, 0.f};

    for (int k0 = 0; k0 < DIN_; k0 += 32) {
        const bf16x8 bfr = *(const bf16x8*)(bp + k0);
#pragma unroll
        for (int mi = 0; mi < 4; ++mi) {
            const bf16x8 afr = *(const bf16x8*)(ap + (long)mi * 16 * DIN_ + k0);
            acc[mi] = __builtin_amdgcn_mfma_f32_16x16x32_bf16(afr, bfr, acc[mi], 0, 0, 0);
        }
    }
    const float bias = bi[n] + bh[n];
#pragma unroll
    for (int mi = 0; mi < 4; ++mi)
#pragma unroll
        for (int r = 0; r < 4; ++r) {
            const int m = m0 + 16 * mi + lk * 4 + r;
            xg[(long)m * G_ + n] = acc[mi][r] + bias;
        }
}

// ---------------------------------------------------------------------------
// Bi-LSTM scan v10 — W FULLY LDS-RESIDENT: 4 blocks/direction x 256 thr.
// R13-R17: one CU re-streams ~400 KB W/step at ~60 GB/s = 6.2us/step across
// FIVE configs (allocator refuses register residency; scratch demotion).
// v10: W per dir = 512 KB bf16 -> 4 blocks x 128 KB LDS = ZERO stream.
// Block (dir,j) owns h-cols [64j,64j+64) x ALL 4 gates (h-slice ownership,
// HW-proven R6/R7) -> cell is LANE-local (all 4 gates of a column land in
// one lane's acc[0..3]). Cross-block h exchange: 8 KB bf16/dir/step via
// global hbuf (double-buffered) + R7's HW-proven flag sync:
//   writer: stores -> __syncthreads -> tid0 {__threadfence; flag=t+1}
//   reader: prefetch xg -> poll flags>=t (wave0) -> __syncthreads ->
//           acquire-agent fence -> stage h to LDS.
// Per-step: stage 8KB + 32 MFMA/wave (LDS-fed) + cell + sync.
// ---------------------------------------------------------------------------
#define NBD 4

__device__ inline float sig_(float x) { return 1.f / (1.f + __expf(-x)); }
__device__ inline float tanh_(float x) {
    float ax = fabsf(x);
    float t = 1.f - 2.f / (1.f + __expf(2.f * ax));
    return copysignf(t, x);
}

__global__ __launch_bounds__(256) void lstm_scan_s(
    const float* __restrict__ xg_f, const float* __restrict__ xg_b,
    const uint4* __restrict__ WBu, unsigned short* __restrict__ hbuf,
    unsigned* __restrict__ flags, float* __restrict__ out)
{
    const int blk = blockIdx.x;
    const int dir = blk >> 2;
    const int j = blk & 3;
    const float* xg = dir ? xg_b : xg_f;
    const uint4* Wg = WBu + (long)dir * 32768;        // [q2 0..31][g 0..1023]
    unsigned short* hb = hbuf + dir * (2 * B_ * HD_); // 2 parity x [16][256]
    unsigned* fl = flags + dir * 64;

    __shared__ uint4 WL[32 * 256];                    // 128 KB (full W slice)
    __shared__ unsigned short h_lds[16 * 264];        // 8.25 KB staged h

    const int tid = threadIdx.x;
    const int lane = tid & 63, w = tid >> 6;          // 4 waves
    const int lcol = lane & 15, lkg = lane >> 4;

    // fill WL once: local row = g*64 + c  <-  global gate row g*256 + 64j + c
    for (int idx = tid; idx < 32 * 256; idx += 256) {
        const int q2 = idx >> 8, loc = idx & 255;
        const int g = loc >> 6, c = loc & 63;
        WL[idx] = Wg[q2 * 1024 + g * 256 + 64 * j + c];
    }
    float c_reg[4] = {};
    const int col = 64 * j + 16 * w + lcol;           // owned h-column
    __syncthreads();

    for (int t = 0; t < R_; ++t) {
        const int tt = dir ? (R_ - 1 - t) : t;
        const int p = t & 1;

        // prefetch xg (immutable data -> safe before the acquire fence;
        // HBM/LLC latency hides under the flag poll)
        float xgv[4][4];
#pragma unroll
        for (int g = 0; g < 4; ++g)
#pragma unroll
            for (int r = 0; r < 4; ++r)
                xgv[g][r] = xg[((long)tt * B_ + lkg * 4 + r) * G_ + g * 256 + col];

        if (t > 0) {
            if (tid < 64) {
                while (true) {
                    unsigned v = (lane < NBD)
                        ? __hip_atomic_load(&fl[lane * 16], __ATOMIC_RELAXED,
                                            __HIP_MEMORY_SCOPE_AGENT)
                        : 0xFFFFFFFFu;
                    if (__all(v >= (unsigned)t)) break;
                    __builtin_amdgcn_s_sleep(1);
                }
            }
            __syncthreads();
            __builtin_amdgcn_fence(__ATOMIC_ACQUIRE, "agent");
        }

        // stage h_t (parity p) -> LDS  (16 rows x 256 bf16; 512 uint4)
        for (int i = tid; i < 512; i += 256) {
            const int b = i >> 5, c8 = (i & 31) * 8;
            *(uint4*)&h_lds[b * 264 + c8] =
                *(const uint4*)&hb[p * (B_ * HD_) + b * HD_ + c8];
        }
        __syncthreads();

        // dot: wave w's 4 gate tiles (rows g*64+16w..+16 local), all LDS-fed
        f32x4 acc[4];
#pragma unroll
        for (int g = 0; g < 4; ++g) acc[g] = (f32x4){0.f, 0.f, 0.f, 0.f};
        const unsigned short* hrow = &h_lds[lcol * 264 + lkg * 8];
#pragma unroll
        for (int kk = 0; kk < 8; ++kk) {
            const bf16x8 a_ = *(const bf16x8*)(hrow + 32 * kk);
#pragma unroll
            for (int g = 0; g < 4; ++g) {
                const uint4 wv = WL[(4 * kk + lkg) * 256 + g * 64 + 16 * w + lcol];
                acc[g] = __builtin_amdgcn_mfma_f32_16x16x32_bf16(
                    a_, u4_to_b8(wv), acc[g], 0, 0, 0);
            }
        }

        // cell: lane owns (batch = lkg*4+r, col) — all 4 gates in-lane
#pragma unroll
        for (int r = 0; r < 4; ++r) {
            const int batch = lkg * 4 + r;
            const float iv = acc[0][r] + xgv[0][r];
            const float fv = acc[1][r] + xgv[1][r];
            const float gv = acc[2][r] + xgv[2][r];
            const float ov = acc[3][r] + xgv[3][r];
            float c = sig_(fv) * c_reg[r] + sig_(iv) * tanh_(gv);
            c_reg[r] = c;
            const float h = sig_(ov) * tanh_(c);
            out[((long)tt * B_ + batch) * (2 * HD_) + dir * HD_ + col] = h;
            hb[(p ^ 1) * (B_ * HD_) + batch * HD_ + col] = bf16_rtn(h);
        }
        __syncthreads();   // drains h stores (vmcnt(0) before s_barrier)
        if (tid == 0) {
            __threadfence();   // wbl2: h lines -> LLC (R7-proven)
            __hip_atomic_store(&fl[j * 16], (unsigned)(t + 1), __ATOMIC_RELAXED,
                               __HIP_MEMORY_SCOPE_AGENT);
        }
    }
}

// ---------------------------------------------------------------------------
extern "C" void kernel_launch(void* const* d_in, const int* in_sizes, int n_in,
                              void* d_out, int out_size, void* d_ws, size_t ws_size,
                              hipStream_t stream)
{
    const float* src  = (const float*)d_in[1];   // [S][B][H]
    const float* ref  = (const float*)d_in[2];   // [R][B][H]
    const float* Wref = (const float*)d_in[3];   // [H][H]
    const float* bref = (const float*)d_in[4];   // [H]
    const float* Wihf = (const float*)d_in[5];   // [G][DIN]
    const float* Whhf = (const float*)d_in[6];   // [G][HD]
    const float* bihf = (const float*)d_in[7];
    const float* bhhf = (const float*)d_in[8];
    const float* Wihb = (const float*)d_in[9];
    const float* Whhb = (const float*)d_in[10];
    const float* bihb = (const float*)d_in[11];
    const float* bhhb = (const float*)d_in[12];
    float* out = (float*)d_out;                  // [R][B][2*HD]

    float* ws = (float*)d_ws;
    // workspace layout (float offsets):
    float* hs   = ws + 0L;                              // 8388608  [B][S][H]
    float* l    = ws + 8388608L;                        // 8388608  [B][S][R]
    unsigned short* as_bf = (unsigned short*)(ws + 16777216L);  // 16.8 MB bf16 [B][S][R]
    unsigned short* refT  = (unsigned short*)(ws + 20971520L);  // 8.4 MB bf16 [B][H][R]
    unsigned short* a_rT  = (unsigned short*)(ws + 23068672L);  // 16.8 MB bf16 [B][R][S]
    unsigned short* catb  = (unsigned short*)(ws + 27262976L);  // 33.6 MB bf16 [B][2H][S]
    unsigned short* binb  = (unsigned short*)(ws + 35651584L);  // 25.2 MB bf16 [T*B][DIN]
    unsigned* WB = (unsigned*)(ws + 41943040L);         // 1 MB scan W bf16
    unsigned short* Wib = (unsigned short*)(ws + 42205184L);    // 6 MB W_ih bf16
    unsigned short* hbuf = (unsigned short*)(ws + 43778048L);   // 32 KB h dbuf
    unsigned* flags = (unsigned*)(ws + 43786240L);      // 512 B
    float* cr  = hs;                                    // alias (hs dead after step 4)
    float* xgf = l;                                     // alias (l dead after a_rT)
    float* xgb = ws + 16777216L;                        // alias (as_bf/refT/a_rT dead after 6)

    // zero h_0 + flags
    hipMemsetAsync(hbuf, 0, 2 * 2 * B_ * HD_ * 2 + 512, stream);

    // 0) one-time weight packs
    transpose_w_bf16<<<dim3(4, 32, 2), 256, 0, stream>>>(Whhf, Whhb, WB);
    pack_bf16<<<dim3((G_ * DIN_ / 4 + 255) / 256), 256, 0, stream>>>(
        Wihf, Wib, (long)G_ * DIN_ / 4);
    pack_bf16<<<dim3((G_ * DIN_ / 4 + 255) / 256), 256, 0, stream>>>(
        Wihb, Wib + (long)G_ * DIN_, (long)G_ * DIN_ / 4);

    // 1) h_s = tanh(src . Wref^T + bref)
    gemm_mk_nk<1, 1><<<dim3(8, 256, 1), 256, 0, stream>>>(
        src, H_, 0, Wref, H_, 0, hs, H_, 0, bref, B_ * S_, H_, H_);

    // 2) l[b] = h_s[b] . h_r[b]^T
    gemm_mk_nk<0, 0><<<dim3(8, 16, B_), 256, 0, stream>>>(
        hs, H_, (long)S_ * H_, ref, (long)B_ * H_, H_, l, R_, (long)S_ * R_,
        nullptr, S_, R_, H_);

    // 3) softmaxes: a_s -> bf16; a_r in place (fp32)
    softmax_cols<<<dim3(R_ / 128, B_), 512, 0, stream>>>(l, as_bf);
    softmax_rows<<<(B_ * S_) / 4, 256, 0, stream>>>(l);

    // 3b) bf16 transposes for the MFMA attention GEMMs
    transpose_ref<<<dim3(R_ / 32, H_ / 32, B_), dim3(32, 8), 0, stream>>>(ref, refT);
    transpose_arT<<<dim3(S_ / 32, R_ / 32, B_), dim3(32, 8), 0, stream>>>(l, a_rT);

    // 4) cat_bf rows 0..511 = h_s^T (bf16)
    transpose_hs<<<dim3(S_ / 32, H_ / 32, B_), dim3(32, 8), 0, stream>>>(hs, catb);

    // 5) cat_bf rows 512..1023: c_s[b,h,s] = sum_r refT[b,h,r]*a_s[b,s,r]  (MFMA)
    gemm56<0><<<dim3(S_ / 64, H_ / 64, B_), 256, 0, stream>>>(
        refT, (long)H_ * R_, R_, as_bf, (long)S_ * R_, R_,
        (void*)(catb + (long)H_ * S_), (long)2 * H_ * S_, S_, R_);

    // 6) c_r[b,r,m] = sum_s cat_bf[b,m,s]*a_rT[b,r,s]  (MFMA, transposed C)
    gemm56<1><<<dim3(R_ / 64, 2 * H_ / 64, B_), 256, 0, stream>>>(
        catb, (long)2 * H_ * S_, S_, a_rT, (long)R_ * S_, S_,
        (void*)cr, (long)R_ * 2 * H_, 2 * H_, S_);

    // 7) bilstm_in -> bf16
    build_bin<<<(R_ * B_ * DIN_ / 4 + 255) / 256, 256, 0, stream>>>(cr, ref, binb);

    // 8) xg = bin . W_ih^T + b_ih + b_hh  via MFMA
    gemm_xg_mfma<<<dim3(G_ / 64, R_ * B_ / 64, 2), 256, 0, stream>>>(
        binb, Wib, bihf, bhhf, bihb, bhhb, xgf, xgb);

    // 9) bi-LSTM scan: 4 blocks/dir, W fully LDS-resident, flag-synced
    lstm_scan_s<<<dim3(2 * NBD), dim3(256), 0, stream>>>(
        xgf, xgb, (const uint4*)WB, hbuf, flags, out);
}